// Round 5
// baseline (3113.945 us; speedup 1.0000x reference)
//
#include <hip/hip_runtime.h>
#include <hip/hip_bf16.h>

typedef __hip_bfloat16 bf16;

// Problem constants
constexpr int Bc  = 8;
constexpr int Lc  = 2500;
constexpr int Cc  = 14;
constexpr int Kc  = 9;
constexpr int Nn  = Bc * Lc;     // 20000
constexpr int NCLS = 20;
constexpr int HID = 128;
constexpr int NL  = 3;
constexpr int CC  = Cc * Cc;     // 196
constexpr int X3  = Cc * 3;      // 42

__device__ __forceinline__ float b2f(bf16 x) { return __bfloat162float(x); }
__device__ __forceinline__ float siluf(float x) { return x / (1.0f + __expf(-x)); }
__device__ __forceinline__ int clampi(int v, int n) {
  return ((unsigned)v < (unsigned)n) ? v : 0;
}
// dual-dtype input load / output store
__device__ __forceinline__ float ldin(const void* p, long i, int f32) {
  return f32 ? ((const float*)p)[i] : b2f(((const bf16*)p)[i]);
}
__device__ __forceinline__ void stout(void* p, long i, float v, int f32) {
  if (f32) ((float*)p)[i] = v;
  else ((bf16*)p)[i] = __float2bfloat16(v);
}

// ======================= dtype detector =======================
// Even-indexed bf16 reads of f32 memory see mantissa bits (random exponent,
// ~10% plausible); of true bf16 memory see real values (~100% plausible).
__global__ void detect_kernel(const void* Xraw, int* dtf, int* dflag) {
  __shared__ int cnt;
  if (threadIdx.x == 0) cnt = 0;
  __syncthreads();
  const bf16* xb = (const bf16*)Xraw;
  int local = 0;
  for (int k = threadIdx.x; k < 4096; k += 256) {
    float v = b2f(xb[2 * k]);
    if (v == v && fabsf(v) > 1e-8f && fabsf(v) < 1e4f) local++;
  }
  atomicAdd(&cnt, local);
  __syncthreads();
  if (threadIdx.x == 0) {
    *dtf = (cnt < 2048) ? 1 : 0;
    if (cnt >= 1024 && cnt < 3072) atomicMax(dflag, 860);  // ambiguous world
  }
}

__global__ void flag_init(int* f) { if (threadIdx.x == 0 && blockIdx.x == 0) *f = 0; }

__global__ void cvt_one(const void* __restrict__ src, float* __restrict__ dst,
                        long n, const int* __restrict__ dtf) {
  int f32 = *dtf;
  long stride = (long)gridDim.x * blockDim.x;
  for (long i = (long)blockIdx.x * blockDim.x + threadIdx.x; i < n; i += stride)
    dst[i] = ldin(src, i, f32);
}

// ======================= checkers =======================
__global__ void check_f32(const float* __restrict__ p, long n, float lim, int code,
                          int* __restrict__ f) {
  long stride = (long)gridDim.x * blockDim.x;
  int bad = 0;
  for (long i = (long)blockIdx.x * blockDim.x + threadIdx.x; i < n; i += stride) {
    float v = p[i];
    if (!(v == v) || fabsf(v) > lim) bad = 1;
  }
  if (bad) atomicMax(f, code);
}
__global__ void check_bf16buf(const bf16* __restrict__ p, long n, float lim, int code,
                              int* __restrict__ f) {
  long stride = (long)gridDim.x * blockDim.x;
  int bad = 0;
  for (long i = (long)blockIdx.x * blockDim.x + threadIdx.x; i < n; i += stride) {
    float v = b2f(p[i]);
    if (!(v == v) || fabsf(v) > lim) bad = 1;
  }
  if (bad) atomicMax(f, code);
}
__global__ void check_int(const int* __restrict__ p, long n, int lo, int hi, int code,
                          int* __restrict__ f) {
  long stride = (long)gridDim.x * blockDim.x;
  int bad = 0;
  for (long i = (long)blockIdx.x * blockDim.x + threadIdx.x; i < n; i += stride) {
    int v = p[i];
    if (v < lo || v >= hi) bad = 1;
  }
  if (bad) atomicMax(f, code);
}

// On any flag: stamp output0 region with the code, output1 with dtype verdict.
__global__ void stamp_kernel(const int* __restrict__ f, int hostflag,
                             const int* __restrict__ dtf, void* out) {
  int v = *f;
  if (hostflag > v) v = hostflag;
  if (v == 0) return;
  int f32 = *dtf;
  float code = (float)v;
  float verdict = f32 ? 512.0f : 256.0f;
  long n0 = (long)Nn * NCLS, n1 = (long)Nn * X3;
  long stride = (long)gridDim.x * blockDim.x;
  for (long i = (long)blockIdx.x * blockDim.x + threadIdx.x; i < n0 + n1; i += stride)
    stout(out, i, (i < n0) ? code : verdict, f32);
}

// ======================= model kernels (fp32 weights from ws) =======================
__global__ __launch_bounds__(128) void wrp_kernel(const float* __restrict__ Wrf,
                                                  const float* __restrict__ We1f,
                                                  float* __restrict__ Wrp) {
  int l = blockIdx.x / CC, j = blockIdx.x % CC;
  int t = threadIdx.x;
  __shared__ float row[HID];
  row[t] = Wrf[(size_t)(l * CC + j) * HID + t];
  __syncthreads();
  float acc = 0.f;
  #pragma unroll 4
  for (int k = 0; k < HID; ++k)
    acc += row[k] * We1f[(size_t)(l * 384 + 256 + k) * HID + t];
  Wrp[(size_t)(l * CC + j) * HID + t] = acc;
}

__global__ __launch_bounds__(128) void htab_kernel(const float* __restrict__ Etf,
                                                   const float* __restrict__ Winf,
                                                   const float* __restrict__ Wchf,
                                                   float* __restrict__ Htab,
                                                   float* __restrict__ cwtab) {
  int r = blockIdx.x, t = threadIdx.x;
  __shared__ float e[HID];
  e[t] = Etf[r * HID + t];
  __syncthreads();
  float acc = 0.f;
  #pragma unroll 4
  for (int k = 0; k < HID; ++k) acc += e[k] * Winf[k * HID + t];
  Htab[r * HID + t] = acc;
  if (t == 0) {
    float v[Cc];
    float mx = -1e30f;
    for (int c = 0; c < Cc; ++c) { v[c] = Wchf[r * Cc + c]; mx = fmaxf(mx, v[c]); }
    float s = 0.f;
    for (int c = 0; c < Cc; ++c) { v[c] = __expf(v[c] - mx); s += v[c]; }
    float inv = 1.0f / s;
    for (int c = 0; c < Cc; ++c) cwtab[r * Cc + c] = v[c] * inv;
  }
}

__global__ void gather_kernel(const void* __restrict__ Xraw, const int* __restrict__ dtf,
                              const int* __restrict__ S, const float* __restrict__ Htab,
                              float* __restrict__ h, float* __restrict__ Xa) {
  int f32 = *dtf;
  int stride = gridDim.x * blockDim.x;
  int i0 = blockIdx.x * blockDim.x + threadIdx.x;
  for (int i = i0; i < Nn * HID; i += stride)
    h[i] = Htab[clampi(S[i >> 7], NCLS) * HID + (i & 127)];
  for (int i = i0; i < Nn * X3; i += stride) Xa[i] = ldin(Xraw, i, f32);
}

__global__ __launch_bounds__(256) void knn_kernel(const float* __restrict__ Xa,
                                                  int* __restrict__ nbr) {
  __shared__ float pos[Lc * 3];
  constexpr int bpc = (Lc + 255) / 256;
  int comp = blockIdx.x / bpc, rb = blockIdx.x % bpc;
  int t = threadIdx.x;
  for (int i = t; i < Lc; i += 256) {
    size_t g = (size_t)(comp * Lc + i) * X3;
    pos[i * 3 + 0] = Xa[g + 3];
    pos[i * 3 + 1] = Xa[g + 4];
    pos[i * 3 + 2] = Xa[g + 5];
  }
  __syncthreads();
  int r = rb * 256 + t;
  if (r >= Lc) return;
  float px = pos[r * 3], py = pos[r * 3 + 1], pz = pos[r * 3 + 2];
  float bd[Kc];
  int   bi[Kc];
  #pragma unroll
  for (int k = 0; k < Kc; ++k) { bd[k] = 1e30f; bi[k] = 0; }
  for (int i = 0; i < Lc; ++i) {
    float dx = px - pos[i * 3], dy = py - pos[i * 3 + 1], dz = pz - pos[i * 3 + 2];
    float d2 = dx * dx + dy * dy + dz * dz;
    if (i == r) continue;
    if (d2 < bd[Kc - 1]) {
      bd[Kc - 1] = d2; bi[Kc - 1] = i;
      #pragma unroll
      for (int p = Kc - 1; p > 0; --p) {
        if (bd[p] < bd[p - 1]) {
          float td = bd[p]; bd[p] = bd[p - 1]; bd[p - 1] = td;
          int   ti = bi[p]; bi[p] = bi[p - 1]; bi[p - 1] = ti;
        }
      }
    }
  }
  int g = comp * Lc + r;
  #pragma unroll
  for (int k = 0; k < Kc; ++k) nbr[g * Kc + k] = comp * Lc + bi[k];
}

__global__ __launch_bounds__(128) void nodeAB_kernel(const float* __restrict__ h,
                                                     const float* __restrict__ We1f,
                                                     const float* __restrict__ be1f,
                                                     bf16* __restrict__ hA,
                                                     bf16* __restrict__ hB) {
  __shared__ float sh[8 * HID];
  int tid = threadIdx.x, n0 = blockIdx.x * 8;
  for (int o = tid; o < 8 * HID; o += 128) sh[o] = h[(size_t)n0 * HID + o];
  __syncthreads();
  float a[8], b[8];
  #pragma unroll
  for (int g = 0; g < 8; ++g) { a[g] = 0.f; b[g] = 0.f; }
  for (int j = 0; j < HID; ++j) {
    float wa = We1f[j * HID + tid];
    float wb = We1f[(HID + j) * HID + tid];
    #pragma unroll
    for (int g = 0; g < 8; ++g) {
      float x = sh[g * HID + j];
      a[g] += x * wa;
      b[g] += x * wb;
    }
  }
  float be = be1f[tid];
  #pragma unroll
  for (int g = 0; g < 8; ++g) {
    hA[(size_t)(n0 + g) * HID + tid] = __float2bfloat16(a[g] + be);
    hB[(size_t)(n0 + g) * HID + tid] = __float2bfloat16(b[g]);
  }
}

constexpr int Gn = 4;
constexpr int EB = Gn * Kc;         // 36
constexpr int LS = 40;

__global__ __launch_bounds__(128) void edge_kernel(
    const float* __restrict__ Xin, float* __restrict__ Xout,
    const bf16* __restrict__ hA, const bf16* __restrict__ hB,
    const int* __restrict__ S, const float* __restrict__ cwtab,
    const int* __restrict__ nbr,
    const float* __restrict__ Wrp, const float* __restrict__ We2f,
    const float* __restrict__ Wx1f, const float* __restrict__ Wx2f,
    bf16* __restrict__ aggm) {
  __shared__ float s_rad[CC * LS];
  __shared__ float s_buf[HID * LS];
  __shared__ float s_xd[EB * X3];
  __shared__ float s_coef[EB * Cc];
  __shared__ float s_cw[Gn * Cc];
  __shared__ int   s_dst[EB];

  int t = threadIdx.x;
  int n0 = blockIdx.x * Gn;

  if (t < EB) s_dst[t] = clampi(nbr[n0 * Kc + t], Nn);
  if (t >= 64 && t < 64 + Gn * Cc) {
    int o = t - 64;
    s_cw[o] = cwtab[clampi(S[n0 + o / Cc], NCLS) * Cc + o % Cc];
  }
  __syncthreads();

  for (int o = t; o < EB * X3; o += 128) {
    int e = o / X3, i = o - e * X3;
    s_xd[o] = Xin[(size_t)(n0 + e / Kc) * X3 + i] - Xin[(size_t)s_dst[e] * X3 + i];
  }
  __syncthreads();

  for (int o = t; o < CC * EB; o += 128) {
    int j = o / EB, e = o - j * EB;
    int c = j / Cc, d = j - c * Cc;
    const float* xe = s_xd + e * X3;
    s_rad[j * LS + e] = (xe[c * 3 + 0] * xe[d * 3 + 0] +
                         xe[c * 3 + 1] * xe[d * 3 + 1] +
                         xe[c * 3 + 2] * xe[d * 3 + 2]) * (1.0f / 14.0f);
  }
  __syncthreads();

  float acc[EB];
  #pragma unroll
  for (int e = 0; e < EB; ++e) acc[e] = 0.f;
  for (int j = 0; j < CC; ++j) {
    float w = Wrp[j * HID + t];
    #pragma unroll
    for (int e = 0; e < EB; ++e) acc[e] += s_rad[j * LS + e] * w;
  }
  {
    float hAr[Gn];
    #pragma unroll
    for (int g = 0; g < Gn; ++g) hAr[g] = b2f(hA[(size_t)(n0 + g) * HID + t]);
    #pragma unroll
    for (int e = 0; e < EB; ++e) {
      float v = acc[e] + hAr[e / Kc] + b2f(hB[(size_t)s_dst[e] * HID + t]);
      s_buf[t * LS + e] = siluf(v);
    }
  }
  __syncthreads();

  float acc2[EB];
  #pragma unroll
  for (int e = 0; e < EB; ++e) acc2[e] = 0.f;
  for (int j = 0; j < HID; ++j) {
    float w = We2f[j * HID + t];
    #pragma unroll
    for (int e = 0; e < EB; ++e) acc2[e] += s_buf[j * LS + e] * w;
  }
  #pragma unroll
  for (int e = 0; e < EB; ++e) acc2[e] = siluf(acc2[e]);
  #pragma unroll
  for (int g = 0; g < Gn; ++g) {
    float s = 0.f;
    #pragma unroll
    for (int k = 0; k < Kc; ++k) s += acc2[g * Kc + k];
    aggm[(size_t)(n0 + g) * HID + t] = __float2bfloat16(s);
  }
  #pragma unroll
  for (int e = 0; e < EB; ++e) s_rad[t * LS + e] = acc2[e];
  __syncthreads();

  float acc3[EB];
  #pragma unroll
  for (int e = 0; e < EB; ++e) acc3[e] = 0.f;
  for (int j = 0; j < HID; ++j) {
    float w = Wx1f[j * HID + t];
    #pragma unroll
    for (int e = 0; e < EB; ++e) acc3[e] += s_rad[j * LS + e] * w;
  }
  #pragma unroll
  for (int e = 0; e < EB; ++e) s_buf[t * LS + e] = siluf(acc3[e]);
  __syncthreads();

  for (int o = t; o < EB * Cc; o += 128) {
    int e = o / Cc, c = o - e * Cc;
    float s = 0.f;
    #pragma unroll 4
    for (int j = 0; j < HID; ++j) s += s_buf[j * LS + e] * Wx2f[j * Cc + c];
    s_coef[o] = s;
  }
  __syncthreads();

  for (int o = t; o < Gn * X3; o += 128) {
    int g = o / X3, rem = o - g * X3, c = rem / 3;
    float s = 0.f;
    #pragma unroll
    for (int k = 0; k < Kc; ++k) {
      int e = g * Kc + k;
      s += s_xd[e * X3 + rem] * s_coef[e * Cc + c];
    }
    int gn = n0 + g;
    Xout[(size_t)gn * X3 + rem] =
        Xin[(size_t)gn * X3 + rem] + s * s_cw[g * Cc + c] * (1.0f / 9.0f);
  }
}

__global__ __launch_bounds__(128) void nodeupd_kernel(float* __restrict__ h,
                                                      const bf16* __restrict__ aggm,
                                                      const float* __restrict__ Wh1f,
                                                      const float* __restrict__ Wh2f) {
  __shared__ float cat[8 * 256];
  __shared__ float u[8 * HID];
  int tid = threadIdx.x, n0 = blockIdx.x * 8;
  for (int o = tid; o < 8 * HID; o += 128) {
    int g = o >> 7, j = o & 127;
    cat[g * 256 + j] = h[(size_t)n0 * HID + o];
    cat[g * 256 + HID + j] = b2f(aggm[(size_t)n0 * HID + o]);
  }
  __syncthreads();
  float acc[8];
  #pragma unroll
  for (int g = 0; g < 8; ++g) acc[g] = 0.f;
  for (int j = 0; j < 256; ++j) {
    float w = Wh1f[j * HID + tid];
    #pragma unroll
    for (int g = 0; g < 8; ++g) acc[g] += cat[g * 256 + j] * w;
  }
  #pragma unroll
  for (int g = 0; g < 8; ++g) u[g * HID + tid] = siluf(acc[g]);
  __syncthreads();
  float acc2[8];
  #pragma unroll
  for (int g = 0; g < 8; ++g) acc2[g] = 0.f;
  for (int j = 0; j < HID; ++j) {
    float w = Wh2f[j * HID + tid];
    #pragma unroll
    for (int g = 0; g < 8; ++g) acc2[g] += u[g * HID + j] * w;
  }
  #pragma unroll
  for (int g = 0; g < 8; ++g) h[(size_t)(n0 + g) * HID + tid] += acc2[g];
}

__global__ __launch_bounds__(128) void final_kernel(const float* __restrict__ h,
                                                    const float* __restrict__ Wf1f,
                                                    const float* __restrict__ Wf2f,
                                                    void* __restrict__ out,
                                                    const int* __restrict__ dtf) {
  __shared__ float sh[8 * HID];
  __shared__ float u[8 * HID];
  int f32 = *dtf;
  int tid = threadIdx.x, n0 = blockIdx.x * 8;
  for (int o = tid; o < 8 * HID; o += 128) sh[o] = siluf(h[(size_t)n0 * HID + o]);
  __syncthreads();
  float acc[8];
  #pragma unroll
  for (int g = 0; g < 8; ++g) acc[g] = 0.f;
  for (int j = 0; j < HID; ++j) {
    float w = Wf1f[j * HID + tid];
    #pragma unroll
    for (int g = 0; g < 8; ++g) acc[g] += sh[g * HID + j] * w;
  }
  #pragma unroll
  for (int g = 0; g < 8; ++g) u[g * HID + tid] = siluf(acc[g]);
  __syncthreads();
  for (int o = tid; o < 8 * NCLS; o += 128) {
    int g = o / NCLS, c = o - g * NCLS;
    float s = 0.f;
    #pragma unroll 4
    for (int j = 0; j < HID; ++j) s += u[g * HID + j] * Wf2f[j * NCLS + c];
    stout(out, (long)(n0 + g) * NCLS + c, s, f32);
  }
}

__global__ void xout_kernel(const float* __restrict__ Xf, void* __restrict__ out,
                            const int* __restrict__ dtf) {
  int f32 = *dtf;
  long base = (long)Nn * NCLS;
  for (long i = blockIdx.x * blockDim.x + threadIdx.x; i < (long)Nn * X3;
       i += (long)gridDim.x * blockDim.x)
    stout(out, base + i, Xf[i], f32);
}

// ---------------------------------------------------------------------------
extern "C" void kernel_launch(void* const* d_in, const int* in_sizes, int n_in,
                              void* d_out, int out_size, void* d_ws, size_t ws_size,
                              hipStream_t stream) {
  const void* X     = d_in[0];
  const int*  S     = (const int*)d_in[1];
  const void* Etab  = d_in[2];
  const void* Wchan = d_in[3];
  const void* Win   = d_in[4];
  const void* Wr    = d_in[5];
  const void* We1   = d_in[6];
  const void* be1   = d_in[7];
  const void* We2   = d_in[8];
  const void* Wx1   = d_in[9];
  const void* Wx2   = d_in[10];
  const void* Wh1   = d_in[11];
  const void* Wh2   = d_in[12];
  const void* Wf1   = d_in[13];
  const void* Wf2   = d_in[14];

  char* base = (char*)d_ws;
  size_t off = 0;
  auto alloc = [&](size_t bytes) {
    void* p = base + off;
    off += (bytes + 255) & ~(size_t)255;
    return p;
  };
  int*   dflag = (int*)  alloc(256);
  int*   dtf   = (int*)  alloc(256);
  int*   nbr   = (int*)  alloc((size_t)Nn * Kc * 4);
  float* Htab  = (float*)alloc(NCLS * HID * 4);
  float* cwtab = (float*)alloc(NCLS * Cc * 4);
  float* Wrpf  = (float*)alloc((size_t)NL * CC * HID * 4);
  // fp32 weight copies
  float* Etf   = (float*)alloc(NCLS * HID * 4);
  float* Wchf  = (float*)alloc(NCLS * Cc * 4);
  float* Winf  = (float*)alloc(HID * HID * 4);
  float* Wrf   = (float*)alloc((size_t)NL * CC * HID * 4);
  float* We1f  = (float*)alloc((size_t)NL * 384 * HID * 4);
  float* be1f  = (float*)alloc(NL * HID * 4);
  float* We2f  = (float*)alloc((size_t)NL * HID * HID * 4);
  float* Wx1f  = (float*)alloc((size_t)NL * HID * HID * 4);
  float* Wx2f  = (float*)alloc((size_t)NL * HID * Cc * 4);
  float* Wh1f  = (float*)alloc((size_t)NL * 256 * HID * 4);
  float* Wh2f  = (float*)alloc((size_t)NL * HID * HID * 4);
  float* Wf1f  = (float*)alloc(HID * HID * 4);
  float* Wf2f  = (float*)alloc(HID * NCLS * 4);
  // activations
  float* Xa    = (float*)alloc((size_t)Nn * X3 * 4);
  float* Xb    = (float*)alloc((size_t)Nn * X3 * 4);
  float* hv    = (float*)alloc((size_t)Nn * HID * 4);
  bf16*  hAv   = (bf16*) alloc((size_t)Nn * HID * 2);
  bf16*  hBv   = (bf16*) alloc((size_t)Nn * HID * 2);
  bf16*  aggmv = (bf16*) alloc((size_t)Nn * HID * 2);
  size_t required = off;

  static const long expect[15] = {840000, 20000, 2560, 280, 16384, 75264, 147456,
                                  384, 49152, 49152, 5376, 98304, 49152, 16384, 2560};
  int hostflag = 0;
  if (n_in != 15) hostflag = 948;
  else
    for (int i = 0; i < 15; ++i)
      if ((long)in_sizes[i] != expect[i]) hostflag = 948;
  if (hostflag == 0 && out_size != Nn * NCLS + Nn * X3) hostflag = 940;
  if (hostflag == 0 && ws_size < required) hostflag = 928;

  flag_init<<<1, 64, 0, stream>>>(dflag);
  detect_kernel<<<1, 256, 0, stream>>>(X, dtf, dflag);

  // convert all weights to fp32 (dual-dtype)
  cvt_one<<<8, 256, 0, stream>>>(Etab, Etf, NCLS * HID, dtf);
  cvt_one<<<2, 256, 0, stream>>>(Wchan, Wchf, NCLS * Cc, dtf);
  cvt_one<<<8, 256, 0, stream>>>(Win, Winf, HID * HID, dtf);
  cvt_one<<<32, 256, 0, stream>>>(Wr, Wrf, (long)NL * CC * HID, dtf);
  cvt_one<<<64, 256, 0, stream>>>(We1, We1f, (long)NL * 384 * HID, dtf);
  cvt_one<<<2, 256, 0, stream>>>(be1, be1f, NL * HID, dtf);
  cvt_one<<<32, 256, 0, stream>>>(We2, We2f, (long)NL * HID * HID, dtf);
  cvt_one<<<32, 256, 0, stream>>>(Wx1, Wx1f, (long)NL * HID * HID, dtf);
  cvt_one<<<4, 256, 0, stream>>>(Wx2, Wx2f, (long)NL * HID * Cc, dtf);
  cvt_one<<<32, 256, 0, stream>>>(Wh1, Wh1f, (long)NL * 256 * HID, dtf);
  cvt_one<<<32, 256, 0, stream>>>(Wh2, Wh2f, (long)NL * HID * HID, dtf);
  cvt_one<<<8, 256, 0, stream>>>(Wf1, Wf1f, HID * HID, dtf);
  cvt_one<<<2, 256, 0, stream>>>(Wf2, Wf2f, HID * NCLS, dtf);

  // checks on converted inputs
  check_f32<<<64, 256, 0, stream>>>(We1f, (long)NL * 384 * HID, 1e3f, 868, dflag);
  check_f32<<<32, 256, 0, stream>>>(Wrf, (long)NL * CC * HID, 1e3f, 868, dflag);
  check_f32<<<32, 256, 0, stream>>>(We2f, (long)NL * HID * HID, 1e3f, 868, dflag);
  check_f32<<<32, 256, 0, stream>>>(Wh1f, (long)NL * 256 * HID, 1e3f, 868, dflag);
  check_int<<<32, 256, 0, stream>>>(S, Nn, 0, NCLS, 880, dflag);

  // precompute
  wrp_kernel<<<NL * CC, 128, 0, stream>>>(Wrf, We1f, Wrpf);
  htab_kernel<<<NCLS, 128, 0, stream>>>(Etf, Winf, Wchf, Htab, cwtab);
  gather_kernel<<<512, 256, 0, stream>>>(X, dtf, S, Htab, hv, Xa);
  knn_kernel<<<Bc * ((Lc + 255) / 256), 256, 0, stream>>>(Xa, nbr);

  check_f32<<<256, 256, 0, stream>>>(Xa, (long)Nn * X3, 1e3f, 900, dflag);
  check_f32<<<8, 256, 0, stream>>>(Htab, NCLS * HID, 1e3f, 620, dflag);
  check_f32<<<2, 256, 0, stream>>>(cwtab, NCLS * Cc, 2.0f, 608, dflag);
  check_f32<<<32, 256, 0, stream>>>(Wrpf, (long)NL * CC * HID, 1e3f, 596, dflag);
  check_f32<<<256, 256, 0, stream>>>(hv, (long)Nn * HID, 1e3f, 512, dflag);
  check_int<<<64, 256, 0, stream>>>(nbr, (long)Nn * Kc, 0, Nn, 400, dflag);

  // layers
  float* Xi = Xa;
  float* Xo = Xb;
  for (int l = 0; l < NL; ++l) {
    nodeAB_kernel<<<Nn / 8, 128, 0, stream>>>(hv, We1f + (size_t)l * 384 * HID,
                                              be1f + l * HID, hAv, hBv);
    if (l == 0) {
      check_bf16buf<<<256, 256, 0, stream>>>(hAv, (long)Nn * HID, 1e3f, 320, dflag);
      check_bf16buf<<<256, 256, 0, stream>>>(hBv, (long)Nn * HID, 1e3f, 304, dflag);
    }
    edge_kernel<<<Nn / Gn, 128, 0, stream>>>(
        Xi, Xo, hAv, hBv, S, cwtab, nbr, Wrpf + (size_t)l * CC * HID,
        We2f + (size_t)l * HID * HID, Wx1f + (size_t)l * HID * HID,
        Wx2f + (size_t)l * HID * Cc, aggmv);
    if (l == 0) {
      check_bf16buf<<<256, 256, 0, stream>>>(aggmv, (long)Nn * HID, 1e3f, 208, dflag);
      check_f32<<<256, 256, 0, stream>>>(Xo, (long)Nn * X3, 1e3f, 160, dflag);
    }
    nodeupd_kernel<<<Nn / 8, 128, 0, stream>>>(hv, aggmv, Wh1f + (size_t)l * 256 * HID,
                                               Wh2f + (size_t)l * HID * HID);
    if (l == 0)
      check_f32<<<256, 256, 0, stream>>>(hv, (long)Nn * HID, 1e3f, 128, dflag);
    float* tmp = Xi; Xi = Xo; Xo = tmp;
  }

  check_f32<<<256, 256, 0, stream>>>(hv, (long)Nn * HID, 1e3f, 112, dflag);
  check_f32<<<256, 256, 0, stream>>>(Xi, (long)Nn * X3, 1e3f, 96, dflag);

  final_kernel<<<Nn / 8, 128, 0, stream>>>(hv, Wf1f, Wf2f, d_out, dtf);
  xout_kernel<<<512, 256, 0, stream>>>(Xi, d_out, dtf);

  stamp_kernel<<<512, 256, 0, stream>>>(dflag, hostflag, dtf, d_out);
}

// Round 6
// 2404.957 us; speedup vs baseline: 1.2948x; 1.2948x over previous
//
#include <hip/hip_runtime.h>
#include <hip/hip_bf16.h>

typedef __hip_bfloat16 bf16;

// Problem constants
constexpr int Bc  = 8;
constexpr int Lc  = 2500;
constexpr int Cc  = 14;
constexpr int Kc  = 9;
constexpr int Nn  = Bc * Lc;     // 20000
constexpr int NCLS = 20;
constexpr int HID = 128;
constexpr int NL  = 3;
constexpr int CC  = Cc * Cc;     // 196
constexpr int X3  = Cc * 3;      // 42

__device__ __forceinline__ float b2f(bf16 x) { return __bfloat162float(x); }
__device__ __forceinline__ float siluf(float x) { return x / (1.0f + __expf(-x)); }
__device__ __forceinline__ int clampi(int v, int n) {
  return ((unsigned)v < (unsigned)n) ? v : 0;
}
// unpack 2 bf16 packed in a uint32 (little-endian: elem0 = low 16 bits)
__device__ __forceinline__ void unpk2(unsigned int u, float& a, float& b) {
  a = __uint_as_float(u << 16);
  b = __uint_as_float(u & 0xffff0000u);
}

// ---------------------------------------------------------------------------
// Wrp[l] = Wr[l] @ We1[l][256:384,:]  (fold radial proj into edge-MLP input)
// ---------------------------------------------------------------------------
__global__ __launch_bounds__(128) void wrp_kernel(const float* __restrict__ Wr,
                                                  const float* __restrict__ We1,
                                                  float* __restrict__ Wrp) {
  int l = blockIdx.x / CC, j = blockIdx.x % CC;
  int t = threadIdx.x;
  __shared__ float row[HID];
  row[t] = Wr[(size_t)(l * CC + j) * HID + t];
  __syncthreads();
  float acc = 0.f;
  #pragma unroll 4
  for (int k = 0; k < HID; ++k)
    acc += row[k] * We1[(size_t)(l * 384 + 256 + k) * HID + t];
  Wrp[(size_t)(l * CC + j) * HID + t] = acc;
}

// Htab = E_tab @ Win (20x128); cwtab = row-softmax(Wchan) (20x14)
__global__ __launch_bounds__(128) void htab_kernel(const float* __restrict__ Et,
                                                   const float* __restrict__ Win,
                                                   const float* __restrict__ Wch,
                                                   float* __restrict__ Htab,
                                                   float* __restrict__ cwtab) {
  int r = blockIdx.x, t = threadIdx.x;
  __shared__ float e[HID];
  e[t] = Et[r * HID + t];
  __syncthreads();
  float acc = 0.f;
  #pragma unroll 4
  for (int k = 0; k < HID; ++k) acc += e[k] * Win[k * HID + t];
  Htab[r * HID + t] = acc;
  if (t == 0) {
    float v[Cc];
    float mx = -1e30f;
    for (int c = 0; c < Cc; ++c) { v[c] = Wch[r * Cc + c]; mx = fmaxf(mx, v[c]); }
    float s = 0.f;
    for (int c = 0; c < Cc; ++c) { v[c] = __expf(v[c] - mx); s += v[c]; }
    float inv = 1.0f / s;
    for (int c = 0; c < Cc; ++c) cwtab[r * Cc + c] = v[c] * inv;
  }
}

// h[n] = Htab[S[n]]
__global__ void gather_kernel(const int* __restrict__ S, const float* __restrict__ Htab,
                              float* __restrict__ h) {
  int stride = gridDim.x * blockDim.x;
  for (int i = blockIdx.x * blockDim.x + threadIdx.x; i < Nn * HID; i += stride)
    h[i] = Htab[clampi(S[i >> 7], NCLS) * HID + (i & 127)];
}

// ---------------------------------------------------------------------------
// kNN on channel-1 coords, per complex; stable tie-break (lower index first)
// ---------------------------------------------------------------------------
__global__ __launch_bounds__(256) void knn_kernel(const float* __restrict__ X,
                                                  int* __restrict__ nbr) {
  __shared__ float pos[Lc * 3];
  constexpr int bpc = (Lc + 255) / 256;
  int comp = blockIdx.x / bpc, rb = blockIdx.x % bpc;
  int t = threadIdx.x;
  for (int i = t; i < Lc; i += 256) {
    size_t g = (size_t)(comp * Lc + i) * X3;
    pos[i * 3 + 0] = X[g + 3];
    pos[i * 3 + 1] = X[g + 4];
    pos[i * 3 + 2] = X[g + 5];
  }
  __syncthreads();
  int r = rb * 256 + t;
  if (r >= Lc) return;
  float px = pos[r * 3], py = pos[r * 3 + 1], pz = pos[r * 3 + 2];
  float bd[Kc];
  int   bi[Kc];
  #pragma unroll
  for (int k = 0; k < Kc; ++k) { bd[k] = 1e30f; bi[k] = 0; }
  for (int i = 0; i < Lc; ++i) {
    float dx = px - pos[i * 3], dy = py - pos[i * 3 + 1], dz = pz - pos[i * 3 + 2];
    float d2 = dx * dx + dy * dy + dz * dz;
    if (i == r) continue;
    if (d2 < bd[Kc - 1]) {
      bd[Kc - 1] = d2; bi[Kc - 1] = i;
      #pragma unroll
      for (int p = Kc - 1; p > 0; --p) {
        if (bd[p] < bd[p - 1]) {
          float td = bd[p]; bd[p] = bd[p - 1]; bd[p - 1] = td;
          int   ti = bi[p]; bi[p] = bi[p - 1]; bi[p - 1] = ti;
        }
      }
    }
  }
  int g = comp * Lc + r;
  #pragma unroll
  for (int k = 0; k < Kc; ++k) nbr[g * Kc + k] = comp * Lc + bi[k];
}

// ---------------------------------------------------------------------------
// Per-node: hA = h@We1[0:128,:] + be1, hB = h@We1[128:256,:]  (bf16 out)
// ---------------------------------------------------------------------------
__global__ __launch_bounds__(128) void nodeAB_kernel(const float* __restrict__ h,
                                                     const float* __restrict__ We1,
                                                     const float* __restrict__ be1,
                                                     bf16* __restrict__ hA,
                                                     bf16* __restrict__ hB) {
  __shared__ float sh[8 * HID];
  int tid = threadIdx.x, n0 = blockIdx.x * 8;
  for (int o = tid; o < 8 * HID; o += 128) sh[o] = h[(size_t)n0 * HID + o];
  __syncthreads();
  float a[8], b[8];
  #pragma unroll
  for (int g = 0; g < 8; ++g) { a[g] = 0.f; b[g] = 0.f; }
  for (int j = 0; j < HID; ++j) {
    float wa = We1[j * HID + tid];
    float wb = We1[(HID + j) * HID + tid];
    #pragma unroll
    for (int g = 0; g < 8; ++g) {
      float x = sh[g * HID + j];
      a[g] += x * wa;
      b[g] += x * wb;
    }
  }
  float be = be1[tid];
  #pragma unroll
  for (int g = 0; g < 8; ++g) {
    hA[(size_t)(n0 + g) * HID + tid] = __float2bfloat16(a[g] + be);
    hB[(size_t)(n0 + g) * HID + tid] = __float2bfloat16(b[g]);
  }
}

// ---------------------------------------------------------------------------
// Fused edge kernel, register-tiled: 4 nodes (36 edges) per 128-thread block.
// Thread = (cg 0..31, eg 0..3): owns 9 edges x 4 cols = 36 f32 accumulators.
// Per K-step: ~3 LDS reads + 1 float4 weight load feed 36 FMAs (was 1:1).
// LDS 50.7 KB -> 3 blocks/CU.
// ---------------------------------------------------------------------------
constexpr int Gn  = 4;
constexpr int EB  = Gn * Kc;       // 36
constexpr int LSV = 52;            // f32 row stride, rows 208 B (16B-aligned)
constexpr int LSR = 48;            // f32 rad-chunk row stride (192 B)
constexpr int LSM = 40;            // bf16 m row stride (80 B)
constexpr int CH  = 28;            // rad chunk rows (196 = 7*28)

__global__ __launch_bounds__(128) void edge_kernel(
    const float* __restrict__ Xin, float* __restrict__ Xout,
    const bf16* __restrict__ hA, const bf16* __restrict__ hB,
    const int* __restrict__ S, const float* __restrict__ cwtab,
    const int* __restrict__ nbr,
    const float* __restrict__ Wrp, const float* __restrict__ We2,
    const float* __restrict__ Wx1, const float* __restrict__ Wx2,
    bf16* __restrict__ aggm) {
  __shared__ __align__(16) float s_v[HID * LSV];    // v1 then t2   26624 B
  __shared__ __align__(16) float s_radc[CH * LSR];  // rad chunk     5376 B
  __shared__ __align__(16) float s_xd[EB * X3];     //               6048 B
  __shared__ bf16  s_m[HID * LSM];                  // m (bf16)     10240 B
  __shared__ float s_coef[EB * Cc];                 //               2016 B
  __shared__ float s_cw[Gn * Cc];
  __shared__ int   s_dst[EB];

  int t = threadIdx.x;
  int n0 = blockIdx.x * Gn;
  int cg = t & 31, eg = t >> 5;
  int col0 = cg * 4;
  int ep0 = eg * 12;   // edge-group offset in s_v/s_radc rows (16B-aligned)
  int em0 = eg * 10;   // edge-group offset in s_m rows (4B-aligned pairs)

  if (t < EB) s_dst[t] = clampi(nbr[n0 * Kc + t], Nn);
  if (t >= 64 && t < 64 + Gn * Cc) {
    int o = t - 64;
    s_cw[o] = cwtab[clampi(S[n0 + o / Cc], NCLS) * Cc + o % Cc];
  }
  __syncthreads();

  // xd[e][i] = X[src_e][i] - X[dst_e][i]
  for (int o = t; o < EB * X3; o += 128) {
    int e = o / X3, i = o - e * X3;
    s_xd[o] = Xin[(size_t)(n0 + e / Kc) * X3 + i] - Xin[(size_t)s_dst[e] * X3 + i];
  }
  // (first chunk's leading barrier covers xd visibility)

  // ---- stage 1: acc = rad @ Wrp, rad staged in 28-row chunks ----
  float acc[9][4];
  #pragma unroll
  for (int ei = 0; ei < 9; ++ei)
    #pragma unroll
    for (int ci = 0; ci < 4; ++ci) acc[ei][ci] = 0.f;

  for (int cb = 0; cb < CC; cb += CH) {
    __syncthreads();   // xd ready / previous chunk consumed
    for (int o = t; o < CH * EB; o += 128) {
      int jl = o / EB, e = o - jl * EB;
      int j = cb + jl, c = j / Cc, d = j - c * Cc;
      const float* xe = s_xd + e * X3;
      s_radc[jl * LSR + (e / 9) * 12 + e % 9] =
          (xe[c * 3 + 0] * xe[d * 3 + 0] + xe[c * 3 + 1] * xe[d * 3 + 1] +
           xe[c * 3 + 2] * xe[d * 3 + 2]) * (1.0f / 14.0f);
    }
    __syncthreads();
    for (int jl = 0; jl < CH; ++jl) {
      int j = cb + jl;
      float4 w = *(const float4*)(Wrp + (size_t)j * HID + col0);
      const float* rp = s_radc + jl * LSR + ep0;
      float4 r0 = *(const float4*)rp;
      float4 r1 = *(const float4*)(rp + 4);
      float rv[9] = {r0.x, r0.y, r0.z, r0.w, r1.x, r1.y, r1.z, r1.w, rp[8]};
      #pragma unroll
      for (int ei = 0; ei < 9; ++ei) {
        acc[ei][0] += rv[ei] * w.x;
        acc[ei][1] += rv[ei] * w.y;
        acc[ei][2] += rv[ei] * w.z;
        acc[ei][3] += rv[ei] * w.w;
      }
    }
  }

  // epilogue: v1 = silu(acc + hA[src] + hB[dst])  -> s_v[col][e]
  {
    float ha[4];
    const unsigned int* hp = (const unsigned int*)(hA + (size_t)(n0 + eg) * HID + col0);
    unpk2(hp[0], ha[0], ha[1]);
    unpk2(hp[1], ha[2], ha[3]);
    #pragma unroll
    for (int ei = 0; ei < 9; ++ei) {
      int dst = s_dst[eg * 9 + ei];
      const unsigned int* bp = (const unsigned int*)(hB + (size_t)dst * HID + col0);
      float hb0, hb1, hb2, hb3;
      unpk2(bp[0], hb0, hb1);
      unpk2(bp[1], hb2, hb3);
      s_v[(col0 + 0) * LSV + ep0 + ei] = siluf(acc[ei][0] + ha[0] + hb0);
      s_v[(col0 + 1) * LSV + ep0 + ei] = siluf(acc[ei][1] + ha[1] + hb1);
      s_v[(col0 + 2) * LSV + ep0 + ei] = siluf(acc[ei][2] + ha[2] + hb2);
      s_v[(col0 + 3) * LSV + ep0 + ei] = siluf(acc[ei][3] + ha[3] + hb3);
    }
  }
  __syncthreads();

  // ---- stage 2: m = silu(v1 @ We2); aggm = per-node sum; m -> s_m (bf16) ----
  float acc2[9][4];
  #pragma unroll
  for (int ei = 0; ei < 9; ++ei)
    #pragma unroll
    for (int ci = 0; ci < 4; ++ci) acc2[ei][ci] = 0.f;
  for (int j = 0; j < HID; ++j) {
    const float* vp = s_v + j * LSV + ep0;
    float4 a0 = *(const float4*)vp;
    float4 a1 = *(const float4*)(vp + 4);
    float4 w = *(const float4*)(We2 + (size_t)j * HID + col0);
    float av[9] = {a0.x, a0.y, a0.z, a0.w, a1.x, a1.y, a1.z, a1.w, vp[8]};
    #pragma unroll
    for (int ei = 0; ei < 9; ++ei) {
      acc2[ei][0] += av[ei] * w.x;
      acc2[ei][1] += av[ei] * w.y;
      acc2[ei][2] += av[ei] * w.z;
      acc2[ei][3] += av[ei] * w.w;
    }
  }
  {
    float sum0 = 0.f, sum1 = 0.f, sum2 = 0.f, sum3 = 0.f;
    #pragma unroll
    for (int ei = 0; ei < 9; ++ei) {
      float v0 = siluf(acc2[ei][0]), v1 = siluf(acc2[ei][1]);
      float v2 = siluf(acc2[ei][2]), v3 = siluf(acc2[ei][3]);
      sum0 += v0; sum1 += v1; sum2 += v2; sum3 += v3;
      s_m[(col0 + 0) * LSM + em0 + ei] = __float2bfloat16(v0);
      s_m[(col0 + 1) * LSM + em0 + ei] = __float2bfloat16(v1);
      s_m[(col0 + 2) * LSM + em0 + ei] = __float2bfloat16(v2);
      s_m[(col0 + 3) * LSM + em0 + ei] = __float2bfloat16(v3);
    }
    bf16* ap = aggm + (size_t)(n0 + eg) * HID + col0;
    ap[0] = __float2bfloat16(sum0);
    ap[1] = __float2bfloat16(sum1);
    ap[2] = __float2bfloat16(sum2);
    ap[3] = __float2bfloat16(sum3);
  }
  __syncthreads();

  // ---- stage 3: t2 = silu(m @ Wx1) -> s_v (v1 dead) ----
  float acc3[9][4];
  #pragma unroll
  for (int ei = 0; ei < 9; ++ei)
    #pragma unroll
    for (int ci = 0; ci < 4; ++ci) acc3[ei][ci] = 0.f;
  for (int j = 0; j < HID; ++j) {
    const unsigned int* mp = (const unsigned int*)(s_m + j * LSM + em0);
    float mv[9];
    unpk2(mp[0], mv[0], mv[1]);
    unpk2(mp[1], mv[2], mv[3]);
    unpk2(mp[2], mv[4], mv[5]);
    unpk2(mp[3], mv[6], mv[7]);
    mv[8] = b2f(s_m[j * LSM + em0 + 8]);
    float4 w = *(const float4*)(Wx1 + (size_t)j * HID + col0);
    #pragma unroll
    for (int ei = 0; ei < 9; ++ei) {
      acc3[ei][0] += mv[ei] * w.x;
      acc3[ei][1] += mv[ei] * w.y;
      acc3[ei][2] += mv[ei] * w.z;
      acc3[ei][3] += mv[ei] * w.w;
    }
  }
  #pragma unroll
  for (int ei = 0; ei < 9; ++ei) {
    s_v[(col0 + 0) * LSV + ep0 + ei] = siluf(acc3[ei][0]);
    s_v[(col0 + 1) * LSV + ep0 + ei] = siluf(acc3[ei][1]);
    s_v[(col0 + 2) * LSV + ep0 + ei] = siluf(acc3[ei][2]);
    s_v[(col0 + 3) * LSV + ep0 + ei] = siluf(acc3[ei][3]);
  }
  __syncthreads();

  // ---- stage 4: coef[e][c] = t2[e] . Wx2[:,c] ----
  for (int o = t; o < EB * Cc; o += 128) {
    int e = o / Cc, c = o - e * Cc;
    int ep = (e / 9) * 12 + e % 9;
    float s = 0.f;
    #pragma unroll 4
    for (int j = 0; j < HID; ++j) s += s_v[j * LSV + ep] * Wx2[j * Cc + c];
    s_coef[o] = s;
  }
  __syncthreads();

  // ---- stage 5: X_out = X_in + (sum_k xd*coef)*cw/K ----
  for (int o = t; o < Gn * X3; o += 128) {
    int g = o / X3, rem = o - g * X3, c = rem / 3;
    float s = 0.f;
    #pragma unroll
    for (int k = 0; k < Kc; ++k) {
      int e = g * Kc + k;
      s += s_xd[e * X3 + rem] * s_coef[e * Cc + c];
    }
    int gn = n0 + g;
    Xout[(size_t)gn * X3 + rem] =
        Xin[(size_t)gn * X3 + rem] + s * s_cw[g * Cc + c] * (1.0f / 9.0f);
  }
}

// ---------------------------------------------------------------------------
// Node update: h += silu(cat(h,aggm) @ Wh1) @ Wh2
// ---------------------------------------------------------------------------
__global__ __launch_bounds__(128) void nodeupd_kernel(float* __restrict__ h,
                                                      const bf16* __restrict__ aggm,
                                                      const float* __restrict__ Wh1,
                                                      const float* __restrict__ Wh2) {
  __shared__ float cat[8 * 256];
  __shared__ float u[8 * HID];
  int tid = threadIdx.x, n0 = blockIdx.x * 8;
  for (int o = tid; o < 8 * HID; o += 128) {
    int g = o >> 7, j = o & 127;
    cat[g * 256 + j] = h[(size_t)n0 * HID + o];
    cat[g * 256 + HID + j] = b2f(aggm[(size_t)n0 * HID + o]);
  }
  __syncthreads();
  float acc[8];
  #pragma unroll
  for (int g = 0; g < 8; ++g) acc[g] = 0.f;
  for (int j = 0; j < 256; ++j) {
    float w = Wh1[j * HID + tid];
    #pragma unroll
    for (int g = 0; g < 8; ++g) acc[g] += cat[g * 256 + j] * w;
  }
  #pragma unroll
  for (int g = 0; g < 8; ++g) u[g * HID + tid] = siluf(acc[g]);
  __syncthreads();
  float acc2[8];
  #pragma unroll
  for (int g = 0; g < 8; ++g) acc2[g] = 0.f;
  for (int j = 0; j < HID; ++j) {
    float w = Wh2[j * HID + tid];
    #pragma unroll
    for (int g = 0; g < 8; ++g) acc2[g] += u[g * HID + j] * w;
  }
  #pragma unroll
  for (int g = 0; g < 8; ++g) h[(size_t)(n0 + g) * HID + tid] += acc2[g];
}

// ---------------------------------------------------------------------------
// Final FFN: logits = silu(silu(h)@Wf1)@Wf2 -> f32 out
// ---------------------------------------------------------------------------
__global__ __launch_bounds__(128) void final_kernel(const float* __restrict__ h,
                                                    const float* __restrict__ Wf1,
                                                    const float* __restrict__ Wf2,
                                                    float* __restrict__ out) {
  __shared__ float sh[8 * HID];
  __shared__ float u[8 * HID];
  int tid = threadIdx.x, n0 = blockIdx.x * 8;
  for (int o = tid; o < 8 * HID; o += 128) sh[o] = siluf(h[(size_t)n0 * HID + o]);
  __syncthreads();
  float acc[8];
  #pragma unroll
  for (int g = 0; g < 8; ++g) acc[g] = 0.f;
  for (int j = 0; j < HID; ++j) {
    float w = Wf1[j * HID + tid];
    #pragma unroll
    for (int g = 0; g < 8; ++g) acc[g] += sh[g * HID + j] * w;
  }
  #pragma unroll
  for (int g = 0; g < 8; ++g) u[g * HID + tid] = siluf(acc[g]);
  __syncthreads();
  for (int o = tid; o < 8 * NCLS; o += 128) {
    int g = o / NCLS, c = o - g * NCLS;
    float s = 0.f;
    #pragma unroll 4
    for (int j = 0; j < HID; ++j) s += u[g * HID + j] * Wf2[j * NCLS + c];
    out[(size_t)(n0 + g) * NCLS + c] = s;
  }
}

__global__ void xout_kernel(const float* __restrict__ Xf, float* __restrict__ out) {
  for (int i = blockIdx.x * blockDim.x + threadIdx.x; i < Nn * X3;
       i += gridDim.x * blockDim.x)
    out[i] = Xf[i];
}

// ---------------------------------------------------------------------------
extern "C" void kernel_launch(void* const* d_in, const int* in_sizes, int n_in,
                              void* d_out, int out_size, void* d_ws, size_t ws_size,
                              hipStream_t stream) {
  const float* X    = (const float*)d_in[0];
  const int*   S    = (const int*)d_in[1];
  const float* Etab = (const float*)d_in[2];
  const float* Wch  = (const float*)d_in[3];
  const float* Win  = (const float*)d_in[4];
  const float* Wr   = (const float*)d_in[5];
  const float* We1  = (const float*)d_in[6];
  const float* be1  = (const float*)d_in[7];
  const float* We2  = (const float*)d_in[8];
  const float* Wx1  = (const float*)d_in[9];
  const float* Wx2  = (const float*)d_in[10];
  const float* Wh1  = (const float*)d_in[11];
  const float* Wh2  = (const float*)d_in[12];
  const float* Wf1  = (const float*)d_in[13];
  const float* Wf2  = (const float*)d_in[14];
  (void)in_sizes; (void)n_in; (void)out_size; (void)ws_size;

  char* base = (char*)d_ws;
  size_t off = 0;
  auto alloc = [&](size_t bytes) {
    void* p = base + off;
    off += (bytes + 255) & ~(size_t)255;
    return p;
  };
  int*   nbr   = (int*)  alloc((size_t)Nn * Kc * 4);
  float* Htab  = (float*)alloc(NCLS * HID * 4);
  float* cwtab = (float*)alloc(NCLS * Cc * 4);
  float* Wrpf  = (float*)alloc((size_t)NL * CC * HID * 4);
  float* Xa    = (float*)alloc((size_t)Nn * X3 * 4);
  float* Xb    = (float*)alloc((size_t)Nn * X3 * 4);
  float* hv    = (float*)alloc((size_t)Nn * HID * 4);
  bf16*  hAv   = (bf16*) alloc((size_t)Nn * HID * 2);
  bf16*  hBv   = (bf16*) alloc((size_t)Nn * HID * 2);
  bf16*  aggmv = (bf16*) alloc((size_t)Nn * HID * 2);   // ~33.4 MB total

  wrp_kernel<<<NL * CC, 128, 0, stream>>>(Wr, We1, Wrpf);
  htab_kernel<<<NCLS, 128, 0, stream>>>(Etab, Win, Wch, Htab, cwtab);
  gather_kernel<<<512, 256, 0, stream>>>(S, Htab, hv);
  knn_kernel<<<Bc * ((Lc + 255) / 256), 256, 0, stream>>>(X, nbr);

  // X ping-pong: layer0 reads the input directly
  const float* Xi = X;
  float* Xo = Xb;
  for (int l = 0; l < NL; ++l) {
    nodeAB_kernel<<<Nn / 8, 128, 0, stream>>>(hv, We1 + (size_t)l * 384 * HID,
                                              be1 + l * HID, hAv, hBv);
    edge_kernel<<<Nn / Gn, 128, 0, stream>>>(
        Xi, Xo, hAv, hBv, S, cwtab, nbr, Wrpf + (size_t)l * CC * HID,
        We2 + (size_t)l * HID * HID, Wx1 + (size_t)l * HID * HID,
        Wx2 + (size_t)l * HID * Cc, aggmv);
    nodeupd_kernel<<<Nn / 8, 128, 0, stream>>>(hv, aggmv, Wh1 + (size_t)l * 256 * HID,
                                               Wh2 + (size_t)l * HID * HID);
    Xi = Xo;
    Xo = (Xo == Xb) ? Xa : Xb;
  }

  float* out = (float*)d_out;
  final_kernel<<<Nn / 8, 128, 0, stream>>>(hv, Wf1, Wf2, out);
  xout_kernel<<<512, 256, 0, stream>>>(Xi, out + (size_t)Nn * NCLS);
}

// Round 7
// 2239.237 us; speedup vs baseline: 1.3906x; 1.0740x over previous
//
#include <hip/hip_runtime.h>
#include <hip/hip_bf16.h>

typedef __hip_bfloat16 bf16;

// Problem constants
constexpr int Bc  = 8;
constexpr int Lc  = 2500;
constexpr int Cc  = 14;
constexpr int Kc  = 9;
constexpr int Nn  = Bc * Lc;     // 20000
constexpr int NCLS = 20;
constexpr int HID = 128;
constexpr int NL  = 3;
constexpr int CC  = Cc * Cc;     // 196
constexpr int X3  = Cc * 3;      // 42

__device__ __forceinline__ float b2f(bf16 x) { return __bfloat162float(x); }
__device__ __forceinline__ float siluf(float x) { return x / (1.0f + __expf(-x)); }
__device__ __forceinline__ int clampi(int v, int n) {
  return ((unsigned)v < (unsigned)n) ? v : 0;
}
// unpack 2 bf16 packed in a uint32 (little-endian: elem0 = low 16 bits)
__device__ __forceinline__ void unpk2(unsigned int u, float& a, float& b) {
  a = __uint_as_float(u << 16);
  b = __uint_as_float(u & 0xffff0000u);
}
__device__ __forceinline__ unsigned short f2bu(float x) {
  bf16 h = __float2bfloat16(x);
  return *reinterpret_cast<unsigned short*>(&h);
}

// ---------------------------------------------------------------------------
// Wrp[l] = Wr[l] @ We1[l][256:384,:]  (fold radial proj into edge-MLP input)
// ---------------------------------------------------------------------------
__global__ __launch_bounds__(128) void wrp_kernel(const float* __restrict__ Wr,
                                                  const float* __restrict__ We1,
                                                  float* __restrict__ Wrp) {
  int l = blockIdx.x / CC, j = blockIdx.x % CC;
  int t = threadIdx.x;
  __shared__ float row[HID];
  row[t] = Wr[(size_t)(l * CC + j) * HID + t];
  __syncthreads();
  float acc = 0.f;
  #pragma unroll 4
  for (int k = 0; k < HID; ++k)
    acc += row[k] * We1[(size_t)(l * 384 + 256 + k) * HID + t];
  Wrp[(size_t)(l * CC + j) * HID + t] = acc;
}

// Htab = E_tab @ Win (20x128); cwtab = row-softmax(Wchan) (20x14)
__global__ __launch_bounds__(128) void htab_kernel(const float* __restrict__ Et,
                                                   const float* __restrict__ Win,
                                                   const float* __restrict__ Wch,
                                                   float* __restrict__ Htab,
                                                   float* __restrict__ cwtab) {
  int r = blockIdx.x, t = threadIdx.x;
  __shared__ float e[HID];
  e[t] = Et[r * HID + t];
  __syncthreads();
  float acc = 0.f;
  #pragma unroll 4
  for (int k = 0; k < HID; ++k) acc += e[k] * Win[k * HID + t];
  Htab[r * HID + t] = acc;
  if (t == 0) {
    float v[Cc];
    float mx = -1e30f;
    for (int c = 0; c < Cc; ++c) { v[c] = Wch[r * Cc + c]; mx = fmaxf(mx, v[c]); }
    float s = 0.f;
    for (int c = 0; c < Cc; ++c) { v[c] = __expf(v[c] - mx); s += v[c]; }
    float inv = 1.0f / s;
    for (int c = 0; c < Cc; ++c) cwtab[r * Cc + c] = v[c] * inv;
  }
}

// h[n] = Htab[S[n]]
__global__ void gather_kernel(const int* __restrict__ S, const float* __restrict__ Htab,
                              float* __restrict__ h) {
  int stride = gridDim.x * blockDim.x;
  for (int i = blockIdx.x * blockDim.x + threadIdx.x; i < Nn * HID; i += stride)
    h[i] = Htab[clampi(S[i >> 7], NCLS) * HID + (i & 127)];
}

// ---------------------------------------------------------------------------
// kNN on channel-1 coords, per complex; stable tie-break (lower index first)
// ---------------------------------------------------------------------------
__global__ __launch_bounds__(256) void knn_kernel(const float* __restrict__ X,
                                                  int* __restrict__ nbr) {
  __shared__ float pos[Lc * 3];
  constexpr int bpc = (Lc + 255) / 256;
  int comp = blockIdx.x / bpc, rb = blockIdx.x % bpc;
  int t = threadIdx.x;
  for (int i = t; i < Lc; i += 256) {
    size_t g = (size_t)(comp * Lc + i) * X3;
    pos[i * 3 + 0] = X[g + 3];
    pos[i * 3 + 1] = X[g + 4];
    pos[i * 3 + 2] = X[g + 5];
  }
  __syncthreads();
  int r = rb * 256 + t;
  if (r >= Lc) return;
  float px = pos[r * 3], py = pos[r * 3 + 1], pz = pos[r * 3 + 2];
  float bd[Kc];
  int   bi[Kc];
  #pragma unroll
  for (int k = 0; k < Kc; ++k) { bd[k] = 1e30f; bi[k] = 0; }
  for (int i = 0; i < Lc; ++i) {
    float dx = px - pos[i * 3], dy = py - pos[i * 3 + 1], dz = pz - pos[i * 3 + 2];
    float d2 = dx * dx + dy * dy + dz * dz;
    if (i == r) continue;
    if (d2 < bd[Kc - 1]) {
      bd[Kc - 1] = d2; bi[Kc - 1] = i;
      #pragma unroll
      for (int p = Kc - 1; p > 0; --p) {
        if (bd[p] < bd[p - 1]) {
          float td = bd[p]; bd[p] = bd[p - 1]; bd[p - 1] = td;
          int   ti = bi[p]; bi[p] = bi[p - 1]; bi[p - 1] = ti;
        }
      }
    }
  }
  int g = comp * Lc + r;
  #pragma unroll
  for (int k = 0; k < Kc; ++k) nbr[g * Kc + k] = comp * Lc + bi[k];
}

// ---------------------------------------------------------------------------
// Per-node: hA = h@We1[0:128,:] + be1, hB = h@We1[128:256,:]  (bf16 out)
// ---------------------------------------------------------------------------
__global__ __launch_bounds__(128) void nodeAB_kernel(const float* __restrict__ h,
                                                     const float* __restrict__ We1,
                                                     const float* __restrict__ be1,
                                                     bf16* __restrict__ hA,
                                                     bf16* __restrict__ hB) {
  __shared__ float sh[8 * HID];
  int tid = threadIdx.x, n0 = blockIdx.x * 8;
  for (int o = tid; o < 8 * HID; o += 128) sh[o] = h[(size_t)n0 * HID + o];
  __syncthreads();
  float a[8], b[8];
  #pragma unroll
  for (int g = 0; g < 8; ++g) { a[g] = 0.f; b[g] = 0.f; }
  for (int j = 0; j < HID; ++j) {
    float wa = We1[j * HID + tid];
    float wb = We1[(HID + j) * HID + tid];
    #pragma unroll
    for (int g = 0; g < 8; ++g) {
      float x = sh[g * HID + j];
      a[g] += x * wa;
      b[g] += x * wb;
    }
  }
  float be = be1[tid];
  #pragma unroll
  for (int g = 0; g < 8; ++g) {
    hA[(size_t)(n0 + g) * HID + tid] = __float2bfloat16(a[g] + be);
    hB[(size_t)(n0 + g) * HID + tid] = __float2bfloat16(b[g]);
  }
}

// ---------------------------------------------------------------------------
// Fused edge kernel: [edge][hid] LDS layout.
// Thread = (cg 0..31, eg 0..3): 9 edges x 4 cols = 36 f32 accumulators.
// Stores: lane cg writes float4 at col cg*4 -> 32 lanes = 128 contiguous
// floats = conflict-free.  K-loop reads are wave-broadcast (2-way = free).
// LDS ~36.9 KB -> 4 blocks/CU.
// ---------------------------------------------------------------------------
constexpr int Gn  = 4;
constexpr int EB  = Gn * Kc;       // 36
constexpr int SVS = 132;           // f32 row stride for s_v (16B-aligned rows)
constexpr int SMS = 66;            // uint row stride for s_m (2 bf16 per uint)
constexpr int LSR = 48;            // f32 rad-chunk row stride
constexpr int CH  = 28;            // rad chunk rows (196 = 7*28)

__global__ __launch_bounds__(128) void edge_kernel(
    const float* __restrict__ Xin, float* __restrict__ Xout,
    const bf16* __restrict__ hA, const bf16* __restrict__ hB,
    const int* __restrict__ S, const float* __restrict__ cwtab,
    const int* __restrict__ nbr,
    const float* __restrict__ Wrp, const float* __restrict__ We2,
    const float* __restrict__ Wx1, const float* __restrict__ Wx2,
    bf16* __restrict__ aggm) {
  __shared__ __align__(16) float s_v[EB * SVS];          // v1 then t2  19008 B
  __shared__ __align__(16) unsigned int s_mu[EB * SMS];  // m bf16x2     9504 B
  __shared__ __align__(16) float s_xd[EB * X3];          //              6048 B
  __shared__ float s_coef[EB * Cc];                      //              2016 B
  __shared__ float s_cw[Gn * Cc];
  __shared__ int   s_dst[EB];
  float* s_radc = (float*)s_mu;   // rad chunk (CH*LSR = 5376 B), stage-1 only

  int t = threadIdx.x;
  int n0 = blockIdx.x * Gn;
  int cg = t & 31, eg = t >> 5;
  int col0 = cg * 4;
  int e0 = eg * 9;

  if (t < EB) s_dst[t] = clampi(nbr[n0 * Kc + t], Nn);
  if (t >= 64 && t < 64 + Gn * Cc) {
    int o = t - 64;
    s_cw[o] = cwtab[clampi(S[n0 + o / Cc], NCLS) * Cc + o % Cc];
  }
  __syncthreads();

  // xd[e][i] = X[src_e][i] - X[dst_e][i]
  for (int o = t; o < EB * X3; o += 128) {
    int e = o / X3, i = o - e * X3;
    s_xd[o] = Xin[(size_t)(n0 + e / Kc) * X3 + i] - Xin[(size_t)s_dst[e] * X3 + i];
  }

  // ---- stage 1: acc = rad @ Wrp, rad staged in 28-row chunks ----
  float acc[9][4];
  #pragma unroll
  for (int ei = 0; ei < 9; ++ei)
    #pragma unroll
    for (int ci = 0; ci < 4; ++ci) acc[ei][ci] = 0.f;

  for (int cb = 0; cb < CC; cb += CH) {
    __syncthreads();   // xd ready / previous chunk consumed
    for (int o = t; o < CH * EB; o += 128) {
      int jl = o / EB, e = o - jl * EB;
      int j = cb + jl, c = j / Cc, d = j - c * Cc;
      const float* xe = s_xd + e * X3;
      s_radc[jl * LSR + (e / 9) * 12 + e % 9] =
          (xe[c * 3 + 0] * xe[d * 3 + 0] + xe[c * 3 + 1] * xe[d * 3 + 1] +
           xe[c * 3 + 2] * xe[d * 3 + 2]) * (1.0f / 14.0f);
    }
    __syncthreads();
    for (int jl = 0; jl < CH; ++jl) {
      int j = cb + jl;
      float4 w = *(const float4*)(Wrp + (size_t)j * HID + col0);
      const float* rp = s_radc + jl * LSR + eg * 12;
      float4 r0 = *(const float4*)rp;
      float4 r1 = *(const float4*)(rp + 4);
      float rv[9] = {r0.x, r0.y, r0.z, r0.w, r1.x, r1.y, r1.z, r1.w, rp[8]};
      #pragma unroll
      for (int ei = 0; ei < 9; ++ei) {
        acc[ei][0] += rv[ei] * w.x;
        acc[ei][1] += rv[ei] * w.y;
        acc[ei][2] += rv[ei] * w.z;
        acc[ei][3] += rv[ei] * w.w;
      }
    }
  }
  __syncthreads();   // all s_radc reads done before v1 writes reuse nothing,
                     // but needed before s_mu writes in stage 2; also keeps
                     // s_v writes ordered vs any stale reads (none).

  // epilogue: v1 = silu(acc + hA[src] + hB[dst]) -> s_v[e][col] (conflict-free)
  {
    float ha[4];
    const unsigned int* hp = (const unsigned int*)(hA + (size_t)(n0 + eg) * HID + col0);
    unpk2(hp[0], ha[0], ha[1]);
    unpk2(hp[1], ha[2], ha[3]);
    #pragma unroll
    for (int ei = 0; ei < 9; ++ei) {
      int dst = s_dst[e0 + ei];
      const unsigned int* bp = (const unsigned int*)(hB + (size_t)dst * HID + col0);
      float hb0, hb1, hb2, hb3;
      unpk2(bp[0], hb0, hb1);
      unpk2(bp[1], hb2, hb3);
      float4 v;
      v.x = siluf(acc[ei][0] + ha[0] + hb0);
      v.y = siluf(acc[ei][1] + ha[1] + hb1);
      v.z = siluf(acc[ei][2] + ha[2] + hb2);
      v.w = siluf(acc[ei][3] + ha[3] + hb3);
      *(float4*)(s_v + (e0 + ei) * SVS + col0) = v;
    }
  }
  __syncthreads();

  // ---- stage 2: m = silu(v1 @ We2); aggm = per-node sum; m -> s_mu (bf16x2) ----
  float acc2[9][4];
  #pragma unroll
  for (int ei = 0; ei < 9; ++ei)
    #pragma unroll
    for (int ci = 0; ci < 4; ++ci) acc2[ei][ci] = 0.f;
  for (int j2 = 0; j2 < HID / 2; ++j2) {
    float4 w0 = *(const float4*)(We2 + (size_t)(2 * j2) * HID + col0);
    float4 w1 = *(const float4*)(We2 + (size_t)(2 * j2 + 1) * HID + col0);
    #pragma unroll
    for (int ei = 0; ei < 9; ++ei) {
      float2 av = *(const float2*)(s_v + (e0 + ei) * SVS + 2 * j2);
      acc2[ei][0] += av.x * w0.x + av.y * w1.x;
      acc2[ei][1] += av.x * w0.y + av.y * w1.y;
      acc2[ei][2] += av.x * w0.z + av.y * w1.z;
      acc2[ei][3] += av.x * w0.w + av.y * w1.w;
    }
  }
  __syncthreads();   // all v1 reads done; s_mu (alias of s_radc) safe to write
  {
    float sum0 = 0.f, sum1 = 0.f, sum2 = 0.f, sum3 = 0.f;
    #pragma unroll
    for (int ei = 0; ei < 9; ++ei) {
      float v0 = siluf(acc2[ei][0]), v1 = siluf(acc2[ei][1]);
      float v2 = siluf(acc2[ei][2]), v3 = siluf(acc2[ei][3]);
      sum0 += v0; sum1 += v1; sum2 += v2; sum3 += v3;
      unsigned int u01 = (unsigned int)f2bu(v0) | ((unsigned int)f2bu(v1) << 16);
      unsigned int u23 = (unsigned int)f2bu(v2) | ((unsigned int)f2bu(v3) << 16);
      *(uint2*)(s_mu + (e0 + ei) * SMS + cg * 2) = make_uint2(u01, u23);
    }
    bf16* ap = aggm + (size_t)(n0 + eg) * HID + col0;
    ap[0] = __float2bfloat16(sum0);
    ap[1] = __float2bfloat16(sum1);
    ap[2] = __float2bfloat16(sum2);
    ap[3] = __float2bfloat16(sum3);
  }
  __syncthreads();

  // ---- stage 3: t2 = silu(m @ Wx1) -> s_v (v1 dead) ----
  float acc3[9][4];
  #pragma unroll
  for (int ei = 0; ei < 9; ++ei)
    #pragma unroll
    for (int ci = 0; ci < 4; ++ci) acc3[ei][ci] = 0.f;
  for (int j2 = 0; j2 < HID / 2; ++j2) {
    float4 w0 = *(const float4*)(Wx1 + (size_t)(2 * j2) * HID + col0);
    float4 w1 = *(const float4*)(Wx1 + (size_t)(2 * j2 + 1) * HID + col0);
    #pragma unroll
    for (int ei = 0; ei < 9; ++ei) {
      float m0, m1;
      unpk2(s_mu[(e0 + ei) * SMS + j2], m0, m1);
      acc3[ei][0] += m0 * w0.x + m1 * w1.x;
      acc3[ei][1] += m0 * w0.y + m1 * w1.y;
      acc3[ei][2] += m0 * w0.z + m1 * w1.z;
      acc3[ei][3] += m0 * w0.w + m1 * w1.w;
    }
  }
  __syncthreads();   // t2 writes below overwrite s_v after all m reads
  #pragma unroll
  for (int ei = 0; ei < 9; ++ei) {
    float4 v;
    v.x = siluf(acc3[ei][0]);
    v.y = siluf(acc3[ei][1]);
    v.z = siluf(acc3[ei][2]);
    v.w = siluf(acc3[ei][3]);
    *(float4*)(s_v + (e0 + ei) * SVS + col0) = v;
  }
  __syncthreads();

  // ---- stage 4: coef[e][c] = t2[e] . Wx2[:,c] ----
  for (int o = t; o < EB * Cc; o += 128) {
    int e = o / Cc, c = o - e * Cc;
    float s = 0.f;
    #pragma unroll 4
    for (int j = 0; j < HID; ++j) s += s_v[e * SVS + j] * Wx2[j * Cc + c];
    s_coef[o] = s;
  }
  __syncthreads();

  // ---- stage 5: X_out = X_in + (sum_k xd*coef)*cw/K ----
  for (int o = t; o < Gn * X3; o += 128) {
    int g = o / X3, rem = o - g * X3, c = rem / 3;
    float s = 0.f;
    #pragma unroll
    for (int k = 0; k < Kc; ++k) {
      int e = g * Kc + k;
      s += s_xd[e * X3 + rem] * s_coef[e * Cc + c];
    }
    int gn = n0 + g;
    Xout[(size_t)gn * X3 + rem] =
        Xin[(size_t)gn * X3 + rem] + s * s_cw[g * Cc + c] * (1.0f / 9.0f);
  }
}

// ---------------------------------------------------------------------------
// Node update: h += silu(cat(h,aggm) @ Wh1) @ Wh2
// ---------------------------------------------------------------------------
__global__ __launch_bounds__(128) void nodeupd_kernel(float* __restrict__ h,
                                                      const bf16* __restrict__ aggm,
                                                      const float* __restrict__ Wh1,
                                                      const float* __restrict__ Wh2) {
  __shared__ float cat[8 * 256];
  __shared__ float u[8 * HID];
  int tid = threadIdx.x, n0 = blockIdx.x * 8;
  for (int o = tid; o < 8 * HID; o += 128) {
    int g = o >> 7, j = o & 127;
    cat[g * 256 + j] = h[(size_t)n0 * HID + o];
    cat[g * 256 + HID + j] = b2f(aggm[(size_t)n0 * HID + o]);
  }
  __syncthreads();
  float acc[8];
  #pragma unroll
  for (int g = 0; g < 8; ++g) acc[g] = 0.f;
  for (int j = 0; j < 256; ++j) {
    float w = Wh1[j * HID + tid];
    #pragma unroll
    for (int g = 0; g < 8; ++g) acc[g] += cat[g * 256 + j] * w;
  }
  #pragma unroll
  for (int g = 0; g < 8; ++g) u[g * HID + tid] = siluf(acc[g]);
  __syncthreads();
  float acc2[8];
  #pragma unroll
  for (int g = 0; g < 8; ++g) acc2[g] = 0.f;
  for (int j = 0; j < HID; ++j) {
    float w = Wh2[j * HID + tid];
    #pragma unroll
    for (int g = 0; g < 8; ++g) acc2[g] += u[g * HID + j] * w;
  }
  #pragma unroll
  for (int g = 0; g < 8; ++g) h[(size_t)(n0 + g) * HID + tid] += acc2[g];
}

// ---------------------------------------------------------------------------
// Final FFN: logits = silu(silu(h)@Wf1)@Wf2 -> f32 out
// ---------------------------------------------------------------------------
__global__ __launch_bounds__(128) void final_kernel(const float* __restrict__ h,
                                                    const float* __restrict__ Wf1,
                                                    const float* __restrict__ Wf2,
                                                    float* __restrict__ out) {
  __shared__ float sh[8 * HID];
  __shared__ float u[8 * HID];
  int tid = threadIdx.x, n0 = blockIdx.x * 8;
  for (int o = tid; o < 8 * HID; o += 128) sh[o] = siluf(h[(size_t)n0 * HID + o]);
  __syncthreads();
  float acc[8];
  #pragma unroll
  for (int g = 0; g < 8; ++g) acc[g] = 0.f;
  for (int j = 0; j < HID; ++j) {
    float w = Wf1[j * HID + tid];
    #pragma unroll
    for (int g = 0; g < 8; ++g) acc[g] += sh[g * HID + j] * w;
  }
  #pragma unroll
  for (int g = 0; g < 8; ++g) u[g * HID + tid] = siluf(acc[g]);
  __syncthreads();
  for (int o = tid; o < 8 * NCLS; o += 128) {
    int g = o / NCLS, c = o - g * NCLS;
    float s = 0.f;
    #pragma unroll 4
    for (int j = 0; j < HID; ++j) s += u[g * HID + j] * Wf2[j * NCLS + c];
    out[(size_t)(n0 + g) * NCLS + c] = s;
  }
}

__global__ void xout_kernel(const float* __restrict__ Xf, float* __restrict__ out) {
  for (int i = blockIdx.x * blockDim.x + threadIdx.x; i < Nn * X3;
       i += gridDim.x * blockDim.x)
    out[i] = Xf[i];
}

// ---------------------------------------------------------------------------
extern "C" void kernel_launch(void* const* d_in, const int* in_sizes, int n_in,
                              void* d_out, int out_size, void* d_ws, size_t ws_size,
                              hipStream_t stream) {
  const float* X    = (const float*)d_in[0];
  const int*   S    = (const int*)d_in[1];
  const float* Etab = (const float*)d_in[2];
  const float* Wch  = (const float*)d_in[3];
  const float* Win  = (const float*)d_in[4];
  const float* Wr   = (const float*)d_in[5];
  const float* We1  = (const float*)d_in[6];
  const float* be1  = (const float*)d_in[7];
  const float* We2  = (const float*)d_in[8];
  const float* Wx1  = (const float*)d_in[9];
  const float* Wx2  = (const float*)d_in[10];
  const float* Wh1  = (const float*)d_in[11];
  const float* Wh2  = (const float*)d_in[12];
  const float* Wf1  = (const float*)d_in[13];
  const float* Wf2  = (const float*)d_in[14];
  (void)in_sizes; (void)n_in; (void)out_size; (void)ws_size;

  char* base = (char*)d_ws;
  size_t off = 0;
  auto alloc = [&](size_t bytes) {
    void* p = base + off;
    off += (bytes + 255) & ~(size_t)255;
    return p;
  };
  int*   nbr   = (int*)  alloc((size_t)Nn * Kc * 4);
  float* Htab  = (float*)alloc(NCLS * HID * 4);
  float* cwtab = (float*)alloc(NCLS * Cc * 4);
  float* Wrpf  = (float*)alloc((size_t)NL * CC * HID * 4);
  float* Xa    = (float*)alloc((size_t)Nn * X3 * 4);
  float* Xb    = (float*)alloc((size_t)Nn * X3 * 4);
  float* hv    = (float*)alloc((size_t)Nn * HID * 4);
  bf16*  hAv   = (bf16*) alloc((size_t)Nn * HID * 2);
  bf16*  hBv   = (bf16*) alloc((size_t)Nn * HID * 2);
  bf16*  aggmv = (bf16*) alloc((size_t)Nn * HID * 2);   // ~33.4 MB total

  wrp_kernel<<<NL * CC, 128, 0, stream>>>(Wr, We1, Wrpf);
  htab_kernel<<<NCLS, 128, 0, stream>>>(Etab, Win, Wch, Htab, cwtab);
  gather_kernel<<<512, 256, 0, stream>>>(S, Htab, hv);
  knn_kernel<<<Bc * ((Lc + 255) / 256), 256, 0, stream>>>(X, nbr);

  // X ping-pong: layer0 reads the input directly
  const float* Xi = X;
  float* Xo = Xb;
  for (int l = 0; l < NL; ++l) {
    nodeAB_kernel<<<Nn / 8, 128, 0, stream>>>(hv, We1 + (size_t)l * 384 * HID,
                                              be1 + l * HID, hAv, hBv);
    edge_kernel<<<Nn / Gn, 128, 0, stream>>>(
        Xi, Xo, hAv, hBv, S, cwtab, nbr, Wrpf + (size_t)l * CC * HID,
        We2 + (size_t)l * HID * HID, Wx1 + (size_t)l * HID * HID,
        Wx2 + (size_t)l * HID * Cc, aggmv);
    nodeupd_kernel<<<Nn / 8, 128, 0, stream>>>(hv, aggmv, Wh1 + (size_t)l * 256 * HID,
                                               Wh2 + (size_t)l * HID * HID);
    Xi = Xo;
    Xo = (Xo == Xb) ? Xa : Xb;
  }

  float* out = (float*)d_out;
  final_kernel<<<Nn / 8, 128, 0, stream>>>(hv, Wf1, Wf2, out);
  xout_kernel<<<512, 256, 0, stream>>>(Xi, out + (size_t)Nn * NCLS);
}

// Round 8
// 1233.833 us; speedup vs baseline: 2.5238x; 1.8149x over previous
//
#include <hip/hip_runtime.h>
#include <hip/hip_bf16.h>

typedef __hip_bfloat16 bf16;

// Problem constants
constexpr int Bc  = 8;
constexpr int Lc  = 2500;
constexpr int Cc  = 14;
constexpr int Kc  = 9;
constexpr int Nn  = Bc * Lc;     // 20000
constexpr int NCLS = 20;
constexpr int HID = 128;
constexpr int NL  = 3;
constexpr int CC  = Cc * Cc;     // 196
constexpr int X3  = Cc * 3;      // 42

typedef __bf16 bf16x8 __attribute__((ext_vector_type(8)));
typedef short  sh8    __attribute__((ext_vector_type(8)));
typedef float  f32x4  __attribute__((ext_vector_type(4)));

__device__ __forceinline__ float b2f(bf16 x) { return __bfloat162float(x); }
__device__ __forceinline__ float b2fu(unsigned short u) {
  return __uint_as_float(((unsigned int)u) << 16);
}
__device__ __forceinline__ unsigned short f2bu(float x) {
  bf16 h = __float2bfloat16(x);
  return *reinterpret_cast<unsigned short*>(&h);
}
__device__ __forceinline__ float siluf(float x) { return x / (1.0f + __expf(-x)); }
__device__ __forceinline__ int clampi(int v, int n) {
  return ((unsigned)v < (unsigned)n) ? v : 0;
}

__device__ __forceinline__ f32x4 mfma16(sh8 a, sh8 b, f32x4 c) {
  return __builtin_amdgcn_mfma_f32_16x16x32_bf16(
      __builtin_bit_cast(bf16x8, a), __builtin_bit_cast(bf16x8, b), c, 0, 0, 0);
}

// A/activation fragment-linear offset (in shorts). MT m-tiles; tile = 512 shorts.
// value (row e, col k) lives at tile (k/32, e/16), lane (e%16)+((k%32)/8)*16, j=k%8.
__device__ __forceinline__ int fragoff(int e, int k, int MT) {
  return (((k >> 5) * MT + (e >> 4)) << 9) +
         (((e & 15) + (((k >> 3) & 3) << 4)) << 3) + (k & 7);
}

// ---------------------------------------------------------------------------
// Wrp[l] = Wr[l] @ We1[l][256:384,:]  (fp32, fold radial proj into edge MLP)
// ---------------------------------------------------------------------------
__global__ __launch_bounds__(128) void wrp_kernel(const float* __restrict__ Wr,
                                                  const float* __restrict__ We1,
                                                  float* __restrict__ Wrp) {
  int l = blockIdx.x / CC, j = blockIdx.x % CC;
  int t = threadIdx.x;
  __shared__ float row[HID];
  row[t] = Wr[(size_t)(l * CC + j) * HID + t];
  __syncthreads();
  float acc = 0.f;
  #pragma unroll 4
  for (int k = 0; k < HID; ++k)
    acc += row[k] * We1[(size_t)(l * 384 + 256 + k) * HID + t];
  Wrp[(size_t)(l * CC + j) * HID + t] = acc;
}

// Shuffle fp32 K x N weight into B-fragment-linear bf16 (zero-padded).
// out[((kt*NT+nt)*64+lane)*8+j] = W[kt*32+(lane>>4)*8+j][nt*16+(lane&15)]
__global__ void shuf_kernel(const float* __restrict__ W, unsigned short* __restrict__ out,
                            int K, int N, int KT, int NT) {
  int total = KT * NT * 512;
  for (int idx = blockIdx.x * blockDim.x + threadIdx.x; idx < total;
       idx += gridDim.x * blockDim.x) {
    int j = idx & 7;
    int lane = (idx >> 3) & 63;
    int nt = (idx >> 9) % NT;
    int kt = idx / (512 * NT);
    int k = kt * 32 + ((lane >> 4) << 3) + j;
    int n = nt * 16 + (lane & 15);
    float v = (k < K && n < N) ? W[(size_t)k * N + n] : 0.f;
    out[idx] = f2bu(v);
  }
}

// Htab = E_tab @ Win (20x128); cwtab = row-softmax(Wchan) (20x14)
__global__ __launch_bounds__(128) void htab_kernel(const float* __restrict__ Et,
                                                   const float* __restrict__ Win,
                                                   const float* __restrict__ Wch,
                                                   float* __restrict__ Htab,
                                                   float* __restrict__ cwtab) {
  int r = blockIdx.x, t = threadIdx.x;
  __shared__ float e[HID];
  e[t] = Et[r * HID + t];
  __syncthreads();
  float acc = 0.f;
  #pragma unroll 4
  for (int k = 0; k < HID; ++k) acc += e[k] * Win[k * HID + t];
  Htab[r * HID + t] = acc;
  if (t == 0) {
    float v[Cc];
    float mx = -1e30f;
    for (int c = 0; c < Cc; ++c) { v[c] = Wch[r * Cc + c]; mx = fmaxf(mx, v[c]); }
    float s = 0.f;
    for (int c = 0; c < Cc; ++c) { v[c] = __expf(v[c] - mx); s += v[c]; }
    float inv = 1.0f / s;
    for (int c = 0; c < Cc; ++c) cwtab[r * Cc + c] = v[c] * inv;
  }
}

// h[n] = Htab[S[n]]
__global__ void gather_kernel(const int* __restrict__ S, const float* __restrict__ Htab,
                              float* __restrict__ h) {
  int stride = gridDim.x * blockDim.x;
  for (int i = blockIdx.x * blockDim.x + threadIdx.x; i < Nn * HID; i += stride)
    h[i] = Htab[clampi(S[i >> 7], NCLS) * HID + (i & 127)];
}

// ---------------------------------------------------------------------------
// kNN on channel-1 coords, per complex; stable tie-break (lower index first)
// ---------------------------------------------------------------------------
__global__ __launch_bounds__(256) void knn_kernel(const float* __restrict__ X,
                                                  int* __restrict__ nbr) {
  __shared__ float pos[Lc * 3];
  constexpr int bpc = (Lc + 255) / 256;
  int comp = blockIdx.x / bpc, rb = blockIdx.x % bpc;
  int t = threadIdx.x;
  for (int i = t; i < Lc; i += 256) {
    size_t g = (size_t)(comp * Lc + i) * X3;
    pos[i * 3 + 0] = X[g + 3];
    pos[i * 3 + 1] = X[g + 4];
    pos[i * 3 + 2] = X[g + 5];
  }
  __syncthreads();
  int r = rb * 256 + t;
  if (r >= Lc) return;
  float px = pos[r * 3], py = pos[r * 3 + 1], pz = pos[r * 3 + 2];
  float bd[Kc];
  int   bi[Kc];
  #pragma unroll
  for (int k = 0; k < Kc; ++k) { bd[k] = 1e30f; bi[k] = 0; }
  for (int i = 0; i < Lc; ++i) {
    float dx = px - pos[i * 3], dy = py - pos[i * 3 + 1], dz = pz - pos[i * 3 + 2];
    float d2 = dx * dx + dy * dy + dz * dz;
    if (i == r) continue;
    if (d2 < bd[Kc - 1]) {
      bd[Kc - 1] = d2; bi[Kc - 1] = i;
      #pragma unroll
      for (int p = Kc - 1; p > 0; --p) {
        if (bd[p] < bd[p - 1]) {
          float td = bd[p]; bd[p] = bd[p - 1]; bd[p - 1] = td;
          int   ti = bi[p]; bi[p] = bi[p - 1]; bi[p - 1] = ti;
        }
      }
    }
  }
  int g = comp * Lc + r;
  #pragma unroll
  for (int k = 0; k < Kc; ++k) nbr[g * Kc + k] = comp * Lc + bi[k];
}

// ---------------------------------------------------------------------------
// Per-node: hA = h@We1[0:128,:] + be1, hB = h@We1[128:256,:]  (bf16 out)
// ---------------------------------------------------------------------------
__global__ __launch_bounds__(128) void nodeAB_kernel(const float* __restrict__ h,
                                                     const float* __restrict__ We1,
                                                     const float* __restrict__ be1,
                                                     bf16* __restrict__ hA,
                                                     bf16* __restrict__ hB) {
  __shared__ float sh[8 * HID];
  int tid = threadIdx.x, n0 = blockIdx.x * 8;
  for (int o = tid; o < 8 * HID; o += 128) sh[o] = h[(size_t)n0 * HID + o];
  __syncthreads();
  float a[8], b[8];
  #pragma unroll
  for (int g = 0; g < 8; ++g) { a[g] = 0.f; b[g] = 0.f; }
  for (int j = 0; j < HID; ++j) {
    float wa = We1[j * HID + tid];
    float wb = We1[(HID + j) * HID + tid];
    #pragma unroll
    for (int g = 0; g < 8; ++g) {
      float x = sh[g * HID + j];
      a[g] += x * wa;
      b[g] += x * wb;
    }
  }
  float be = be1[tid];
  #pragma unroll
  for (int g = 0; g < 8; ++g) {
    hA[(size_t)(n0 + g) * HID + tid] = __float2bfloat16(a[g] + be);
    hB[(size_t)(n0 + g) * HID + tid] = __float2bfloat16(b[g]);
  }
}

// ---------------------------------------------------------------------------
// MFMA edge kernel: 4 nodes / 36 edges (pad M=48), 256 threads = 4 waves.
// Wave w owns N-cols [32w, 32w+32) (2 N-tiles) for stages 1-3.
// Activations live in LDS in A-fragment-linear order (contiguous b128 reads);
// weights pre-shuffled to B-fragment-linear bf16 in ws (coalesced loads).
// Pad rows propagate exact zeros (silu(0)=0), so no guards in the GEMMs.
// ---------------------------------------------------------------------------
constexpr int GN  = 4;
constexpr int NE  = GN * Kc;     // 36
constexpr int MT3 = 3;           // m-tiles (M padded to 48)

__global__ __launch_bounds__(256) void edge_kernel(
    const float* __restrict__ Xin, float* __restrict__ Xout,
    const bf16* __restrict__ hA, const bf16* __restrict__ hB,
    const int* __restrict__ S, const float* __restrict__ cwtab,
    const int* __restrict__ nbr,
    const unsigned short* __restrict__ Wrp_s, const unsigned short* __restrict__ We2_s,
    const unsigned short* __restrict__ Wx1_s, const unsigned short* __restrict__ Wx2_s,
    bf16* __restrict__ aggm) {
  __shared__ __align__(16) unsigned short s_R1[48 * 224];  // rad(KT=7) / t2(KT=4), 21504 B
  __shared__ __align__(16) unsigned short s_R2[48 * 128];  // v1 / m / coef(f32), 12288 B
  __shared__ __align__(16) unsigned short s_xd[NE * 44];   // bf16 xd, 3168 B
  __shared__ __align__(16) unsigned short s_hB[NE * 130];  // gathered hB rows, 9360 B
  __shared__ __align__(16) unsigned short s_hA[GN * 128];  // 1024 B
  __shared__ float s_cw[GN * Cc];
  __shared__ int   s_dst[NE];

  int t = threadIdx.x;
  int n0 = blockIdx.x * GN;
  int lane = t & 63, wv = t >> 6;
  int quad = lane >> 4, l15 = lane & 15;
  int wnb = wv << 5;              // wave N-col base

  // ---- staging phase 0: dst, cw, zero R1/R2, hA copy ----
  if (t < NE) s_dst[t] = clampi(nbr[n0 * Kc + t], Nn);
  if (t >= 64 && t < 64 + GN * Cc) {
    int o = t - 64;
    s_cw[o] = cwtab[clampi(S[n0 + o / Cc], NCLS) * Cc + o % Cc];
  }
  {
    unsigned int* r1 = (unsigned int*)s_R1;
    for (int o = t; o < 48 * 112; o += 256) r1[o] = 0u;
    unsigned int* r2 = (unsigned int*)s_R2;
    for (int o = t; o < 48 * 64; o += 256) r2[o] = 0u;
    const unsigned int* src = (const unsigned int*)(hA + (size_t)n0 * HID);
    unsigned int* dA = (unsigned int*)s_hA;
    for (int o = t; o < GN * 64; o += 256) dA[o] = src[o];
  }
  __syncthreads();

  // ---- staging phase 1: xd (bf16) and hB row gather ----
  for (int o = t; o < NE * X3; o += 256) {
    int e = o / X3, i = o - e * X3;
    float v = Xin[(size_t)(n0 + e / Kc) * X3 + i] - Xin[(size_t)s_dst[e] * X3 + i];
    s_xd[e * 44 + i] = f2bu(v);
  }
  {
    unsigned int* d = (unsigned int*)s_hB;  // row stride 130 shorts = 65 uints
    const unsigned int* hb = (const unsigned int*)hB;
    for (int o = t; o < NE * 64; o += 256) {
      int e = o >> 6, w = o & 63;
      d[e * 65 + w] = hb[(size_t)s_dst[e] * 64 + w];
    }
  }
  __syncthreads();

  // ---- rad -> R1 fragment-linear bf16 (pad rows stay 0) ----
  for (int o = t; o < NE * CC; o += 256) {
    int e = o / CC, j = o - e * CC;
    int c = j / Cc, d = j - c * Cc;
    const unsigned short* xe = s_xd + e * 44;
    float v = (b2fu(xe[c * 3 + 0]) * b2fu(xe[d * 3 + 0]) +
               b2fu(xe[c * 3 + 1]) * b2fu(xe[d * 3 + 1]) +
               b2fu(xe[c * 3 + 2]) * b2fu(xe[d * 3 + 2])) * (1.0f / 14.0f);
    s_R1[fragoff(e, j, MT3)] = f2bu(v);
  }
  __syncthreads();

  // ---- stage 1: acc1 = rad @ Wrp  (K=224, KT=7) ----
  f32x4 acc1[MT3][2];
  #pragma unroll
  for (int mt = 0; mt < MT3; ++mt)
    #pragma unroll
    for (int nl = 0; nl < 2; ++nl) acc1[mt][nl] = (f32x4){0.f, 0.f, 0.f, 0.f};
  const sh8* r1v = (const sh8*)s_R1;
  for (int kt = 0; kt < 7; ++kt) {
    sh8 b0 = ((const sh8*)Wrp_s)[((kt << 3) + (wv << 1) + 0) * 64 + lane];
    sh8 b1 = ((const sh8*)Wrp_s)[((kt << 3) + (wv << 1) + 1) * 64 + lane];
    #pragma unroll
    for (int mt = 0; mt < MT3; ++mt) {
      sh8 a = r1v[(kt * MT3 + mt) * 64 + lane];
      acc1[mt][0] = mfma16(a, b0, acc1[mt][0]);
      acc1[mt][1] = mfma16(a, b1, acc1[mt][1]);
    }
  }
  // v1 epilogue: silu(acc + hA[src] + hB[dst]) -> R2 frag order (real rows only)
  #pragma unroll
  for (int mt = 0; mt < MT3; ++mt)
    #pragma unroll
    for (int nl = 0; nl < 2; ++nl) {
      int col = wnb + (nl << 4) + l15;
      #pragma unroll
      for (int r = 0; r < 4; ++r) {
        int row = (mt << 4) + (quad << 2) + r;
        if (row < NE) {
          float v = acc1[mt][nl][r] + b2fu(s_hA[((row / Kc) << 7) + col]) +
                    b2fu(s_hB[row * 130 + col]);
          s_R2[fragoff(row, col, MT3)] = f2bu(siluf(v));
        }
      }
    }
  __syncthreads();

  // ---- stage 2: acc2 = v1 @ We2 (K=128, KT=4) ----
  f32x4 acc2[MT3][2];
  #pragma unroll
  for (int mt = 0; mt < MT3; ++mt)
    #pragma unroll
    for (int nl = 0; nl < 2; ++nl) acc2[mt][nl] = (f32x4){0.f, 0.f, 0.f, 0.f};
  const sh8* r2v = (const sh8*)s_R2;
  for (int kt = 0; kt < 4; ++kt) {
    sh8 b0 = ((const sh8*)We2_s)[((kt << 3) + (wv << 1) + 0) * 64 + lane];
    sh8 b1 = ((const sh8*)We2_s)[((kt << 3) + (wv << 1) + 1) * 64 + lane];
    #pragma unroll
    for (int mt = 0; mt < MT3; ++mt) {
      sh8 a = r2v[(kt * MT3 + mt) * 64 + lane];
      acc2[mt][0] = mfma16(a, b0, acc2[mt][0]);
      acc2[mt][1] = mfma16(a, b1, acc2[mt][1]);
    }
  }
  __syncthreads();   // all v1 reads complete
  // m epilogue: silu(acc2) -> R2 (overwrite v1; pad rows write exact 0)
  #pragma unroll
  for (int mt = 0; mt < MT3; ++mt)
    #pragma unroll
    for (int nl = 0; nl < 2; ++nl) {
      int col = wnb + (nl << 4) + l15;
      #pragma unroll
      for (int r = 0; r < 4; ++r) {
        int row = (mt << 4) + (quad << 2) + r;
        s_R2[fragoff(row, col, MT3)] = f2bu(siluf(acc2[mt][nl][r]));
      }
    }
  __syncthreads();

  // ---- aggm (reads m) + stage 3: acc3 = m @ Wx1 ----
  for (int o = t; o < GN * HID; o += 256) {
    int g = o >> 7, col = o & 127;
    float s = 0.f;
    #pragma unroll
    for (int k = 0; k < Kc; ++k) s += b2fu(s_R2[fragoff(g * Kc + k, col, MT3)]);
    aggm[(size_t)(n0 + g) * HID + col] = __float2bfloat16(s);
  }
  f32x4 acc3[MT3][2];
  #pragma unroll
  for (int mt = 0; mt < MT3; ++mt)
    #pragma unroll
    for (int nl = 0; nl < 2; ++nl) acc3[mt][nl] = (f32x4){0.f, 0.f, 0.f, 0.f};
  for (int kt = 0; kt < 4; ++kt) {
    sh8 b0 = ((const sh8*)Wx1_s)[((kt << 3) + (wv << 1) + 0) * 64 + lane];
    sh8 b1 = ((const sh8*)Wx1_s)[((kt << 3) + (wv << 1) + 1) * 64 + lane];
    #pragma unroll
    for (int mt = 0; mt < MT3; ++mt) {
      sh8 a = r2v[(kt * MT3 + mt) * 64 + lane];
      acc3[mt][0] = mfma16(a, b0, acc3[mt][0]);
      acc3[mt][1] = mfma16(a, b1, acc3[mt][1]);
    }
  }
  // t2 epilogue -> R1 frag order (rad dead since stage 1; covers all rows/kt<4)
  #pragma unroll
  for (int mt = 0; mt < MT3; ++mt)
    #pragma unroll
    for (int nl = 0; nl < 2; ++nl) {
      int col = wnb + (nl << 4) + l15;
      #pragma unroll
      for (int r = 0; r < 4; ++r) {
        int row = (mt << 4) + (quad << 2) + r;
        s_R1[fragoff(row, col, MT3)] = f2bu(siluf(acc3[mt][nl][r]));
      }
    }
  __syncthreads();

  // ---- stage 4 (wave 0 only): coef = t2 @ Wx2 (N padded to 16, NT=1) ----
  float* s_coef = (float*)s_R2;   // 48*16 f32 = 3072 B (m dead)
  if (wv == 0) {
    f32x4 a4[MT3];
    #pragma unroll
    for (int mt = 0; mt < MT3; ++mt) a4[mt] = (f32x4){0.f, 0.f, 0.f, 0.f};
    for (int kt = 0; kt < 4; ++kt) {
      sh8 b = ((const sh8*)Wx2_s)[kt * 64 + lane];
      #pragma unroll
      for (int mt = 0; mt < MT3; ++mt) {
        sh8 a = r1v[(kt * MT3 + mt) * 64 + lane];
        a4[mt] = mfma16(a, b, a4[mt]);
      }
    }
    #pragma unroll
    for (int mt = 0; mt < MT3; ++mt)
      #pragma unroll
      for (int r = 0; r < 4; ++r) {
        int row = (mt << 4) + (quad << 2) + r;
        s_coef[(row << 4) + l15] = a4[mt][r];
      }
  }
  __syncthreads();

  // ---- stage 5: X_out = X_in + (sum_k xd*coef)*cw/K ----
  for (int o = t; o < GN * X3; o += 256) {
    int g = o / X3, rem = o - g * X3, c = rem / 3;
    float s = 0.f;
    #pragma unroll
    for (int k = 0; k < Kc; ++k) {
      int e = g * Kc + k;
      s += b2fu(s_xd[e * 44 + rem]) * s_coef[(e << 4) + c];
    }
    int gn = n0 + g;
    Xout[(size_t)gn * X3 + rem] =
        Xin[(size_t)gn * X3 + rem] + s * s_cw[g * Cc + c] * (1.0f / 9.0f);
  }
}

// ---------------------------------------------------------------------------
// Node update: h += silu(cat(h,aggm) @ Wh1) @ Wh2
// ---------------------------------------------------------------------------
__global__ __launch_bounds__(128) void nodeupd_kernel(float* __restrict__ h,
                                                      const bf16* __restrict__ aggm,
                                                      const float* __restrict__ Wh1,
                                                      const float* __restrict__ Wh2) {
  __shared__ float cat[8 * 256];
  __shared__ float u[8 * HID];
  int tid = threadIdx.x, n0 = blockIdx.x * 8;
  for (int o = tid; o < 8 * HID; o += 128) {
    int g = o >> 7, j = o & 127;
    cat[g * 256 + j] = h[(size_t)n0 * HID + o];
    cat[g * 256 + HID + j] = b2f(aggm[(size_t)n0 * HID + o]);
  }
  __syncthreads();
  float acc[8];
  #pragma unroll
  for (int g = 0; g < 8; ++g) acc[g] = 0.f;
  for (int j = 0; j < 256; ++j) {
    float w = Wh1[j * HID + tid];
    #pragma unroll
    for (int g = 0; g < 8; ++g) acc[g] += cat[g * 256 + j] * w;
  }
  #pragma unroll
  for (int g = 0; g < 8; ++g) u[g * HID + tid] = siluf(acc[g]);
  __syncthreads();
  float acc2[8];
  #pragma unroll
  for (int g = 0; g < 8; ++g) acc2[g] = 0.f;
  for (int j = 0; j < HID; ++j) {
    float w = Wh2[j * HID + tid];
    #pragma unroll
    for (int g = 0; g < 8; ++g) acc2[g] += u[g * HID + j] * w;
  }
  #pragma unroll
  for (int g = 0; g < 8; ++g) h[(size_t)(n0 + g) * HID + tid] += acc2[g];
}

// ---------------------------------------------------------------------------
// Final FFN: logits = silu(silu(h)@Wf1)@Wf2 -> f32 out
// ---------------------------------------------------------------------------
__global__ __launch_bounds__(128) void final_kernel(const float* __restrict__ h,
                                                    const float* __restrict__ Wf1,
                                                    const float* __restrict__ Wf2,
                                                    float* __restrict__ out) {
  __shared__ float sh[8 * HID];
  __shared__ float u[8 * HID];
  int tid = threadIdx.x, n0 = blockIdx.x * 8;
  for (int o = tid; o < 8 * HID; o += 128) sh[o] = siluf(h[(size_t)n0 * HID + o]);
  __syncthreads();
  float acc[8];
  #pragma unroll
  for (int g = 0; g < 8; ++g) acc[g] = 0.f;
  for (int j = 0; j < HID; ++j) {
    float w = Wf1[j * HID + tid];
    #pragma unroll
    for (int g = 0; g < 8; ++g) acc[g] += sh[g * HID + j] * w;
  }
  #pragma unroll
  for (int g = 0; g < 8; ++g) u[g * HID + tid] = siluf(acc[g]);
  __syncthreads();
  for (int o = tid; o < 8 * NCLS; o += 128) {
    int g = o / NCLS, c = o - g * NCLS;
    float s = 0.f;
    #pragma unroll 4
    for (int j = 0; j < HID; ++j) s += u[g * HID + j] * Wf2[j * NCLS + c];
    out[(size_t)(n0 + g) * NCLS + c] = s;
  }
}

__global__ void xout_kernel(const float* __restrict__ Xf, float* __restrict__ out) {
  for (int i = blockIdx.x * blockDim.x + threadIdx.x; i < Nn * X3;
       i += gridDim.x * blockDim.x)
    out[i] = Xf[i];
}

// ---------------------------------------------------------------------------
extern "C" void kernel_launch(void* const* d_in, const int* in_sizes, int n_in,
                              void* d_out, int out_size, void* d_ws, size_t ws_size,
                              hipStream_t stream) {
  const float* X    = (const float*)d_in[0];
  const int*   S    = (const int*)d_in[1];
  const float* Etab = (const float*)d_in[2];
  const float* Wch  = (const float*)d_in[3];
  const float* Win  = (const float*)d_in[4];
  const float* Wr   = (const float*)d_in[5];
  const float* We1  = (const float*)d_in[6];
  const float* be1  = (const float*)d_in[7];
  const float* We2  = (const float*)d_in[8];
  const float* Wx1  = (const float*)d_in[9];
  const float* Wx2  = (const float*)d_in[10];
  const float* Wh1  = (const float*)d_in[11];
  const float* Wh2  = (const float*)d_in[12];
  const float* Wf1  = (const float*)d_in[13];
  const float* Wf2  = (const float*)d_in[14];
  (void)in_sizes; (void)n_in; (void)out_size; (void)ws_size;

  char* base = (char*)d_ws;
  size_t off = 0;
  auto alloc = [&](size_t bytes) {
    void* p = base + off;
    off += (bytes + 255) & ~(size_t)255;
    return p;
  };
  int*   nbr   = (int*)  alloc((size_t)Nn * Kc * 4);
  float* Htab  = (float*)alloc(NCLS * HID * 4);
  float* cwtab = (float*)alloc(NCLS * Cc * 4);
  float* Wrpf  = (float*)alloc((size_t)NL * CC * HID * 4);
  float* Xa    = (float*)alloc((size_t)Nn * X3 * 4);
  float* Xb    = (float*)alloc((size_t)Nn * X3 * 4);
  float* hv    = (float*)alloc((size_t)Nn * HID * 4);
  bf16*  hAv   = (bf16*) alloc((size_t)Nn * HID * 2);
  bf16*  hBv   = (bf16*) alloc((size_t)Nn * HID * 2);
  bf16*  aggmv = (bf16*) alloc((size_t)Nn * HID * 2);
  // shuffled bf16 weight fragments
  constexpr int WRP_SZ = 7 * 8 * 512;   // 28672 shorts / layer
  constexpr int W128_SZ = 4 * 8 * 512;  // 16384
  constexpr int WX2_SZ = 4 * 1 * 512;   // 2048
  unsigned short* Wrp_s = (unsigned short*)alloc((size_t)NL * WRP_SZ * 2);
  unsigned short* We2_s = (unsigned short*)alloc((size_t)NL * W128_SZ * 2);
  unsigned short* Wx1_s = (unsigned short*)alloc((size_t)NL * W128_SZ * 2);
  unsigned short* Wx2_s = (unsigned short*)alloc((size_t)NL * WX2_SZ * 2);

  wrp_kernel<<<NL * CC, 128, 0, stream>>>(Wr, We1, Wrpf);
  htab_kernel<<<NCLS, 128, 0, stream>>>(Etab, Win, Wch, Htab, cwtab);
  gather_kernel<<<512, 256, 0, stream>>>(S, Htab, hv);
  knn_kernel<<<Bc * ((Lc + 255) / 256), 256, 0, stream>>>(X, nbr);

  for (int l = 0; l < NL; ++l) {
    shuf_kernel<<<32, 256, 0, stream>>>(Wrpf + (size_t)l * CC * HID,
                                        Wrp_s + (size_t)l * WRP_SZ, CC, HID, 7, 8);
    shuf_kernel<<<16, 256, 0, stream>>>(We2 + (size_t)l * HID * HID,
                                        We2_s + (size_t)l * W128_SZ, HID, HID, 4, 8);
    shuf_kernel<<<16, 256, 0, stream>>>(Wx1 + (size_t)l * HID * HID,
                                        Wx1_s + (size_t)l * W128_SZ, HID, HID, 4, 8);
    shuf_kernel<<<4, 256, 0, stream>>>(Wx2 + (size_t)l * HID * Cc,
                                       Wx2_s + (size_t)l * WX2_SZ, HID, Cc, 4, 1);
  }

  // X ping-pong: layer0 reads the input directly
  const float* Xi = X;
  float* Xo = Xb;
  for (int l = 0; l < NL; ++l) {
    nodeAB_kernel<<<Nn / 8, 128, 0, stream>>>(hv, We1 + (size_t)l * 384 * HID,
                                              be1 + l * HID, hAv, hBv);
    edge_kernel<<<Nn / GN, 256, 0, stream>>>(
        Xi, Xo, hAv, hBv, S, cwtab, nbr,
        Wrp_s + (size_t)l * WRP_SZ, We2_s + (size_t)l * W128_SZ,
        Wx1_s + (size_t)l * W128_SZ, Wx2_s + (size_t)l * WX2_SZ, aggmv);
    nodeupd_kernel<<<Nn / 8, 128, 0, stream>>>(hv, aggmv, Wh1 + (size_t)l * 256 * HID,
                                               Wh2 + (size_t)l * HID * HID);
    Xi = Xo;
    Xo = (Xo == Xb) ? Xa : Xb;
  }

  float* out = (float*)d_out;
  final_kernel<<<Nn / 8, 128, 0, stream>>>(hv, Wf1, Wf2, out);
  xout_kernel<<<512, 256, 0, stream>>>(Xi, out + (size_t)Nn * NCLS);
}

// Round 9
// 1029.975 us; speedup vs baseline: 3.0233x; 1.1979x over previous
//
#include <hip/hip_runtime.h>
#include <hip/hip_bf16.h>

typedef __hip_bfloat16 bf16;

// Problem constants
constexpr int Bc  = 8;
constexpr int Lc  = 2500;
constexpr int Cc  = 14;
constexpr int Kc  = 9;
constexpr int Nn  = Bc * Lc;     // 20000
constexpr int NCLS = 20;
constexpr int HID = 128;
constexpr int NL  = 3;
constexpr int CC  = Cc * Cc;     // 196
constexpr int X3  = Cc * 3;      // 42

typedef __bf16 bf16x8 __attribute__((ext_vector_type(8)));
typedef short  sh8    __attribute__((ext_vector_type(8)));
typedef float  f32x4  __attribute__((ext_vector_type(4)));

__device__ __forceinline__ float b2f(bf16 x) { return __bfloat162float(x); }
__device__ __forceinline__ float b2fu(unsigned short u) {
  return __uint_as_float(((unsigned int)u) << 16);
}
__device__ __forceinline__ unsigned short f2bu(float x) {
  bf16 h = __float2bfloat16(x);
  return *reinterpret_cast<unsigned short*>(&h);
}
__device__ __forceinline__ float siluf(float x) { return x / (1.0f + __expf(-x)); }
__device__ __forceinline__ int clampi(int v, int n) {
  return ((unsigned)v < (unsigned)n) ? v : 0;
}

__device__ __forceinline__ f32x4 mfma16(sh8 a, sh8 b, f32x4 c) {
  return __builtin_amdgcn_mfma_f32_16x16x32_bf16(
      __builtin_bit_cast(bf16x8, a), __builtin_bit_cast(bf16x8, b), c, 0, 0, 0);
}

// A/activation fragment-linear offset (in shorts). MT m-tiles; tile = 512 shorts.
// value (row e, col k) lives at tile (k/32, e/16), lane (e%16)+((k%32)/8)*16, j=k%8.
__device__ __forceinline__ int fragoff(int e, int k, int MT) {
  return (((k >> 5) * MT + (e >> 4)) << 9) +
         (((e & 15) + (((k >> 3) & 3) << 4)) << 3) + (k & 7);
}

// ---------------------------------------------------------------------------
// Wrp[l] = Wr[l] @ We1[l][256:384,:]  (fp32, fold radial proj into edge MLP)
// ---------------------------------------------------------------------------
__global__ __launch_bounds__(128) void wrp_kernel(const float* __restrict__ Wr,
                                                  const float* __restrict__ We1,
                                                  float* __restrict__ Wrp) {
  int l = blockIdx.x / CC, j = blockIdx.x % CC;
  int t = threadIdx.x;
  __shared__ float row[HID];
  row[t] = Wr[(size_t)(l * CC + j) * HID + t];
  __syncthreads();
  float acc = 0.f;
  #pragma unroll 4
  for (int k = 0; k < HID; ++k)
    acc += row[k] * We1[(size_t)(l * 384 + 256 + k) * HID + t];
  Wrp[(size_t)(l * CC + j) * HID + t] = acc;
}

// Shuffle fp32 K x N weight into B-fragment-linear bf16 (zero-padded).
// out[((kt*NT+nt)*64+lane)*8+j] = W[kt*32+(lane>>4)*8+j][nt*16+(lane&15)]
__global__ void shuf_kernel(const float* __restrict__ W, unsigned short* __restrict__ out,
                            int K, int N, int KT, int NT) {
  int total = KT * NT * 512;
  for (int idx = blockIdx.x * blockDim.x + threadIdx.x; idx < total;
       idx += gridDim.x * blockDim.x) {
    int j = idx & 7;
    int lane = (idx >> 3) & 63;
    int nt = (idx >> 9) % NT;
    int kt = idx / (512 * NT);
    int k = kt * 32 + ((lane >> 4) << 3) + j;
    int n = nt * 16 + (lane & 15);
    float v = (k < K && n < N) ? W[(size_t)k * N + n] : 0.f;
    out[idx] = f2bu(v);
  }
}

// Htab = E_tab @ Win (20x128); cwtab = row-softmax(Wchan) (20x14)
__global__ __launch_bounds__(128) void htab_kernel(const float* __restrict__ Et,
                                                   const float* __restrict__ Win,
                                                   const float* __restrict__ Wch,
                                                   float* __restrict__ Htab,
                                                   float* __restrict__ cwtab) {
  int r = blockIdx.x, t = threadIdx.x;
  __shared__ float e[HID];
  e[t] = Et[r * HID + t];
  __syncthreads();
  float acc = 0.f;
  #pragma unroll 4
  for (int k = 0; k < HID; ++k) acc += e[k] * Win[k * HID + t];
  Htab[r * HID + t] = acc;
  if (t == 0) {
    float v[Cc];
    float mx = -1e30f;
    for (int c = 0; c < Cc; ++c) { v[c] = Wch[r * Cc + c]; mx = fmaxf(mx, v[c]); }
    float s = 0.f;
    for (int c = 0; c < Cc; ++c) { v[c] = __expf(v[c] - mx); s += v[c]; }
    float inv = 1.0f / s;
    for (int c = 0; c < Cc; ++c) cwtab[r * Cc + c] = v[c] * inv;
  }
}

// h[n] = Htab[S[n]]
__global__ void gather_kernel(const int* __restrict__ S, const float* __restrict__ Htab,
                              float* __restrict__ h) {
  int stride = gridDim.x * blockDim.x;
  for (int i = blockIdx.x * blockDim.x + threadIdx.x; i < Nn * HID; i += stride)
    h[i] = Htab[clampi(S[i >> 7], NCLS) * HID + (i & 127)];
}

// ---------------------------------------------------------------------------
// kNN, parallelized: 32 rows/block, 8 threads per row (313 candidates each),
// private top-9 per subset, then stable lexicographic (d2, idx) 8-way merge.
// Subsets are contiguous increasing index ranges -> merge reproduces jax
// top_k's stable tie-break exactly.
// ---------------------------------------------------------------------------
constexpr int KROWS = 32;
constexpr int KSUB  = 8;
constexpr int KCH   = (Lc + KSUB - 1) / KSUB;   // 313

__global__ __launch_bounds__(256) void knn_kernel(const float* __restrict__ X,
                                                  int* __restrict__ nbr) {
  __shared__ float pos[Lc * 3];                 // 30000 B
  __shared__ float s_bd[KROWS * KSUB * Kc];     //  9216 B
  __shared__ int   s_bi[KROWS * KSUB * Kc];     //  9216 B
  constexpr int bpc = (Lc + KROWS - 1) / KROWS; // 79 blocks per complex
  int comp = blockIdx.x / bpc, rb = blockIdx.x % bpc;
  int t = threadIdx.x;
  for (int i = t; i < Lc; i += 256) {
    size_t g = (size_t)(comp * Lc + i) * X3;
    pos[i * 3 + 0] = X[g + 3];
    pos[i * 3 + 1] = X[g + 4];
    pos[i * 3 + 2] = X[g + 5];
  }
  __syncthreads();

  int rl = t >> 3, q = t & 7;
  int r = rb * KROWS + rl;
  float bd[Kc];
  int   bi[Kc];
  #pragma unroll
  for (int k = 0; k < Kc; ++k) { bd[k] = 1e30f; bi[k] = 0x7fffffff; }
  if (r < Lc) {
    float px = pos[r * 3], py = pos[r * 3 + 1], pz = pos[r * 3 + 2];
    int i0 = q * KCH;
    int i1 = i0 + KCH; if (i1 > Lc) i1 = Lc;
    for (int i = i0; i < i1; ++i) {
      float dx = px - pos[i * 3], dy = py - pos[i * 3 + 1], dz = pz - pos[i * 3 + 2];
      float d2 = dx * dx + dy * dy + dz * dz;
      if (i == r) continue;
      if (d2 < bd[Kc - 1]) {
        bd[Kc - 1] = d2; bi[Kc - 1] = i;
        #pragma unroll
        for (int p = Kc - 1; p > 0; --p) {
          if (bd[p] < bd[p - 1]) {
            float td = bd[p]; bd[p] = bd[p - 1]; bd[p - 1] = td;
            int   ti = bi[p]; bi[p] = bi[p - 1]; bi[p - 1] = ti;
          }
        }
      }
    }
  }
  #pragma unroll
  for (int k = 0; k < Kc; ++k) {
    s_bd[(rl * KSUB + q) * Kc + k] = bd[k];
    s_bi[(rl * KSUB + q) * Kc + k] = bi[k];
  }
  __syncthreads();

  if (t < KROWS) {
    int r2 = rb * KROWS + t;
    if (r2 < Lc) {
      int p[KSUB];
      #pragma unroll
      for (int qq = 0; qq < KSUB; ++qq) p[qq] = 0;
      int gbase = (comp * Lc + r2) * Kc;
      #pragma unroll
      for (int k = 0; k < Kc; ++k) {
        float bestd = 1e30f;
        int   besti = 0x7fffffff, bq = 0;
        #pragma unroll
        for (int qq = 0; qq < KSUB; ++qq) {
          if (p[qq] < Kc) {
            float d = s_bd[(t * KSUB + qq) * Kc + p[qq]];
            int   ix = s_bi[(t * KSUB + qq) * Kc + p[qq]];
            if (d < bestd || (d == bestd && ix < besti)) {
              bestd = d; besti = ix; bq = qq;
            }
          }
        }
        p[bq]++;
        nbr[gbase + k] = comp * Lc + besti;
      }
    }
  }
}

// ---------------------------------------------------------------------------
// Per-node: hA = h@We1[0:128,:] + be1, hB = h@We1[128:256,:]  (bf16 out)
// ---------------------------------------------------------------------------
__global__ __launch_bounds__(128) void nodeAB_kernel(const float* __restrict__ h,
                                                     const float* __restrict__ We1,
                                                     const float* __restrict__ be1,
                                                     bf16* __restrict__ hA,
                                                     bf16* __restrict__ hB) {
  __shared__ float sh[8 * HID];
  int tid = threadIdx.x, n0 = blockIdx.x * 8;
  for (int o = tid; o < 8 * HID; o += 128) sh[o] = h[(size_t)n0 * HID + o];
  __syncthreads();
  float a[8], b[8];
  #pragma unroll
  for (int g = 0; g < 8; ++g) { a[g] = 0.f; b[g] = 0.f; }
  for (int j = 0; j < HID; ++j) {
    float wa = We1[j * HID + tid];
    float wb = We1[(HID + j) * HID + tid];
    #pragma unroll
    for (int g = 0; g < 8; ++g) {
      float x = sh[g * HID + j];
      a[g] += x * wa;
      b[g] += x * wb;
    }
  }
  float be = be1[tid];
  #pragma unroll
  for (int g = 0; g < 8; ++g) {
    hA[(size_t)(n0 + g) * HID + tid] = __float2bfloat16(a[g] + be);
    hB[(size_t)(n0 + g) * HID + tid] = __float2bfloat16(b[g]);
  }
}

// ---------------------------------------------------------------------------
// MFMA edge kernel: 4 nodes / 36 edges (pad M=48), 256 threads = 4 waves.
// Wave w owns N-cols [32w, 32w+32) (2 N-tiles) for stages 1-3.
// Activations live in LDS in A-fragment-linear order (contiguous b128 reads);
// weights pre-shuffled to B-fragment-linear bf16 in ws (coalesced loads).
// Pad rows propagate exact zeros (silu(0)=0), so no guards in the GEMMs.
// ---------------------------------------------------------------------------
constexpr int GN  = 4;
constexpr int NE  = GN * Kc;     // 36
constexpr int MT3 = 3;           // m-tiles (M padded to 48)

__global__ __launch_bounds__(256) void edge_kernel(
    const float* __restrict__ Xin, float* __restrict__ Xout,
    const bf16* __restrict__ hA, const bf16* __restrict__ hB,
    const int* __restrict__ S, const float* __restrict__ cwtab,
    const int* __restrict__ nbr,
    const unsigned short* __restrict__ Wrp_s, const unsigned short* __restrict__ We2_s,
    const unsigned short* __restrict__ Wx1_s, const unsigned short* __restrict__ Wx2_s,
    bf16* __restrict__ aggm) {
  __shared__ __align__(16) unsigned short s_R1[48 * 224];  // rad(KT=7) / t2(KT=4), 21504 B
  __shared__ __align__(16) unsigned short s_R2[48 * 128];  // v1 / m / coef(f32), 12288 B
  __shared__ __align__(16) unsigned short s_xd[NE * 44];   // bf16 xd, 3168 B
  __shared__ __align__(16) unsigned short s_hB[NE * 130];  // gathered hB rows, 9360 B
  __shared__ __align__(16) unsigned short s_hA[GN * 128];  // 1024 B
  __shared__ float s_cw[GN * Cc];
  __shared__ int   s_dst[NE];

  int t = threadIdx.x;
  int n0 = blockIdx.x * GN;
  int lane = t & 63, wv = t >> 6;
  int quad = lane >> 4, l15 = lane & 15;
  int wnb = wv << 5;              // wave N-col base

  // ---- staging phase 0: dst, cw, zero R1/R2, hA copy ----
  if (t < NE) s_dst[t] = clampi(nbr[n0 * Kc + t], Nn);
  if (t >= 64 && t < 64 + GN * Cc) {
    int o = t - 64;
    s_cw[o] = cwtab[clampi(S[n0 + o / Cc], NCLS) * Cc + o % Cc];
  }
  {
    unsigned int* r1 = (unsigned int*)s_R1;
    for (int o = t; o < 48 * 112; o += 256) r1[o] = 0u;
    unsigned int* r2 = (unsigned int*)s_R2;
    for (int o = t; o < 48 * 64; o += 256) r2[o] = 0u;
    const unsigned int* src = (const unsigned int*)(hA + (size_t)n0 * HID);
    unsigned int* dA = (unsigned int*)s_hA;
    for (int o = t; o < GN * 64; o += 256) dA[o] = src[o];
  }
  __syncthreads();

  // ---- staging phase 1: xd (bf16) and hB row gather ----
  for (int o = t; o < NE * X3; o += 256) {
    int e = o / X3, i = o - e * X3;
    float v = Xin[(size_t)(n0 + e / Kc) * X3 + i] - Xin[(size_t)s_dst[e] * X3 + i];
    s_xd[e * 44 + i] = f2bu(v);
  }
  {
    unsigned int* d = (unsigned int*)s_hB;  // row stride 130 shorts = 65 uints
    const unsigned int* hb = (const unsigned int*)hB;
    for (int o = t; o < NE * 64; o += 256) {
      int e = o >> 6, w = o & 63;
      d[e * 65 + w] = hb[(size_t)s_dst[e] * 64 + w];
    }
  }
  __syncthreads();

  // ---- rad -> R1 fragment-linear bf16 (pad rows stay 0) ----
  for (int o = t; o < NE * CC; o += 256) {
    int e = o / CC, j = o - e * CC;
    int c = j / Cc, d = j - c * Cc;
    const unsigned short* xe = s_xd + e * 44;
    float v = (b2fu(xe[c * 3 + 0]) * b2fu(xe[d * 3 + 0]) +
               b2fu(xe[c * 3 + 1]) * b2fu(xe[d * 3 + 1]) +
               b2fu(xe[c * 3 + 2]) * b2fu(xe[d * 3 + 2])) * (1.0f / 14.0f);
    s_R1[fragoff(e, j, MT3)] = f2bu(v);
  }
  __syncthreads();

  // ---- stage 1: acc1 = rad @ Wrp  (K=224, KT=7) ----
  f32x4 acc1[MT3][2];
  #pragma unroll
  for (int mt = 0; mt < MT3; ++mt)
    #pragma unroll
    for (int nl = 0; nl < 2; ++nl) acc1[mt][nl] = (f32x4){0.f, 0.f, 0.f, 0.f};
  const sh8* r1v = (const sh8*)s_R1;
  for (int kt = 0; kt < 7; ++kt) {
    sh8 b0 = ((const sh8*)Wrp_s)[((kt << 3) + (wv << 1) + 0) * 64 + lane];
    sh8 b1 = ((const sh8*)Wrp_s)[((kt << 3) + (wv << 1) + 1) * 64 + lane];
    #pragma unroll
    for (int mt = 0; mt < MT3; ++mt) {
      sh8 a = r1v[(kt * MT3 + mt) * 64 + lane];
      acc1[mt][0] = mfma16(a, b0, acc1[mt][0]);
      acc1[mt][1] = mfma16(a, b1, acc1[mt][1]);
    }
  }
  // v1 epilogue: silu(acc + hA[src] + hB[dst]) -> R2 frag order (real rows only)
  #pragma unroll
  for (int mt = 0; mt < MT3; ++mt)
    #pragma unroll
    for (int nl = 0; nl < 2; ++nl) {
      int col = wnb + (nl << 4) + l15;
      #pragma unroll
      for (int r = 0; r < 4; ++r) {
        int row = (mt << 4) + (quad << 2) + r;
        if (row < NE) {
          float v = acc1[mt][nl][r] + b2fu(s_hA[((row / Kc) << 7) + col]) +
                    b2fu(s_hB[row * 130 + col]);
          s_R2[fragoff(row, col, MT3)] = f2bu(siluf(v));
        }
      }
    }
  __syncthreads();

  // ---- stage 2: acc2 = v1 @ We2 (K=128, KT=4) ----
  f32x4 acc2[MT3][2];
  #pragma unroll
  for (int mt = 0; mt < MT3; ++mt)
    #pragma unroll
    for (int nl = 0; nl < 2; ++nl) acc2[mt][nl] = (f32x4){0.f, 0.f, 0.f, 0.f};
  const sh8* r2v = (const sh8*)s_R2;
  for (int kt = 0; kt < 4; ++kt) {
    sh8 b0 = ((const sh8*)We2_s)[((kt << 3) + (wv << 1) + 0) * 64 + lane];
    sh8 b1 = ((const sh8*)We2_s)[((kt << 3) + (wv << 1) + 1) * 64 + lane];
    #pragma unroll
    for (int mt = 0; mt < MT3; ++mt) {
      sh8 a = r2v[(kt * MT3 + mt) * 64 + lane];
      acc2[mt][0] = mfma16(a, b0, acc2[mt][0]);
      acc2[mt][1] = mfma16(a, b1, acc2[mt][1]);
    }
  }
  __syncthreads();   // all v1 reads complete
  // m epilogue: silu(acc2) -> R2 (overwrite v1; pad rows write exact 0)
  #pragma unroll
  for (int mt = 0; mt < MT3; ++mt)
    #pragma unroll
    for (int nl = 0; nl < 2; ++nl) {
      int col = wnb + (nl << 4) + l15;
      #pragma unroll
      for (int r = 0; r < 4; ++r) {
        int row = (mt << 4) + (quad << 2) + r;
        s_R2[fragoff(row, col, MT3)] = f2bu(siluf(acc2[mt][nl][r]));
      }
    }
  __syncthreads();

  // ---- aggm (reads m) + stage 3: acc3 = m @ Wx1 ----
  for (int o = t; o < GN * HID; o += 256) {
    int g = o >> 7, col = o & 127;
    float s = 0.f;
    #pragma unroll
    for (int k = 0; k < Kc; ++k) s += b2fu(s_R2[fragoff(g * Kc + k, col, MT3)]);
    aggm[(size_t)(n0 + g) * HID + col] = __float2bfloat16(s);
  }
  f32x4 acc3[MT3][2];
  #pragma unroll
  for (int mt = 0; mt < MT3; ++mt)
    #pragma unroll
    for (int nl = 0; nl < 2; ++nl) acc3[mt][nl] = (f32x4){0.f, 0.f, 0.f, 0.f};
  for (int kt = 0; kt < 4; ++kt) {
    sh8 b0 = ((const sh8*)Wx1_s)[((kt << 3) + (wv << 1) + 0) * 64 + lane];
    sh8 b1 = ((const sh8*)Wx1_s)[((kt << 3) + (wv << 1) + 1) * 64 + lane];
    #pragma unroll
    for (int mt = 0; mt < MT3; ++mt) {
      sh8 a = r2v[(kt * MT3 + mt) * 64 + lane];
      acc3[mt][0] = mfma16(a, b0, acc3[mt][0]);
      acc3[mt][1] = mfma16(a, b1, acc3[mt][1]);
    }
  }
  // t2 epilogue -> R1 frag order (rad dead since stage 1; covers all rows/kt<4)
  #pragma unroll
  for (int mt = 0; mt < MT3; ++mt)
    #pragma unroll
    for (int nl = 0; nl < 2; ++nl) {
      int col = wnb + (nl << 4) + l15;
      #pragma unroll
      for (int r = 0; r < 4; ++r) {
        int row = (mt << 4) + (quad << 2) + r;
        s_R1[fragoff(row, col, MT3)] = f2bu(siluf(acc3[mt][nl][r]));
      }
    }
  __syncthreads();

  // ---- stage 4 (wave 0 only): coef = t2 @ Wx2 (N padded to 16, NT=1) ----
  float* s_coef = (float*)s_R2;   // 48*16 f32 = 3072 B (m dead)
  if (wv == 0) {
    f32x4 a4[MT3];
    #pragma unroll
    for (int mt = 0; mt < MT3; ++mt) a4[mt] = (f32x4){0.f, 0.f, 0.f, 0.f};
    for (int kt = 0; kt < 4; ++kt) {
      sh8 b = ((const sh8*)Wx2_s)[kt * 64 + lane];
      #pragma unroll
      for (int mt = 0; mt < MT3; ++mt) {
        sh8 a = r1v[(kt * MT3 + mt) * 64 + lane];
        a4[mt] = mfma16(a, b, a4[mt]);
      }
    }
    #pragma unroll
    for (int mt = 0; mt < MT3; ++mt)
      #pragma unroll
      for (int r = 0; r < 4; ++r) {
        int row = (mt << 4) + (quad << 2) + r;
        s_coef[(row << 4) + l15] = a4[mt][r];
      }
  }
  __syncthreads();

  // ---- stage 5: X_out = X_in + (sum_k xd*coef)*cw/K ----
  for (int o = t; o < GN * X3; o += 256) {
    int g = o / X3, rem = o - g * X3, c = rem / 3;
    float s = 0.f;
    #pragma unroll
    for (int k = 0; k < Kc; ++k) {
      int e = g * Kc + k;
      s += b2fu(s_xd[e * 44 + rem]) * s_coef[(e << 4) + c];
    }
    int gn = n0 + g;
    Xout[(size_t)gn * X3 + rem] =
        Xin[(size_t)gn * X3 + rem] + s * s_cw[g * Cc + c] * (1.0f / 9.0f);
  }
}

// ---------------------------------------------------------------------------
// Node update: h += silu(cat(h,aggm) @ Wh1) @ Wh2
// ---------------------------------------------------------------------------
__global__ __launch_bounds__(128) void nodeupd_kernel(float* __restrict__ h,
                                                      const bf16* __restrict__ aggm,
                                                      const float* __restrict__ Wh1,
                                                      const float* __restrict__ Wh2) {
  __shared__ float cat[8 * 256];
  __shared__ float u[8 * HID];
  int tid = threadIdx.x, n0 = blockIdx.x * 8;
  for (int o = tid; o < 8 * HID; o += 128) {
    int g = o >> 7, j = o & 127;
    cat[g * 256 + j] = h[(size_t)n0 * HID + o];
    cat[g * 256 + HID + j] = b2f(aggm[(size_t)n0 * HID + o]);
  }
  __syncthreads();
  float acc[8];
  #pragma unroll
  for (int g = 0; g < 8; ++g) acc[g] = 0.f;
  for (int j = 0; j < 256; ++j) {
    float w = Wh1[j * HID + tid];
    #pragma unroll
    for (int g = 0; g < 8; ++g) acc[g] += cat[g * 256 + j] * w;
  }
  #pragma unroll
  for (int g = 0; g < 8; ++g) u[g * HID + tid] = siluf(acc[g]);
  __syncthreads();
  float acc2[8];
  #pragma unroll
  for (int g = 0; g < 8; ++g) acc2[g] = 0.f;
  for (int j = 0; j < HID; ++j) {
    float w = Wh2[j * HID + tid];
    #pragma unroll
    for (int g = 0; g < 8; ++g) acc2[g] += u[g * HID + j] * w;
  }
  #pragma unroll
  for (int g = 0; g < 8; ++g) h[(size_t)(n0 + g) * HID + tid] += acc2[g];
}

// ---------------------------------------------------------------------------
// Final FFN: logits = silu(silu(h)@Wf1)@Wf2 -> f32 out
// ---------------------------------------------------------------------------
__global__ __launch_bounds__(128) void final_kernel(const float* __restrict__ h,
                                                    const float* __restrict__ Wf1,
                                                    const float* __restrict__ Wf2,
                                                    float* __restrict__ out) {
  __shared__ float sh[8 * HID];
  __shared__ float u[8 * HID];
  int tid = threadIdx.x, n0 = blockIdx.x * 8;
  for (int o = tid; o < 8 * HID; o += 128) sh[o] = siluf(h[(size_t)n0 * HID + o]);
  __syncthreads();
  float acc[8];
  #pragma unroll
  for (int g = 0; g < 8; ++g) acc[g] = 0.f;
  for (int j = 0; j < HID; ++j) {
    float w = Wf1[j * HID + tid];
    #pragma unroll
    for (int g = 0; g < 8; ++g) acc[g] += sh[g * HID + j] * w;
  }
  #pragma unroll
  for (int g = 0; g < 8; ++g) u[g * HID + tid] = siluf(acc[g]);
  __syncthreads();
  for (int o = tid; o < 8 * NCLS; o += 128) {
    int g = o / NCLS, c = o - g * NCLS;
    float s = 0.f;
    #pragma unroll 4
    for (int j = 0; j < HID; ++j) s += u[g * HID + j] * Wf2[j * NCLS + c];
    out[(size_t)(n0 + g) * NCLS + c] = s;
  }
}

__global__ void xout_kernel(const float* __restrict__ Xf, float* __restrict__ out) {
  for (int i = blockIdx.x * blockDim.x + threadIdx.x; i < Nn * X3;
       i += gridDim.x * blockDim.x)
    out[i] = Xf[i];
}

// ---------------------------------------------------------------------------
extern "C" void kernel_launch(void* const* d_in, const int* in_sizes, int n_in,
                              void* d_out, int out_size, void* d_ws, size_t ws_size,
                              hipStream_t stream) {
  const float* X    = (const float*)d_in[0];
  const int*   S    = (const int*)d_in[1];
  const float* Etab = (const float*)d_in[2];
  const float* Wch  = (const float*)d_in[3];
  const float* Win  = (const float*)d_in[4];
  const float* Wr   = (const float*)d_in[5];
  const float* We1  = (const float*)d_in[6];
  const float* be1  = (const float*)d_in[7];
  const float* We2  = (const float*)d_in[8];
  const float* Wx1  = (const float*)d_in[9];
  const float* Wx2  = (const float*)d_in[10];
  const float* Wh1  = (const float*)d_in[11];
  const float* Wh2  = (const float*)d_in[12];
  const float* Wf1  = (const float*)d_in[13];
  const float* Wf2  = (const float*)d_in[14];
  (void)in_sizes; (void)n_in; (void)out_size; (void)ws_size;

  char* base = (char*)d_ws;
  size_t off = 0;
  auto alloc = [&](size_t bytes) {
    void* p = base + off;
    off += (bytes + 255) & ~(size_t)255;
    return p;
  };
  int*   nbr   = (int*)  alloc((size_t)Nn * Kc * 4);
  float* Htab  = (float*)alloc(NCLS * HID * 4);
  float* cwtab = (float*)alloc(NCLS * Cc * 4);
  float* Wrpf  = (float*)alloc((size_t)NL * CC * HID * 4);
  float* Xa    = (float*)alloc((size_t)Nn * X3 * 4);
  float* Xb    = (float*)alloc((size_t)Nn * X3 * 4);
  float* hv    = (float*)alloc((size_t)Nn * HID * 4);
  bf16*  hAv   = (bf16*) alloc((size_t)Nn * HID * 2);
  bf16*  hBv   = (bf16*) alloc((size_t)Nn * HID * 2);
  bf16*  aggmv = (bf16*) alloc((size_t)Nn * HID * 2);
  // shuffled bf16 weight fragments
  constexpr int WRP_SZ = 7 * 8 * 512;   // 28672 shorts / layer
  constexpr int W128_SZ = 4 * 8 * 512;  // 16384
  constexpr int WX2_SZ = 4 * 1 * 512;   // 2048
  unsigned short* Wrp_s = (unsigned short*)alloc((size_t)NL * WRP_SZ * 2);
  unsigned short* We2_s = (unsigned short*)alloc((size_t)NL * W128_SZ * 2);
  unsigned short* Wx1_s = (unsigned short*)alloc((size_t)NL * W128_SZ * 2);
  unsigned short* Wx2_s = (unsigned short*)alloc((size_t)NL * WX2_SZ * 2);

  wrp_kernel<<<NL * CC, 128, 0, stream>>>(Wr, We1, Wrpf);
  htab_kernel<<<NCLS, 128, 0, stream>>>(Etab, Win, Wch, Htab, cwtab);
  gather_kernel<<<512, 256, 0, stream>>>(S, Htab, hv);
  knn_kernel<<<Bc * ((Lc + KROWS - 1) / KROWS), 256, 0, stream>>>(X, nbr);

  for (int l = 0; l < NL; ++l) {
    shuf_kernel<<<32, 256, 0, stream>>>(Wrpf + (size_t)l * CC * HID,
                                        Wrp_s + (size_t)l * WRP_SZ, CC, HID, 7, 8);
    shuf_kernel<<<16, 256, 0, stream>>>(We2 + (size_t)l * HID * HID,
                                        We2_s + (size_t)l * W128_SZ, HID, HID, 4, 8);
    shuf_kernel<<<16, 256, 0, stream>>>(Wx1 + (size_t)l * HID * HID,
                                        Wx1_s + (size_t)l * W128_SZ, HID, HID, 4, 8);
    shuf_kernel<<<4, 256, 0, stream>>>(Wx2 + (size_t)l * HID * Cc,
                                       Wx2_s + (size_t)l * WX2_SZ, HID, Cc, 4, 1);
  }

  // X ping-pong: layer0 reads the input directly
  const float* Xi = X;
  float* Xo = Xb;
  for (int l = 0; l < NL; ++l) {
    nodeAB_kernel<<<Nn / 8, 128, 0, stream>>>(hv, We1 + (size_t)l * 384 * HID,
                                              be1 + l * HID, hAv, hBv);
    edge_kernel<<<Nn / GN, 256, 0, stream>>>(
        Xi, Xo, hAv, hBv, S, cwtab, nbr,
        Wrp_s + (size_t)l * WRP_SZ, We2_s + (size_t)l * W128_SZ,
        Wx1_s + (size_t)l * W128_SZ, Wx2_s + (size_t)l * WX2_SZ, aggmv);
    nodeupd_kernel<<<Nn / 8, 128, 0, stream>>>(hv, aggmv, Wh1 + (size_t)l * 256 * HID,
                                               Wh2 + (size_t)l * HID * HID);
    Xi = Xo;
    Xo = (Xo == Xb) ? Xa : Xb;
  }

  float* out = (float*)d_out;
  final_kernel<<<Nn / 8, 128, 0, stream>>>(hv, Wf1, Wf2, out);
  xout_kernel<<<512, 256, 0, stream>>>(Xi, out + (size_t)Nn * NCLS);
}

// Round 10
// 1003.128 us; speedup vs baseline: 3.1042x; 1.0268x over previous
//
#include <hip/hip_runtime.h>
#include <hip/hip_bf16.h>

typedef __hip_bfloat16 bf16;

// Problem constants
constexpr int Bc  = 8;
constexpr int Lc  = 2500;
constexpr int Cc  = 14;
constexpr int Kc  = 9;
constexpr int Nn  = Bc * Lc;     // 20000
constexpr int NCLS = 20;
constexpr int HID = 128;
constexpr int NL  = 3;
constexpr int CC  = Cc * Cc;     // 196
constexpr int X3  = Cc * 3;      // 42

typedef __bf16 bf16x8 __attribute__((ext_vector_type(8)));
typedef short  sh8    __attribute__((ext_vector_type(8)));
typedef float  f32x4  __attribute__((ext_vector_type(4)));

__device__ __forceinline__ float b2f(bf16 x) { return __bfloat162float(x); }
__device__ __forceinline__ float b2fu(unsigned short u) {
  return __uint_as_float(((unsigned int)u) << 16);
}
__device__ __forceinline__ unsigned short f2bu(float x) {
  bf16 h = __float2bfloat16(x);
  return *reinterpret_cast<unsigned short*>(&h);
}
__device__ __forceinline__ float siluf(float x) { return x / (1.0f + __expf(-x)); }
__device__ __forceinline__ int clampi(int v, int n) {
  return ((unsigned)v < (unsigned)n) ? v : 0;
}

__device__ __forceinline__ f32x4 mfma16(sh8 a, sh8 b, f32x4 c) {
  return __builtin_amdgcn_mfma_f32_16x16x32_bf16(
      __builtin_bit_cast(bf16x8, a), __builtin_bit_cast(bf16x8, b), c, 0, 0, 0);
}

// A/activation fragment-linear offset (in shorts). MT m-tiles; tile = 512 shorts.
__device__ __forceinline__ int fragoff(int e, int k, int MT) {
  return (((k >> 5) * MT + (e >> 4)) << 9) +
         (((e & 15) + (((k >> 3) & 3) << 4)) << 3) + (k & 7);
}

// ---------------------------------------------------------------------------
// Wrp[l] = Wr[l] @ We1[l][256:384,:]  (fp32, fold radial proj into edge MLP)
// ---------------------------------------------------------------------------
__global__ __launch_bounds__(128) void wrp_kernel(const float* __restrict__ Wr,
                                                  const float* __restrict__ We1,
                                                  float* __restrict__ Wrp) {
  int l = blockIdx.x / CC, j = blockIdx.x % CC;
  int t = threadIdx.x;
  __shared__ float row[HID];
  row[t] = Wr[(size_t)(l * CC + j) * HID + t];
  __syncthreads();
  float acc = 0.f;
  #pragma unroll 4
  for (int k = 0; k < HID; ++k)
    acc += row[k] * We1[(size_t)(l * 384 + 256 + k) * HID + t];
  Wrp[(size_t)(l * CC + j) * HID + t] = acc;
}

// Shuffle fp32 K x N weight into B-fragment-linear bf16 (zero-padded).
__global__ void shuf_kernel(const float* __restrict__ W, unsigned short* __restrict__ out,
                            int K, int N, int KT, int NT) {
  int total = KT * NT * 512;
  for (int idx = blockIdx.x * blockDim.x + threadIdx.x; idx < total;
       idx += gridDim.x * blockDim.x) {
    int j = idx & 7;
    int lane = (idx >> 3) & 63;
    int nt = (idx >> 9) % NT;
    int kt = idx / (512 * NT);
    int k = kt * 32 + ((lane >> 4) << 3) + j;
    int n = nt * 16 + (lane & 15);
    float v = (k < K && n < N) ? W[(size_t)k * N + n] : 0.f;
    out[idx] = f2bu(v);
  }
}

// Htab = E_tab @ Win (20x128); cwtab = row-softmax(Wchan) (20x14)
__global__ __launch_bounds__(128) void htab_kernel(const float* __restrict__ Et,
                                                   const float* __restrict__ Win,
                                                   const float* __restrict__ Wch,
                                                   float* __restrict__ Htab,
                                                   float* __restrict__ cwtab) {
  int r = blockIdx.x, t = threadIdx.x;
  __shared__ float e[HID];
  e[t] = Et[r * HID + t];
  __syncthreads();
  float acc = 0.f;
  #pragma unroll 4
  for (int k = 0; k < HID; ++k) acc += e[k] * Win[k * HID + t];
  Htab[r * HID + t] = acc;
  if (t == 0) {
    float v[Cc];
    float mx = -1e30f;
    for (int c = 0; c < Cc; ++c) { v[c] = Wch[r * Cc + c]; mx = fmaxf(mx, v[c]); }
    float s = 0.f;
    for (int c = 0; c < Cc; ++c) { v[c] = __expf(v[c] - mx); s += v[c]; }
    float inv = 1.0f / s;
    for (int c = 0; c < Cc; ++c) cwtab[r * Cc + c] = v[c] * inv;
  }
}

// h[n] = Htab[S[n]]
__global__ void gather_kernel(const int* __restrict__ S, const float* __restrict__ Htab,
                              float* __restrict__ h) {
  int stride = gridDim.x * blockDim.x;
  for (int i = blockIdx.x * blockDim.x + threadIdx.x; i < Nn * HID; i += stride)
    h[i] = Htab[clampi(S[i >> 7], NCLS) * HID + (i & 127)];
}

// ---------------------------------------------------------------------------
// kNN: 32 rows/block, 8 threads/row; SoA pos + 4-wide float4 candidate batches
// (3 ds_read_b128 per 4 candidates instead of 12 scalar reads).  Subsets are
// contiguous ascending index ranges (KCH=316, 4-aligned); stable (d2, idx)
// 8-way merge reproduces jax top_k tie-breaking exactly.
// ---------------------------------------------------------------------------
constexpr int KROWS = 32;
constexpr int KSUB  = 8;
constexpr int KCH   = 316;                      // 4-aligned, 8*316 >= 2500

__global__ __launch_bounds__(256) void knn_kernel(const float* __restrict__ X,
                                                  int* __restrict__ nbr) {
  __shared__ __align__(16) float s_px[2512];    // 10048 B each
  __shared__ __align__(16) float s_py[2512];
  __shared__ __align__(16) float s_pz[2512];
  __shared__ float s_bd[KROWS * KSUB * Kc];     //  9216 B
  __shared__ int   s_bi[KROWS * KSUB * Kc];     //  9216 B
  constexpr int bpc = (Lc + KROWS - 1) / KROWS; // 79 blocks per complex
  int comp = blockIdx.x / bpc, rb = blockIdx.x % bpc;
  int t = threadIdx.x;
  for (int i = t; i < Lc; i += 256) {
    size_t g = (size_t)(comp * Lc + i) * X3;
    s_px[i] = X[g + 3];
    s_py[i] = X[g + 4];
    s_pz[i] = X[g + 5];
  }
  __syncthreads();

  int rl = t >> 3, q = t & 7;
  int r = rb * KROWS + rl;
  float bd[Kc];
  int   bi[Kc];
  #pragma unroll
  for (int k = 0; k < Kc; ++k) { bd[k] = 1e30f; bi[k] = 0x7fffffff; }
  if (r < Lc) {
    float px = s_px[r], py = s_py[r], pz = s_pz[r];
    int i0 = q * KCH;
    int i1 = i0 + KCH; if (i1 > Lc) i1 = Lc;
    int i = i0;
    for (; i + 4 <= i1; i += 4) {
      float4 xs = *(const float4*)(s_px + i);
      float4 ys = *(const float4*)(s_py + i);
      float4 zs = *(const float4*)(s_pz + i);
      float d2v[4];
      {
        float dx, dy, dz;
        dx = px - xs.x; dy = py - ys.x; dz = pz - zs.x; d2v[0] = dx*dx + dy*dy + dz*dz;
        dx = px - xs.y; dy = py - ys.y; dz = pz - zs.y; d2v[1] = dx*dx + dy*dy + dz*dz;
        dx = px - xs.z; dy = py - ys.z; dz = pz - zs.z; d2v[2] = dx*dx + dy*dy + dz*dz;
        dx = px - xs.w; dy = py - ys.w; dz = pz - zs.w; d2v[3] = dx*dx + dy*dy + dz*dz;
      }
      #pragma unroll
      for (int u = 0; u < 4; ++u) {
        int ii = i + u;
        float d2 = d2v[u];
        if (ii != r && d2 < bd[Kc - 1]) {
          bd[Kc - 1] = d2; bi[Kc - 1] = ii;
          #pragma unroll
          for (int p = Kc - 1; p > 0; --p) {
            if (bd[p] < bd[p - 1]) {
              float td = bd[p]; bd[p] = bd[p - 1]; bd[p - 1] = td;
              int   ti = bi[p]; bi[p] = bi[p - 1]; bi[p - 1] = ti;
            }
          }
        }
      }
    }
    for (; i < i1; ++i) {   // tail (empty for current constants; kept for safety)
      float dx = px - s_px[i], dy = py - s_py[i], dz = pz - s_pz[i];
      float d2 = dx * dx + dy * dy + dz * dz;
      if (i != r && d2 < bd[Kc - 1]) {
        bd[Kc - 1] = d2; bi[Kc - 1] = i;
        #pragma unroll
        for (int p = Kc - 1; p > 0; --p) {
          if (bd[p] < bd[p - 1]) {
            float td = bd[p]; bd[p] = bd[p - 1]; bd[p - 1] = td;
            int   ti = bi[p]; bi[p] = bi[p - 1]; bi[p - 1] = ti;
          }
        }
      }
    }
  }
  #pragma unroll
  for (int k = 0; k < Kc; ++k) {
    s_bd[(rl * KSUB + q) * Kc + k] = bd[k];
    s_bi[(rl * KSUB + q) * Kc + k] = bi[k];
  }
  __syncthreads();

  if (t < KROWS) {
    int r2 = rb * KROWS + t;
    if (r2 < Lc) {
      int p[KSUB];
      #pragma unroll
      for (int qq = 0; qq < KSUB; ++qq) p[qq] = 0;
      int gbase = (comp * Lc + r2) * Kc;
      #pragma unroll
      for (int k = 0; k < Kc; ++k) {
        float bestd = 1e30f;
        int   besti = 0x7fffffff, bq = 0;
        #pragma unroll
        for (int qq = 0; qq < KSUB; ++qq) {
          if (p[qq] < Kc) {
            float d = s_bd[(t * KSUB + qq) * Kc + p[qq]];
            int   ix = s_bi[(t * KSUB + qq) * Kc + p[qq]];
            if (d < bestd || (d == bestd && ix < besti)) {
              bestd = d; besti = ix; bq = qq;
            }
          }
        }
        p[bq]++;
        nbr[gbase + k] = comp * Lc + besti;
      }
    }
  }
}

// ---------------------------------------------------------------------------
// Per-node: hA = h@We1[0:128,:] + be1, hB = h@We1[128:256,:]  (bf16 out)
// Standalone version (layer 0 only).
// ---------------------------------------------------------------------------
__global__ __launch_bounds__(128) void nodeAB_kernel(const float* __restrict__ h,
                                                     const float* __restrict__ We1,
                                                     const float* __restrict__ be1,
                                                     bf16* __restrict__ hA,
                                                     bf16* __restrict__ hB) {
  __shared__ float sh[8 * HID];
  int tid = threadIdx.x, n0 = blockIdx.x * 8;
  for (int o = tid; o < 8 * HID; o += 128) sh[o] = h[(size_t)n0 * HID + o];
  __syncthreads();
  float a[8], b[8];
  #pragma unroll
  for (int g = 0; g < 8; ++g) { a[g] = 0.f; b[g] = 0.f; }
  for (int j = 0; j < HID; ++j) {
    float wa = We1[j * HID + tid];
    float wb = We1[(HID + j) * HID + tid];
    #pragma unroll
    for (int g = 0; g < 8; ++g) {
      float x = sh[g * HID + j];
      a[g] += x * wa;
      b[g] += x * wb;
    }
  }
  float be = be1[tid];
  #pragma unroll
  for (int g = 0; g < 8; ++g) {
    hA[(size_t)(n0 + g) * HID + tid] = __float2bfloat16(a[g] + be);
    hB[(size_t)(n0 + g) * HID + tid] = __float2bfloat16(b[g]);
  }
}

// ---------------------------------------------------------------------------
// Fused node update + next layer's AB projection:
//   h += silu(cat(h,aggm)@Wh1)@Wh2;  hA/hB = hnew@We1_next(+be1_next)
// Identical fp32 op order to the two separate kernels.
// ---------------------------------------------------------------------------
__global__ __launch_bounds__(128) void fused_upd_AB(
    float* __restrict__ h, const bf16* __restrict__ aggm,
    const float* __restrict__ Wh1, const float* __restrict__ Wh2,
    const float* __restrict__ We1n, const float* __restrict__ be1n,
    bf16* __restrict__ hA, bf16* __restrict__ hB) {
  __shared__ float cat[8 * 256];
  __shared__ float u[8 * HID];
  int tid = threadIdx.x, n0 = blockIdx.x * 8;
  for (int o = tid; o < 8 * HID; o += 128) {
    int g = o >> 7, j = o & 127;
    cat[g * 256 + j] = h[(size_t)n0 * HID + o];
    cat[g * 256 + HID + j] = b2f(aggm[(size_t)n0 * HID + o]);
  }
  __syncthreads();
  float acc[8];
  #pragma unroll
  for (int g = 0; g < 8; ++g) acc[g] = 0.f;
  for (int j = 0; j < 256; ++j) {
    float w = Wh1[j * HID + tid];
    #pragma unroll
    for (int g = 0; g < 8; ++g) acc[g] += cat[g * 256 + j] * w;
  }
  #pragma unroll
  for (int g = 0; g < 8; ++g) u[g * HID + tid] = siluf(acc[g]);
  __syncthreads();
  float acc2[8];
  #pragma unroll
  for (int g = 0; g < 8; ++g) acc2[g] = 0.f;
  for (int j = 0; j < HID; ++j) {
    float w = Wh2[j * HID + tid];
    #pragma unroll
    for (int g = 0; g < 8; ++g) acc2[g] += u[g * HID + j] * w;
  }
  float hn[8];
  #pragma unroll
  for (int g = 0; g < 8; ++g) {
    hn[g] = cat[g * 256 + tid] + acc2[g];
    h[(size_t)(n0 + g) * HID + tid] = hn[g];
  }
  __syncthreads();   // all u reads done; safe to overwrite
  #pragma unroll
  for (int g = 0; g < 8; ++g) u[g * HID + tid] = hn[g];
  __syncthreads();
  // AB projection from hnew (in u)
  float a[8], b[8];
  #pragma unroll
  for (int g = 0; g < 8; ++g) { a[g] = 0.f; b[g] = 0.f; }
  for (int j = 0; j < HID; ++j) {
    float wa = We1n[j * HID + tid];
    float wb = We1n[(HID + j) * HID + tid];
    #pragma unroll
    for (int g = 0; g < 8; ++g) {
      float x = u[g * HID + j];
      a[g] += x * wa;
      b[g] += x * wb;
    }
  }
  float be = be1n[tid];
  #pragma unroll
  for (int g = 0; g < 8; ++g) {
    hA[(size_t)(n0 + g) * HID + tid] = __float2bfloat16(a[g] + be);
    hB[(size_t)(n0 + g) * HID + tid] = __float2bfloat16(b[g]);
  }
}

// ---------------------------------------------------------------------------
// Fused last node update + final FFN: logits = silu(silu(hnew)@Wf1)@Wf2
// ---------------------------------------------------------------------------
__global__ __launch_bounds__(128) void fused_upd_final(
    const float* __restrict__ h, const bf16* __restrict__ aggm,
    const float* __restrict__ Wh1, const float* __restrict__ Wh2,
    const float* __restrict__ Wf1, const float* __restrict__ Wf2,
    float* __restrict__ out) {
  __shared__ float cat[8 * 256];
  __shared__ float u[8 * HID];
  int tid = threadIdx.x, n0 = blockIdx.x * 8;
  for (int o = tid; o < 8 * HID; o += 128) {
    int g = o >> 7, j = o & 127;
    cat[g * 256 + j] = h[(size_t)n0 * HID + o];
    cat[g * 256 + HID + j] = b2f(aggm[(size_t)n0 * HID + o]);
  }
  __syncthreads();
  float acc[8];
  #pragma unroll
  for (int g = 0; g < 8; ++g) acc[g] = 0.f;
  for (int j = 0; j < 256; ++j) {
    float w = Wh1[j * HID + tid];
    #pragma unroll
    for (int g = 0; g < 8; ++g) acc[g] += cat[g * 256 + j] * w;
  }
  #pragma unroll
  for (int g = 0; g < 8; ++g) u[g * HID + tid] = siluf(acc[g]);
  __syncthreads();
  float acc2[8];
  #pragma unroll
  for (int g = 0; g < 8; ++g) acc2[g] = 0.f;
  for (int j = 0; j < HID; ++j) {
    float w = Wh2[j * HID + tid];
    #pragma unroll
    for (int g = 0; g < 8; ++g) acc2[g] += u[g * HID + j] * w;
  }
  float hn[8];
  #pragma unroll
  for (int g = 0; g < 8; ++g) hn[g] = cat[g * 256 + tid] + acc2[g];
  __syncthreads();
  #pragma unroll
  for (int g = 0; g < 8; ++g) u[g * HID + tid] = siluf(hn[g]);
  __syncthreads();
  float acc3[8];
  #pragma unroll
  for (int g = 0; g < 8; ++g) acc3[g] = 0.f;
  for (int j = 0; j < HID; ++j) {
    float w = Wf1[j * HID + tid];
    #pragma unroll
    for (int g = 0; g < 8; ++g) acc3[g] += u[g * HID + j] * w;
  }
  __syncthreads();   // cat reads done long ago; reuse as u2
  #pragma unroll
  for (int g = 0; g < 8; ++g) cat[g * HID + tid] = siluf(acc3[g]);
  __syncthreads();
  for (int o = tid; o < 8 * NCLS; o += 128) {
    int g = o / NCLS, c = o - g * NCLS;
    float s = 0.f;
    #pragma unroll 4
    for (int j = 0; j < HID; ++j) s += cat[g * HID + j] * Wf2[j * NCLS + c];
    out[(size_t)(n0 + g) * NCLS + c] = s;
  }
}

// ---------------------------------------------------------------------------
// MFMA edge kernel (unchanged from round 9)
// ---------------------------------------------------------------------------
constexpr int GN  = 4;
constexpr int NE  = GN * Kc;     // 36
constexpr int MT3 = 3;           // m-tiles (M padded to 48)

__global__ __launch_bounds__(256) void edge_kernel(
    const float* __restrict__ Xin, float* __restrict__ Xout,
    const bf16* __restrict__ hA, const bf16* __restrict__ hB,
    const int* __restrict__ S, const float* __restrict__ cwtab,
    const int* __restrict__ nbr,
    const unsigned short* __restrict__ Wrp_s, const unsigned short* __restrict__ We2_s,
    const unsigned short* __restrict__ Wx1_s, const unsigned short* __restrict__ Wx2_s,
    bf16* __restrict__ aggm) {
  __shared__ __align__(16) unsigned short s_R1[48 * 224];
  __shared__ __align__(16) unsigned short s_R2[48 * 128];
  __shared__ __align__(16) unsigned short s_xd[NE * 44];
  __shared__ __align__(16) unsigned short s_hB[NE * 130];
  __shared__ __align__(16) unsigned short s_hA[GN * 128];
  __shared__ float s_cw[GN * Cc];
  __shared__ int   s_dst[NE];

  int t = threadIdx.x;
  int n0 = blockIdx.x * GN;
  int lane = t & 63, wv = t >> 6;
  int quad = lane >> 4, l15 = lane & 15;
  int wnb = wv << 5;

  if (t < NE) s_dst[t] = clampi(nbr[n0 * Kc + t], Nn);
  if (t >= 64 && t < 64 + GN * Cc) {
    int o = t - 64;
    s_cw[o] = cwtab[clampi(S[n0 + o / Cc], NCLS) * Cc + o % Cc];
  }
  {
    unsigned int* r1 = (unsigned int*)s_R1;
    for (int o = t; o < 48 * 112; o += 256) r1[o] = 0u;
    unsigned int* r2 = (unsigned int*)s_R2;
    for (int o = t; o < 48 * 64; o += 256) r2[o] = 0u;
    const unsigned int* src = (const unsigned int*)(hA + (size_t)n0 * HID);
    unsigned int* dA = (unsigned int*)s_hA;
    for (int o = t; o < GN * 64; o += 256) dA[o] = src[o];
  }
  __syncthreads();

  for (int o = t; o < NE * X3; o += 256) {
    int e = o / X3, i = o - e * X3;
    float v = Xin[(size_t)(n0 + e / Kc) * X3 + i] - Xin[(size_t)s_dst[e] * X3 + i];
    s_xd[e * 44 + i] = f2bu(v);
  }
  {
    unsigned int* d = (unsigned int*)s_hB;
    const unsigned int* hb = (const unsigned int*)hB;
    for (int o = t; o < NE * 64; o += 256) {
      int e = o >> 6, w = o & 63;
      d[e * 65 + w] = hb[(size_t)s_dst[e] * 64 + w];
    }
  }
  __syncthreads();

  for (int o = t; o < NE * CC; o += 256) {
    int e = o / CC, j = o - e * CC;
    int c = j / Cc, d = j - c * Cc;
    const unsigned short* xe = s_xd + e * 44;
    float v = (b2fu(xe[c * 3 + 0]) * b2fu(xe[d * 3 + 0]) +
               b2fu(xe[c * 3 + 1]) * b2fu(xe[d * 3 + 1]) +
               b2fu(xe[c * 3 + 2]) * b2fu(xe[d * 3 + 2])) * (1.0f / 14.0f);
    s_R1[fragoff(e, j, MT3)] = f2bu(v);
  }
  __syncthreads();

  f32x4 acc1[MT3][2];
  #pragma unroll
  for (int mt = 0; mt < MT3; ++mt)
    #pragma unroll
    for (int nl = 0; nl < 2; ++nl) acc1[mt][nl] = (f32x4){0.f, 0.f, 0.f, 0.f};
  const sh8* r1v = (const sh8*)s_R1;
  for (int kt = 0; kt < 7; ++kt) {
    sh8 b0 = ((const sh8*)Wrp_s)[((kt << 3) + (wv << 1) + 0) * 64 + lane];
    sh8 b1 = ((const sh8*)Wrp_s)[((kt << 3) + (wv << 1) + 1) * 64 + lane];
    #pragma unroll
    for (int mt = 0; mt < MT3; ++mt) {
      sh8 a = r1v[(kt * MT3 + mt) * 64 + lane];
      acc1[mt][0] = mfma16(a, b0, acc1[mt][0]);
      acc1[mt][1] = mfma16(a, b1, acc1[mt][1]);
    }
  }
  #pragma unroll
  for (int mt = 0; mt < MT3; ++mt)
    #pragma unroll
    for (int nl = 0; nl < 2; ++nl) {
      int col = wnb + (nl << 4) + l15;
      #pragma unroll
      for (int r = 0; r < 4; ++r) {
        int row = (mt << 4) + (quad << 2) + r;
        if (row < NE) {
          float v = acc1[mt][nl][r] + b2fu(s_hA[((row / Kc) << 7) + col]) +
                    b2fu(s_hB[row * 130 + col]);
          s_R2[fragoff(row, col, MT3)] = f2bu(siluf(v));
        }
      }
    }
  __syncthreads();

  f32x4 acc2[MT3][2];
  #pragma unroll
  for (int mt = 0; mt < MT3; ++mt)
    #pragma unroll
    for (int nl = 0; nl < 2; ++nl) acc2[mt][nl] = (f32x4){0.f, 0.f, 0.f, 0.f};
  const sh8* r2v = (const sh8*)s_R2;
  for (int kt = 0; kt < 4; ++kt) {
    sh8 b0 = ((const sh8*)We2_s)[((kt << 3) + (wv << 1) + 0) * 64 + lane];
    sh8 b1 = ((const sh8*)We2_s)[((kt << 3) + (wv << 1) + 1) * 64 + lane];
    #pragma unroll
    for (int mt = 0; mt < MT3; ++mt) {
      sh8 a = r2v[(kt * MT3 + mt) * 64 + lane];
      acc2[mt][0] = mfma16(a, b0, acc2[mt][0]);
      acc2[mt][1] = mfma16(a, b1, acc2[mt][1]);
    }
  }
  __syncthreads();
  #pragma unroll
  for (int mt = 0; mt < MT3; ++mt)
    #pragma unroll
    for (int nl = 0; nl < 2; ++nl) {
      int col = wnb + (nl << 4) + l15;
      #pragma unroll
      for (int r = 0; r < 4; ++r) {
        int row = (mt << 4) + (quad << 2) + r;
        s_R2[fragoff(row, col, MT3)] = f2bu(siluf(acc2[mt][nl][r]));
      }
    }
  __syncthreads();

  for (int o = t; o < GN * HID; o += 256) {
    int g = o >> 7, col = o & 127;
    float s = 0.f;
    #pragma unroll
    for (int k = 0; k < Kc; ++k) s += b2fu(s_R2[fragoff(g * Kc + k, col, MT3)]);
    aggm[(size_t)(n0 + g) * HID + col] = __float2bfloat16(s);
  }
  f32x4 acc3[MT3][2];
  #pragma unroll
  for (int mt = 0; mt < MT3; ++mt)
    #pragma unroll
    for (int nl = 0; nl < 2; ++nl) acc3[mt][nl] = (f32x4){0.f, 0.f, 0.f, 0.f};
  for (int kt = 0; kt < 4; ++kt) {
    sh8 b0 = ((const sh8*)Wx1_s)[((kt << 3) + (wv << 1) + 0) * 64 + lane];
    sh8 b1 = ((const sh8*)Wx1_s)[((kt << 3) + (wv << 1) + 1) * 64 + lane];
    #pragma unroll
    for (int mt = 0; mt < MT3; ++mt) {
      sh8 a = r2v[(kt * MT3 + mt) * 64 + lane];
      acc3[mt][0] = mfma16(a, b0, acc3[mt][0]);
      acc3[mt][1] = mfma16(a, b1, acc3[mt][1]);
    }
  }
  #pragma unroll
  for (int mt = 0; mt < MT3; ++mt)
    #pragma unroll
    for (int nl = 0; nl < 2; ++nl) {
      int col = wnb + (nl << 4) + l15;
      #pragma unroll
      for (int r = 0; r < 4; ++r) {
        int row = (mt << 4) + (quad << 2) + r;
        s_R1[fragoff(row, col, MT3)] = f2bu(siluf(acc3[mt][nl][r]));
      }
    }
  __syncthreads();

  float* s_coef = (float*)s_R2;
  if (wv == 0) {
    f32x4 a4[MT3];
    #pragma unroll
    for (int mt = 0; mt < MT3; ++mt) a4[mt] = (f32x4){0.f, 0.f, 0.f, 0.f};
    for (int kt = 0; kt < 4; ++kt) {
      sh8 b = ((const sh8*)Wx2_s)[kt * 64 + lane];
      #pragma unroll
      for (int mt = 0; mt < MT3; ++mt) {
        sh8 a = r1v[(kt * MT3 + mt) * 64 + lane];
        a4[mt] = mfma16(a, b, a4[mt]);
      }
    }
    #pragma unroll
    for (int mt = 0; mt < MT3; ++mt)
      #pragma unroll
      for (int r = 0; r < 4; ++r) {
        int row = (mt << 4) + (quad << 2) + r;
        s_coef[(row << 4) + l15] = a4[mt][r];
      }
  }
  __syncthreads();

  for (int o = t; o < GN * X3; o += 256) {
    int g = o / X3, rem = o - g * X3, c = rem / 3;
    float s = 0.f;
    #pragma unroll
    for (int k = 0; k < Kc; ++k) {
      int e = g * Kc + k;
      s += b2fu(s_xd[e * 44 + rem]) * s_coef[(e << 4) + c];
    }
    int gn = n0 + g;
    Xout[(size_t)gn * X3 + rem] =
        Xin[(size_t)gn * X3 + rem] + s * s_cw[g * Cc + c] * (1.0f / 9.0f);
  }
}

__global__ void xout_kernel(const float* __restrict__ Xf, float* __restrict__ out) {
  for (int i = blockIdx.x * blockDim.x + threadIdx.x; i < Nn * X3;
       i += gridDim.x * blockDim.x)
    out[i] = Xf[i];
}

// ---------------------------------------------------------------------------
extern "C" void kernel_launch(void* const* d_in, const int* in_sizes, int n_in,
                              void* d_out, int out_size, void* d_ws, size_t ws_size,
                              hipStream_t stream) {
  const float* X    = (const float*)d_in[0];
  const int*   S    = (const int*)d_in[1];
  const float* Etab = (const float*)d_in[2];
  const float* Wch  = (const float*)d_in[3];
  const float* Win  = (const float*)d_in[4];
  const float* Wr   = (const float*)d_in[5];
  const float* We1  = (const float*)d_in[6];
  const float* be1  = (const float*)d_in[7];
  const float* We2  = (const float*)d_in[8];
  const float* Wx1  = (const float*)d_in[9];
  const float* Wx2  = (const float*)d_in[10];
  const float* Wh1  = (const float*)d_in[11];
  const float* Wh2  = (const float*)d_in[12];
  const float* Wf1  = (const float*)d_in[13];
  const float* Wf2  = (const float*)d_in[14];
  (void)in_sizes; (void)n_in; (void)out_size; (void)ws_size;

  char* base = (char*)d_ws;
  size_t off = 0;
  auto alloc = [&](size_t bytes) {
    void* p = base + off;
    off += (bytes + 255) & ~(size_t)255;
    return p;
  };
  int*   nbr   = (int*)  alloc((size_t)Nn * Kc * 4);
  float* Htab  = (float*)alloc(NCLS * HID * 4);
  float* cwtab = (float*)alloc(NCLS * Cc * 4);
  float* Wrpf  = (float*)alloc((size_t)NL * CC * HID * 4);
  float* Xa    = (float*)alloc((size_t)Nn * X3 * 4);
  float* Xb    = (float*)alloc((size_t)Nn * X3 * 4);
  float* hv    = (float*)alloc((size_t)Nn * HID * 4);
  bf16*  hAv   = (bf16*) alloc((size_t)Nn * HID * 2);
  bf16*  hBv   = (bf16*) alloc((size_t)Nn * HID * 2);
  bf16*  aggmv = (bf16*) alloc((size_t)Nn * HID * 2);
  constexpr int WRP_SZ = 7 * 8 * 512;
  constexpr int W128_SZ = 4 * 8 * 512;
  constexpr int WX2_SZ = 4 * 1 * 512;
  unsigned short* Wrp_s = (unsigned short*)alloc((size_t)NL * WRP_SZ * 2);
  unsigned short* We2_s = (unsigned short*)alloc((size_t)NL * W128_SZ * 2);
  unsigned short* Wx1_s = (unsigned short*)alloc((size_t)NL * W128_SZ * 2);
  unsigned short* Wx2_s = (unsigned short*)alloc((size_t)NL * WX2_SZ * 2);

  wrp_kernel<<<NL * CC, 128, 0, stream>>>(Wr, We1, Wrpf);
  htab_kernel<<<NCLS, 128, 0, stream>>>(Etab, Win, Wch, Htab, cwtab);
  gather_kernel<<<512, 256, 0, stream>>>(S, Htab, hv);
  knn_kernel<<<Bc * ((Lc + KROWS - 1) / KROWS), 256, 0, stream>>>(X, nbr);

  for (int l = 0; l < NL; ++l) {
    shuf_kernel<<<32, 256, 0, stream>>>(Wrpf + (size_t)l * CC * HID,
                                        Wrp_s + (size_t)l * WRP_SZ, CC, HID, 7, 8);
    shuf_kernel<<<16, 256, 0, stream>>>(We2 + (size_t)l * HID * HID,
                                        We2_s + (size_t)l * W128_SZ, HID, HID, 4, 8);
    shuf_kernel<<<16, 256, 0, stream>>>(Wx1 + (size_t)l * HID * HID,
                                        Wx1_s + (size_t)l * W128_SZ, HID, HID, 4, 8);
    shuf_kernel<<<4, 256, 0, stream>>>(Wx2 + (size_t)l * HID * Cc,
                                       Wx2_s + (size_t)l * WX2_SZ, HID, Cc, 4, 1);
  }

  // layer 0 AB projection, then per-layer: edge -> fused node update
  nodeAB_kernel<<<Nn / 8, 128, 0, stream>>>(hv, We1, be1, hAv, hBv);

  const float* Xi = X;
  float* Xo = Xb;
  float* out = (float*)d_out;
  for (int l = 0; l < NL; ++l) {
    edge_kernel<<<Nn / GN, 256, 0, stream>>>(
        Xi, Xo, hAv, hBv, S, cwtab, nbr,
        Wrp_s + (size_t)l * WRP_SZ, We2_s + (size_t)l * W128_SZ,
        Wx1_s + (size_t)l * W128_SZ, Wx2_s + (size_t)l * WX2_SZ, aggmv);
    if (l < NL - 1) {
      fused_upd_AB<<<Nn / 8, 128, 0, stream>>>(
          hv, aggmv, Wh1 + (size_t)l * 256 * HID, Wh2 + (size_t)l * HID * HID,
          We1 + (size_t)(l + 1) * 384 * HID, be1 + (l + 1) * HID, hAv, hBv);
    } else {
      fused_upd_final<<<Nn / 8, 128, 0, stream>>>(
          hv, aggmv, Wh1 + (size_t)l * 256 * HID, Wh2 + (size_t)l * HID * HID,
          Wf1, Wf2, out);
    }
    Xi = Xo;
    Xo = (Xo == Xb) ? Xa : Xb;
  }

  xout_kernel<<<512, 256, 0, stream>>>(Xi, out + (size_t)Nn * NCLS);
}

// Round 11
// 884.845 us; speedup vs baseline: 3.5192x; 1.1337x over previous
//
#include <hip/hip_runtime.h>
#include <hip/hip_bf16.h>

typedef __hip_bfloat16 bf16;

// Problem constants
constexpr int Bc  = 8;
constexpr int Lc  = 2500;
constexpr int Cc  = 14;
constexpr int Kc  = 9;
constexpr int Nn  = Bc * Lc;     // 20000
constexpr int NCLS = 20;
constexpr int HID = 128;
constexpr int NL  = 3;
constexpr int CC  = Cc * Cc;     // 196
constexpr int X3  = Cc * 3;      // 42

typedef __bf16 bf16x8 __attribute__((ext_vector_type(8)));
typedef short  sh8    __attribute__((ext_vector_type(8)));
typedef float  f32x4  __attribute__((ext_vector_type(4)));

__device__ __forceinline__ float b2f(bf16 x) { return __bfloat162float(x); }
__device__ __forceinline__ float b2fu(unsigned short u) {
  return __uint_as_float(((unsigned int)u) << 16);
}
__device__ __forceinline__ unsigned short f2bu(float x) {
  bf16 h = __float2bfloat16(x);
  return *reinterpret_cast<unsigned short*>(&h);
}
__device__ __forceinline__ float siluf(float x) { return x / (1.0f + __expf(-x)); }
__device__ __forceinline__ int clampi(int v, int n) {
  return ((unsigned)v < (unsigned)n) ? v : 0;
}

__device__ __forceinline__ f32x4 mfma16(sh8 a, sh8 b, f32x4 c) {
  return __builtin_amdgcn_mfma_f32_16x16x32_bf16(
      __builtin_bit_cast(bf16x8, a), __builtin_bit_cast(bf16x8, b), c, 0, 0, 0);
}

// A/activation fragment-linear offset (in shorts). MT m-tiles; tile = 512 shorts.
__device__ __forceinline__ int fragoff(int e, int k, int MT) {
  return (((k >> 5) * MT + (e >> 4)) << 9) +
         (((e & 15) + (((k >> 3) & 3) << 4)) << 3) + (k & 7);
}

// ---------------------------------------------------------------------------
// Wrp[l] = Wr[l] @ We1[l][256:384,:]  (fp32, fold radial proj into edge MLP)
// ---------------------------------------------------------------------------
__global__ __launch_bounds__(128) void wrp_kernel(const float* __restrict__ Wr,
                                                  const float* __restrict__ We1,
                                                  float* __restrict__ Wrp) {
  int l = blockIdx.x / CC, j = blockIdx.x % CC;
  int t = threadIdx.x;
  __shared__ float row[HID];
  row[t] = Wr[(size_t)(l * CC + j) * HID + t];
  __syncthreads();
  float acc = 0.f;
  #pragma unroll 4
  for (int k = 0; k < HID; ++k)
    acc += row[k] * We1[(size_t)(l * 384 + 256 + k) * HID + t];
  Wrp[(size_t)(l * CC + j) * HID + t] = acc;
}

// Shuffle fp32 K x N weight into B-fragment-linear bf16 (zero-padded).
__global__ void shuf_kernel(const float* __restrict__ W, unsigned short* __restrict__ out,
                            int K, int N, int KT, int NT) {
  int total = KT * NT * 512;
  for (int idx = blockIdx.x * blockDim.x + threadIdx.x; idx < total;
       idx += gridDim.x * blockDim.x) {
    int j = idx & 7;
    int lane = (idx >> 3) & 63;
    int nt = (idx >> 9) % NT;
    int kt = idx / (512 * NT);
    int k = kt * 32 + ((lane >> 4) << 3) + j;
    int n = nt * 16 + (lane & 15);
    float v = (k < K && n < N) ? W[(size_t)k * N + n] : 0.f;
    out[idx] = f2bu(v);
  }
}

// Htab = E_tab @ Win (20x128); cwtab = row-softmax(Wchan) (20x14)
__global__ __launch_bounds__(128) void htab_kernel(const float* __restrict__ Et,
                                                   const float* __restrict__ Win,
                                                   const float* __restrict__ Wch,
                                                   float* __restrict__ Htab,
                                                   float* __restrict__ cwtab) {
  int r = blockIdx.x, t = threadIdx.x;
  __shared__ float e[HID];
  e[t] = Et[r * HID + t];
  __syncthreads();
  float acc = 0.f;
  #pragma unroll 4
  for (int k = 0; k < HID; ++k) acc += e[k] * Win[k * HID + t];
  Htab[r * HID + t] = acc;
  if (t == 0) {
    float v[Cc];
    float mx = -1e30f;
    for (int c = 0; c < Cc; ++c) { v[c] = Wch[r * Cc + c]; mx = fmaxf(mx, v[c]); }
    float s = 0.f;
    for (int c = 0; c < Cc; ++c) { v[c] = __expf(v[c] - mx); s += v[c]; }
    float inv = 1.0f / s;
    for (int c = 0; c < Cc; ++c) cwtab[r * Cc + c] = v[c] * inv;
  }
}

// h[n] = Htab[S[n]]
__global__ void gather_kernel(const int* __restrict__ S, const float* __restrict__ Htab,
                              float* __restrict__ h) {
  int stride = gridDim.x * blockDim.x;
  for (int i = blockIdx.x * blockDim.x + threadIdx.x; i < Nn * HID; i += stride)
    h[i] = Htab[clampi(S[i >> 7], NCLS) * HID + (i & 127)];
}

// ---------------------------------------------------------------------------
// Extract CA coords to compact global SoA: posG[comp][axis][PSTR]
// ---------------------------------------------------------------------------
constexpr int PSTR = 2512;   // 4-aligned row stride, padded

__global__ void posx_kernel(const float* __restrict__ X, float* __restrict__ posG) {
  int total = Bc * PSTR;
  for (int i = blockIdx.x * blockDim.x + threadIdx.x; i < total;
       i += gridDim.x * blockDim.x) {
    int comp = i / PSTR, j = i - comp * PSTR;
    float x = 1e30f, y = 1e30f, z = 1e30f;
    if (j < Lc) {
      size_t g = (size_t)(comp * Lc + j) * X3;
      x = X[g + 3]; y = X[g + 4]; z = X[g + 5];
    }
    float* b = posG + (size_t)comp * 3 * PSTR;
    b[j] = x; b[PSTR + j] = y; b[2 * PSTR + j] = z;
  }
}

// ---------------------------------------------------------------------------
// kNN, zero-LDS: 8 rows/block, 32 threads/row, 80 candidates/thread (global
// SoA reads, L1/L2-served).  Private sorted top-9 per thread; 9 rounds of
// 64-bit shfl_xor min-reduction on key (d2_bits<<32)|idx merge the 32 lists.
// d2>=0 => float bits monotone => lexicographic (d2, idx) min == jax top_k
// stable order exactly.  No __shared__ -> residency capped by waves only.
// ---------------------------------------------------------------------------
constexpr int KR2 = 8;    // rows per block
constexpr int KC2 = 80;   // candidates per thread (4-aligned; 32*80 >= 2500)

__global__ __launch_bounds__(256) void knn_kernel(const float* __restrict__ posG,
                                                  int* __restrict__ nbr) {
  constexpr int bpc = (Lc + KR2 - 1) / KR2;   // 313
  int comp = blockIdx.x / bpc, rb = blockIdx.x % bpc;
  int t = threadIdx.x;
  int rl = t >> 5, q = t & 31;
  int r = rb * KR2 + rl;
  const float* px = posG + (size_t)comp * 3 * PSTR;
  const float* py = px + PSTR;
  const float* pz = py + PSTR;

  float bd[Kc];
  int   bi[Kc];
  #pragma unroll
  for (int k = 0; k < Kc; ++k) { bd[k] = __int_as_float(0x7f800000); bi[k] = 0x7fffffff; }

  if (r < Lc) {
    float rx = px[r], ry = py[r], rz = pz[r];
    int c0 = q * KC2;
    int c1 = c0 + KC2; if (c1 > Lc) c1 = Lc;
    for (int i = c0; i < c1; i += 4) {
      float4 xs = *(const float4*)(px + i);
      float4 ys = *(const float4*)(py + i);
      float4 zs = *(const float4*)(pz + i);
      float d2v[4];
      {
        float dx, dy, dz;
        dx = rx - xs.x; dy = ry - ys.x; dz = rz - zs.x; d2v[0] = dx*dx + dy*dy + dz*dz;
        dx = rx - xs.y; dy = ry - ys.y; dz = rz - zs.y; d2v[1] = dx*dx + dy*dy + dz*dz;
        dx = rx - xs.z; dy = ry - ys.z; dz = rz - zs.z; d2v[2] = dx*dx + dy*dy + dz*dz;
        dx = rx - xs.w; dy = ry - ys.w; dz = rz - zs.w; d2v[3] = dx*dx + dy*dy + dz*dz;
      }
      #pragma unroll
      for (int u = 0; u < 4; ++u) {
        int ii = i + u;
        float d2 = d2v[u];
        if (ii != r && d2 < bd[Kc - 1]) {
          bd[Kc - 1] = d2; bi[Kc - 1] = ii;
          #pragma unroll
          for (int p = Kc - 1; p > 0; --p) {
            if (bd[p] < bd[p - 1]) {
              float td = bd[p]; bd[p] = bd[p - 1]; bd[p - 1] = td;
              int   ti = bi[p]; bi[p] = bi[p - 1]; bi[p - 1] = ti;
            }
          }
        }
      }
    }
  }

  // 32-way stable merge via 9 rounds of half-wave min-reduction
  int gbase = (comp * Lc + r) * Kc;
  #pragma unroll
  for (int k = 0; k < Kc; ++k) {
    unsigned long long mykey =
        ((unsigned long long)__float_as_uint(bd[0]) << 32) | (unsigned int)bi[0];
    unsigned long long w = mykey;
    #pragma unroll
    for (int m = 1; m <= 16; m <<= 1) {
      unsigned long long o = __shfl_xor(w, m);
      if (o < w) w = o;
    }
    if (r < Lc && q == k)
      nbr[gbase + k] = comp * Lc + (int)(unsigned int)(w & 0xffffffffULL);
    if (mykey == w) {
      #pragma unroll
      for (int s = 0; s < Kc - 1; ++s) { bd[s] = bd[s + 1]; bi[s] = bi[s + 1]; }
      bd[Kc - 1] = __int_as_float(0x7f800000); bi[Kc - 1] = 0x7fffffff;
    }
  }
}

// ---------------------------------------------------------------------------
// Per-node: hA = h@We1[0:128,:] + be1, hB = h@We1[128:256,:]  (bf16 out)
// Standalone version (layer 0 only).
// ---------------------------------------------------------------------------
__global__ __launch_bounds__(128) void nodeAB_kernel(const float* __restrict__ h,
                                                     const float* __restrict__ We1,
                                                     const float* __restrict__ be1,
                                                     bf16* __restrict__ hA,
                                                     bf16* __restrict__ hB) {
  __shared__ float sh[8 * HID];
  int tid = threadIdx.x, n0 = blockIdx.x * 8;
  for (int o = tid; o < 8 * HID; o += 128) sh[o] = h[(size_t)n0 * HID + o];
  __syncthreads();
  float a[8], b[8];
  #pragma unroll
  for (int g = 0; g < 8; ++g) { a[g] = 0.f; b[g] = 0.f; }
  for (int j = 0; j < HID; ++j) {
    float wa = We1[j * HID + tid];
    float wb = We1[(HID + j) * HID + tid];
    #pragma unroll
    for (int g = 0; g < 8; ++g) {
      float x = sh[g * HID + j];
      a[g] += x * wa;
      b[g] += x * wb;
    }
  }
  float be = be1[tid];
  #pragma unroll
  for (int g = 0; g < 8; ++g) {
    hA[(size_t)(n0 + g) * HID + tid] = __float2bfloat16(a[g] + be);
    hB[(size_t)(n0 + g) * HID + tid] = __float2bfloat16(b[g]);
  }
}

// ---------------------------------------------------------------------------
// Fused node update + next layer's AB projection
// ---------------------------------------------------------------------------
__global__ __launch_bounds__(128) void fused_upd_AB(
    float* __restrict__ h, const bf16* __restrict__ aggm,
    const float* __restrict__ Wh1, const float* __restrict__ Wh2,
    const float* __restrict__ We1n, const float* __restrict__ be1n,
    bf16* __restrict__ hA, bf16* __restrict__ hB) {
  __shared__ float cat[8 * 256];
  __shared__ float u[8 * HID];
  int tid = threadIdx.x, n0 = blockIdx.x * 8;
  for (int o = tid; o < 8 * HID; o += 128) {
    int g = o >> 7, j = o & 127;
    cat[g * 256 + j] = h[(size_t)n0 * HID + o];
    cat[g * 256 + HID + j] = b2f(aggm[(size_t)n0 * HID + o]);
  }
  __syncthreads();
  float acc[8];
  #pragma unroll
  for (int g = 0; g < 8; ++g) acc[g] = 0.f;
  for (int j = 0; j < 256; ++j) {
    float w = Wh1[j * HID + tid];
    #pragma unroll
    for (int g = 0; g < 8; ++g) acc[g] += cat[g * 256 + j] * w;
  }
  #pragma unroll
  for (int g = 0; g < 8; ++g) u[g * HID + tid] = siluf(acc[g]);
  __syncthreads();
  float acc2[8];
  #pragma unroll
  for (int g = 0; g < 8; ++g) acc2[g] = 0.f;
  for (int j = 0; j < HID; ++j) {
    float w = Wh2[j * HID + tid];
    #pragma unroll
    for (int g = 0; g < 8; ++g) acc2[g] += u[g * HID + j] * w;
  }
  float hn[8];
  #pragma unroll
  for (int g = 0; g < 8; ++g) {
    hn[g] = cat[g * 256 + tid] + acc2[g];
    h[(size_t)(n0 + g) * HID + tid] = hn[g];
  }
  __syncthreads();
  #pragma unroll
  for (int g = 0; g < 8; ++g) u[g * HID + tid] = hn[g];
  __syncthreads();
  float a[8], b[8];
  #pragma unroll
  for (int g = 0; g < 8; ++g) { a[g] = 0.f; b[g] = 0.f; }
  for (int j = 0; j < HID; ++j) {
    float wa = We1n[j * HID + tid];
    float wb = We1n[(HID + j) * HID + tid];
    #pragma unroll
    for (int g = 0; g < 8; ++g) {
      float x = u[g * HID + j];
      a[g] += x * wa;
      b[g] += x * wb;
    }
  }
  float be = be1n[tid];
  #pragma unroll
  for (int g = 0; g < 8; ++g) {
    hA[(size_t)(n0 + g) * HID + tid] = __float2bfloat16(a[g] + be);
    hB[(size_t)(n0 + g) * HID + tid] = __float2bfloat16(b[g]);
  }
}

// ---------------------------------------------------------------------------
// Fused last node update + final FFN
// ---------------------------------------------------------------------------
__global__ __launch_bounds__(128) void fused_upd_final(
    const float* __restrict__ h, const bf16* __restrict__ aggm,
    const float* __restrict__ Wh1, const float* __restrict__ Wh2,
    const float* __restrict__ Wf1, const float* __restrict__ Wf2,
    float* __restrict__ out) {
  __shared__ float cat[8 * 256];
  __shared__ float u[8 * HID];
  int tid = threadIdx.x, n0 = blockIdx.x * 8;
  for (int o = tid; o < 8 * HID; o += 128) {
    int g = o >> 7, j = o & 127;
    cat[g * 256 + j] = h[(size_t)n0 * HID + o];
    cat[g * 256 + HID + j] = b2f(aggm[(size_t)n0 * HID + o]);
  }
  __syncthreads();
  float acc[8];
  #pragma unroll
  for (int g = 0; g < 8; ++g) acc[g] = 0.f;
  for (int j = 0; j < 256; ++j) {
    float w = Wh1[j * HID + tid];
    #pragma unroll
    for (int g = 0; g < 8; ++g) acc[g] += cat[g * 256 + j] * w;
  }
  #pragma unroll
  for (int g = 0; g < 8; ++g) u[g * HID + tid] = siluf(acc[g]);
  __syncthreads();
  float acc2[8];
  #pragma unroll
  for (int g = 0; g < 8; ++g) acc2[g] = 0.f;
  for (int j = 0; j < HID; ++j) {
    float w = Wh2[j * HID + tid];
    #pragma unroll
    for (int g = 0; g < 8; ++g) acc2[g] += u[g * HID + j] * w;
  }
  float hn[8];
  #pragma unroll
  for (int g = 0; g < 8; ++g) hn[g] = cat[g * 256 + tid] + acc2[g];
  __syncthreads();
  #pragma unroll
  for (int g = 0; g < 8; ++g) u[g * HID + tid] = siluf(hn[g]);
  __syncthreads();
  float acc3[8];
  #pragma unroll
  for (int g = 0; g < 8; ++g) acc3[g] = 0.f;
  for (int j = 0; j < HID; ++j) {
    float w = Wf1[j * HID + tid];
    #pragma unroll
    for (int g = 0; g < 8; ++g) acc3[g] += u[g * HID + j] * w;
  }
  __syncthreads();
  #pragma unroll
  for (int g = 0; g < 8; ++g) cat[g * HID + tid] = siluf(acc3[g]);
  __syncthreads();
  for (int o = tid; o < 8 * NCLS; o += 128) {
    int g = o / NCLS, c = o - g * NCLS;
    float s = 0.f;
    #pragma unroll 4
    for (int j = 0; j < HID; ++j) s += cat[g * HID + j] * Wf2[j * NCLS + c];
    out[(size_t)(n0 + g) * NCLS + c] = s;
  }
}

// ---------------------------------------------------------------------------
// MFMA edge kernel (unchanged)
// ---------------------------------------------------------------------------
constexpr int GN  = 4;
constexpr int NE  = GN * Kc;     // 36
constexpr int MT3 = 3;           // m-tiles (M padded to 48)

__global__ __launch_bounds__(256) void edge_kernel(
    const float* __restrict__ Xin, float* __restrict__ Xout,
    const bf16* __restrict__ hA, const bf16* __restrict__ hB,
    const int* __restrict__ S, const float* __restrict__ cwtab,
    const int* __restrict__ nbr,
    const unsigned short* __restrict__ Wrp_s, const unsigned short* __restrict__ We2_s,
    const unsigned short* __restrict__ Wx1_s, const unsigned short* __restrict__ Wx2_s,
    bf16* __restrict__ aggm) {
  __shared__ __align__(16) unsigned short s_R1[48 * 224];
  __shared__ __align__(16) unsigned short s_R2[48 * 128];
  __shared__ __align__(16) unsigned short s_xd[NE * 44];
  __shared__ __align__(16) unsigned short s_hB[NE * 130];
  __shared__ __align__(16) unsigned short s_hA[GN * 128];
  __shared__ float s_cw[GN * Cc];
  __shared__ int   s_dst[NE];

  int t = threadIdx.x;
  int n0 = blockIdx.x * GN;
  int lane = t & 63, wv = t >> 6;
  int quad = lane >> 4, l15 = lane & 15;
  int wnb = wv << 5;

  if (t < NE) s_dst[t] = clampi(nbr[n0 * Kc + t], Nn);
  if (t >= 64 && t < 64 + GN * Cc) {
    int o = t - 64;
    s_cw[o] = cwtab[clampi(S[n0 + o / Cc], NCLS) * Cc + o % Cc];
  }
  {
    unsigned int* r1 = (unsigned int*)s_R1;
    for (int o = t; o < 48 * 112; o += 256) r1[o] = 0u;
    unsigned int* r2 = (unsigned int*)s_R2;
    for (int o = t; o < 48 * 64; o += 256) r2[o] = 0u;
    const unsigned int* src = (const unsigned int*)(hA + (size_t)n0 * HID);
    unsigned int* dA = (unsigned int*)s_hA;
    for (int o = t; o < GN * 64; o += 256) dA[o] = src[o];
  }
  __syncthreads();

  for (int o = t; o < NE * X3; o += 256) {
    int e = o / X3, i = o - e * X3;
    float v = Xin[(size_t)(n0 + e / Kc) * X3 + i] - Xin[(size_t)s_dst[e] * X3 + i];
    s_xd[e * 44 + i] = f2bu(v);
  }
  {
    unsigned int* d = (unsigned int*)s_hB;
    const unsigned int* hb = (const unsigned int*)hB;
    for (int o = t; o < NE * 64; o += 256) {
      int e = o >> 6, w = o & 63;
      d[e * 65 + w] = hb[(size_t)s_dst[e] * 64 + w];
    }
  }
  __syncthreads();

  for (int o = t; o < NE * CC; o += 256) {
    int e = o / CC, j = o - e * CC;
    int c = j / Cc, d = j - c * Cc;
    const unsigned short* xe = s_xd + e * 44;
    float v = (b2fu(xe[c * 3 + 0]) * b2fu(xe[d * 3 + 0]) +
               b2fu(xe[c * 3 + 1]) * b2fu(xe[d * 3 + 1]) +
               b2fu(xe[c * 3 + 2]) * b2fu(xe[d * 3 + 2])) * (1.0f / 14.0f);
    s_R1[fragoff(e, j, MT3)] = f2bu(v);
  }
  __syncthreads();

  f32x4 acc1[MT3][2];
  #pragma unroll
  for (int mt = 0; mt < MT3; ++mt)
    #pragma unroll
    for (int nl = 0; nl < 2; ++nl) acc1[mt][nl] = (f32x4){0.f, 0.f, 0.f, 0.f};
  const sh8* r1v = (const sh8*)s_R1;
  for (int kt = 0; kt < 7; ++kt) {
    sh8 b0 = ((const sh8*)Wrp_s)[((kt << 3) + (wv << 1) + 0) * 64 + lane];
    sh8 b1 = ((const sh8*)Wrp_s)[((kt << 3) + (wv << 1) + 1) * 64 + lane];
    #pragma unroll
    for (int mt = 0; mt < MT3; ++mt) {
      sh8 a = r1v[(kt * MT3 + mt) * 64 + lane];
      acc1[mt][0] = mfma16(a, b0, acc1[mt][0]);
      acc1[mt][1] = mfma16(a, b1, acc1[mt][1]);
    }
  }
  #pragma unroll
  for (int mt = 0; mt < MT3; ++mt)
    #pragma unroll
    for (int nl = 0; nl < 2; ++nl) {
      int col = wnb + (nl << 4) + l15;
      #pragma unroll
      for (int r = 0; r < 4; ++r) {
        int row = (mt << 4) + (quad << 2) + r;
        if (row < NE) {
          float v = acc1[mt][nl][r] + b2fu(s_hA[((row / Kc) << 7) + col]) +
                    b2fu(s_hB[row * 130 + col]);
          s_R2[fragoff(row, col, MT3)] = f2bu(siluf(v));
        }
      }
    }
  __syncthreads();

  f32x4 acc2[MT3][2];
  #pragma unroll
  for (int mt = 0; mt < MT3; ++mt)
    #pragma unroll
    for (int nl = 0; nl < 2; ++nl) acc2[mt][nl] = (f32x4){0.f, 0.f, 0.f, 0.f};
  const sh8* r2v = (const sh8*)s_R2;
  for (int kt = 0; kt < 4; ++kt) {
    sh8 b0 = ((const sh8*)We2_s)[((kt << 3) + (wv << 1) + 0) * 64 + lane];
    sh8 b1 = ((const sh8*)We2_s)[((kt << 3) + (wv << 1) + 1) * 64 + lane];
    #pragma unroll
    for (int mt = 0; mt < MT3; ++mt) {
      sh8 a = r2v[(kt * MT3 + mt) * 64 + lane];
      acc2[mt][0] = mfma16(a, b0, acc2[mt][0]);
      acc2[mt][1] = mfma16(a, b1, acc2[mt][1]);
    }
  }
  __syncthreads();
  #pragma unroll
  for (int mt = 0; mt < MT3; ++mt)
    #pragma unroll
    for (int nl = 0; nl < 2; ++nl) {
      int col = wnb + (nl << 4) + l15;
      #pragma unroll
      for (int r = 0; r < 4; ++r) {
        int row = (mt << 4) + (quad << 2) + r;
        s_R2[fragoff(row, col, MT3)] = f2bu(siluf(acc2[mt][nl][r]));
      }
    }
  __syncthreads();

  for (int o = t; o < GN * HID; o += 256) {
    int g = o >> 7, col = o & 127;
    float s = 0.f;
    #pragma unroll
    for (int k = 0; k < Kc; ++k) s += b2fu(s_R2[fragoff(g * Kc + k, col, MT3)]);
    aggm[(size_t)(n0 + g) * HID + col] = __float2bfloat16(s);
  }
  f32x4 acc3[MT3][2];
  #pragma unroll
  for (int mt = 0; mt < MT3; ++mt)
    #pragma unroll
    for (int nl = 0; nl < 2; ++nl) acc3[mt][nl] = (f32x4){0.f, 0.f, 0.f, 0.f};
  for (int kt = 0; kt < 4; ++kt) {
    sh8 b0 = ((const sh8*)Wx1_s)[((kt << 3) + (wv << 1) + 0) * 64 + lane];
    sh8 b1 = ((const sh8*)Wx1_s)[((kt << 3) + (wv << 1) + 1) * 64 + lane];
    #pragma unroll
    for (int mt = 0; mt < MT3; ++mt) {
      sh8 a = r2v[(kt * MT3 + mt) * 64 + lane];
      acc3[mt][0] = mfma16(a, b0, acc3[mt][0]);
      acc3[mt][1] = mfma16(a, b1, acc3[mt][1]);
    }
  }
  #pragma unroll
  for (int mt = 0; mt < MT3; ++mt)
    #pragma unroll
    for (int nl = 0; nl < 2; ++nl) {
      int col = wnb + (nl << 4) + l15;
      #pragma unroll
      for (int r = 0; r < 4; ++r) {
        int row = (mt << 4) + (quad << 2) + r;
        s_R1[fragoff(row, col, MT3)] = f2bu(siluf(acc3[mt][nl][r]));
      }
    }
  __syncthreads();

  float* s_coef = (float*)s_R2;
  if (wv == 0) {
    f32x4 a4[MT3];
    #pragma unroll
    for (int mt = 0; mt < MT3; ++mt) a4[mt] = (f32x4){0.f, 0.f, 0.f, 0.f};
    for (int kt = 0; kt < 4; ++kt) {
      sh8 b = ((const sh8*)Wx2_s)[kt * 64 + lane];
      #pragma unroll
      for (int mt = 0; mt < MT3; ++mt) {
        sh8 a = r1v[(kt * MT3 + mt) * 64 + lane];
        a4[mt] = mfma16(a, b, a4[mt]);
      }
    }
    #pragma unroll
    for (int mt = 0; mt < MT3; ++mt)
      #pragma unroll
      for (int r = 0; r < 4; ++r) {
        int row = (mt << 4) + (quad << 2) + r;
        s_coef[(row << 4) + l15] = a4[mt][r];
      }
  }
  __syncthreads();

  for (int o = t; o < GN * X3; o += 256) {
    int g = o / X3, rem = o - g * X3, c = rem / 3;
    float s = 0.f;
    #pragma unroll
    for (int k = 0; k < Kc; ++k) {
      int e = g * Kc + k;
      s += b2fu(s_xd[e * 44 + rem]) * s_coef[(e << 4) + c];
    }
    int gn = n0 + g;
    Xout[(size_t)gn * X3 + rem] =
        Xin[(size_t)gn * X3 + rem] + s * s_cw[g * Cc + c] * (1.0f / 9.0f);
  }
}

// ---------------------------------------------------------------------------
extern "C" void kernel_launch(void* const* d_in, const int* in_sizes, int n_in,
                              void* d_out, int out_size, void* d_ws, size_t ws_size,
                              hipStream_t stream) {
  const float* X    = (const float*)d_in[0];
  const int*   S    = (const int*)d_in[1];
  const float* Etab = (const float*)d_in[2];
  const float* Wch  = (const float*)d_in[3];
  const float* Win  = (const float*)d_in[4];
  const float* Wr   = (const float*)d_in[5];
  const float* We1  = (const float*)d_in[6];
  const float* be1  = (const float*)d_in[7];
  const float* We2  = (const float*)d_in[8];
  const float* Wx1  = (const float*)d_in[9];
  const float* Wx2  = (const float*)d_in[10];
  const float* Wh1  = (const float*)d_in[11];
  const float* Wh2  = (const float*)d_in[12];
  const float* Wf1  = (const float*)d_in[13];
  const float* Wf2  = (const float*)d_in[14];
  (void)in_sizes; (void)n_in; (void)out_size; (void)ws_size;

  char* base = (char*)d_ws;
  size_t off = 0;
  auto alloc = [&](size_t bytes) {
    void* p = base + off;
    off += (bytes + 255) & ~(size_t)255;
    return p;
  };
  int*   nbr   = (int*)  alloc((size_t)Nn * Kc * 4);
  float* Htab  = (float*)alloc(NCLS * HID * 4);
  float* cwtab = (float*)alloc(NCLS * Cc * 4);
  float* Wrpf  = (float*)alloc((size_t)NL * CC * HID * 4);
  float* posG  = (float*)alloc((size_t)Bc * 3 * PSTR * 4);
  float* Xa    = (float*)alloc((size_t)Nn * X3 * 4);
  float* Xb    = (float*)alloc((size_t)Nn * X3 * 4);
  float* hv    = (float*)alloc((size_t)Nn * HID * 4);
  bf16*  hAv   = (bf16*) alloc((size_t)Nn * HID * 2);
  bf16*  hBv   = (bf16*) alloc((size_t)Nn * HID * 2);
  bf16*  aggmv = (bf16*) alloc((size_t)Nn * HID * 2);
  constexpr int WRP_SZ = 7 * 8 * 512;
  constexpr int W128_SZ = 4 * 8 * 512;
  constexpr int WX2_SZ = 4 * 1 * 512;
  unsigned short* Wrp_s = (unsigned short*)alloc((size_t)NL * WRP_SZ * 2);
  unsigned short* We2_s = (unsigned short*)alloc((size_t)NL * W128_SZ * 2);
  unsigned short* Wx1_s = (unsigned short*)alloc((size_t)NL * W128_SZ * 2);
  unsigned short* Wx2_s = (unsigned short*)alloc((size_t)NL * WX2_SZ * 2);

  wrp_kernel<<<NL * CC, 128, 0, stream>>>(Wr, We1, Wrpf);
  htab_kernel<<<NCLS, 128, 0, stream>>>(Etab, Win, Wch, Htab, cwtab);
  gather_kernel<<<512, 256, 0, stream>>>(S, Htab, hv);
  posx_kernel<<<79, 256, 0, stream>>>(X, posG);
  knn_kernel<<<Bc * ((Lc + KR2 - 1) / KR2), 256, 0, stream>>>(posG, nbr);

  for (int l = 0; l < NL; ++l) {
    shuf_kernel<<<32, 256, 0, stream>>>(Wrpf + (size_t)l * CC * HID,
                                        Wrp_s + (size_t)l * WRP_SZ, CC, HID, 7, 8);
    shuf_kernel<<<16, 256, 0, stream>>>(We2 + (size_t)l * HID * HID,
                                        We2_s + (size_t)l * W128_SZ, HID, HID, 4, 8);
    shuf_kernel<<<16, 256, 0, stream>>>(Wx1 + (size_t)l * HID * HID,
                                        Wx1_s + (size_t)l * W128_SZ, HID, HID, 4, 8);
    shuf_kernel<<<4, 256, 0, stream>>>(Wx2 + (size_t)l * HID * Cc,
                                       Wx2_s + (size_t)l * WX2_SZ, HID, Cc, 4, 1);
  }

  nodeAB_kernel<<<Nn / 8, 128, 0, stream>>>(hv, We1, be1, hAv, hBv);

  float* out = (float*)d_out;
  float* outX = out + (size_t)Nn * NCLS;
  const float* Xi = X;
  for (int l = 0; l < NL; ++l) {
    // last layer writes X directly into the output buffer
    float* Xo = (l == NL - 1) ? outX : ((l == 0) ? Xb : Xa);
    edge_kernel<<<Nn / GN, 256, 0, stream>>>(
        Xi, Xo, hAv, hBv, S, cwtab, nbr,
        Wrp_s + (size_t)l * WRP_SZ, We2_s + (size_t)l * W128_SZ,
        Wx1_s + (size_t)l * W128_SZ, Wx2_s + (size_t)l * WX2_SZ, aggmv);
    if (l < NL - 1) {
      fused_upd_AB<<<Nn / 8, 128, 0, stream>>>(
          hv, aggmv, Wh1 + (size_t)l * 256 * HID, Wh2 + (size_t)l * HID * HID,
          We1 + (size_t)(l + 1) * 384 * HID, be1 + (l + 1) * HID, hAv, hBv);
    } else {
      fused_upd_final<<<Nn / 8, 128, 0, stream>>>(
          hv, aggmv, Wh1 + (size_t)l * 256 * HID, Wh2 + (size_t)l * HID * HID,
          Wf1, Wf2, out);
    }
    Xi = Xo;
  }
}

// Round 12
// 680.422 us; speedup vs baseline: 4.5765x; 1.3004x over previous
//
#include <hip/hip_runtime.h>
#include <hip/hip_bf16.h>

typedef __hip_bfloat16 bf16;

// Problem constants
constexpr int Bc  = 8;
constexpr int Lc  = 2500;
constexpr int Cc  = 14;
constexpr int Kc  = 9;
constexpr int Nn  = Bc * Lc;     // 20000
constexpr int NCLS = 20;
constexpr int HID = 128;
constexpr int NL  = 3;
constexpr int CC  = Cc * Cc;     // 196
constexpr int X3  = Cc * 3;      // 42

typedef __bf16 bf16x8 __attribute__((ext_vector_type(8)));
typedef short  sh8    __attribute__((ext_vector_type(8)));
typedef float  f32x4  __attribute__((ext_vector_type(4)));

__device__ __forceinline__ float b2f(bf16 x) { return __bfloat162float(x); }
__device__ __forceinline__ float b2fu(unsigned short u) {
  return __uint_as_float(((unsigned int)u) << 16);
}
__device__ __forceinline__ unsigned short f2bu(float x) {
  bf16 h = __float2bfloat16(x);
  return *reinterpret_cast<unsigned short*>(&h);
}
__device__ __forceinline__ float siluf(float x) { return x / (1.0f + __expf(-x)); }
__device__ __forceinline__ int clampi(int v, int n) {
  return ((unsigned)v < (unsigned)n) ? v : 0;
}

__device__ __forceinline__ f32x4 mfma16(sh8 a, sh8 b, f32x4 c) {
  return __builtin_amdgcn_mfma_f32_16x16x32_bf16(
      __builtin_bit_cast(bf16x8, a), __builtin_bit_cast(bf16x8, b), c, 0, 0, 0);
}

// A/activation fragment-linear offset (in shorts). MT m-tiles; tile = 512 shorts.
__device__ __forceinline__ int fragoff(int e, int k, int MT) {
  return (((k >> 5) * MT + (e >> 4)) << 9) +
         (((e & 15) + (((k >> 3) & 3) << 4)) << 3) + (k & 7);
}

// ---------------------------------------------------------------------------
// Wrp[l] = Wr[l] @ We1[l][256:384,:]  (fp32, fold radial proj into edge MLP)
// ---------------------------------------------------------------------------
__global__ __launch_bounds__(128) void wrp_kernel(const float* __restrict__ Wr,
                                                  const float* __restrict__ We1,
                                                  float* __restrict__ Wrp) {
  int l = blockIdx.x / CC, j = blockIdx.x % CC;
  int t = threadIdx.x;
  __shared__ float row[HID];
  row[t] = Wr[(size_t)(l * CC + j) * HID + t];
  __syncthreads();
  float acc = 0.f;
  #pragma unroll 4
  for (int k = 0; k < HID; ++k)
    acc += row[k] * We1[(size_t)(l * 384 + 256 + k) * HID + t];
  Wrp[(size_t)(l * CC + j) * HID + t] = acc;
}

// ---------------------------------------------------------------------------
// Batched weight shuffle: fp32 KxN -> B-fragment-linear bf16 (zero-padded).
// All 26 weight tensors in one launch (blockIdx.y = entry).
// ---------------------------------------------------------------------------
constexpr int NSH = 26;
struct ShufArgs {
  const float* src[NSH];
  unsigned short* dst[NSH];
  int K[NSH], N[NSH], KT[NSH], NT[NSH];
};

__global__ void shufb_kernel(ShufArgs a) {
  int e = blockIdx.y;
  int K = a.K[e], N = a.N[e], NT = a.NT[e];
  int total = a.KT[e] * NT * 512;
  const float* W = a.src[e];
  unsigned short* out = a.dst[e];
  for (int idx = blockIdx.x * blockDim.x + threadIdx.x; idx < total;
       idx += gridDim.x * blockDim.x) {
    int j = idx & 7;
    int lane = (idx >> 3) & 63;
    int nt = (idx >> 9) % NT;
    int kt = idx / (512 * NT);
    int k = kt * 32 + ((lane >> 4) << 3) + j;
    int n = nt * 16 + (lane & 15);
    float v = (k < K && n < N) ? W[(size_t)k * N + n] : 0.f;
    out[idx] = f2bu(v);
  }
}

// Htab = E_tab @ Win (20x128); cwtab = row-softmax(Wchan) (20x14)
__global__ __launch_bounds__(128) void htab_kernel(const float* __restrict__ Et,
                                                   const float* __restrict__ Win,
                                                   const float* __restrict__ Wch,
                                                   float* __restrict__ Htab,
                                                   float* __restrict__ cwtab) {
  int r = blockIdx.x, t = threadIdx.x;
  __shared__ float e[HID];
  e[t] = Et[r * HID + t];
  __syncthreads();
  float acc = 0.f;
  #pragma unroll 4
  for (int k = 0; k < HID; ++k) acc += e[k] * Win[k * HID + t];
  Htab[r * HID + t] = acc;
  if (t == 0) {
    float v[Cc];
    float mx = -1e30f;
    for (int c = 0; c < Cc; ++c) { v[c] = Wch[r * Cc + c]; mx = fmaxf(mx, v[c]); }
    float s = 0.f;
    for (int c = 0; c < Cc; ++c) { v[c] = __expf(v[c] - mx); s += v[c]; }
    float inv = 1.0f / s;
    for (int c = 0; c < Cc; ++c) cwtab[r * Cc + c] = v[c] * inv;
  }
}

// h[n] = Htab[S[n]]
__global__ void gather_kernel(const int* __restrict__ S, const float* __restrict__ Htab,
                              float* __restrict__ h) {
  int stride = gridDim.x * blockDim.x;
  for (int i = blockIdx.x * blockDim.x + threadIdx.x; i < Nn * HID; i += stride)
    h[i] = Htab[clampi(S[i >> 7], NCLS) * HID + (i & 127)];
}

// ---------------------------------------------------------------------------
// Extract CA coords to compact global SoA: posG[comp][axis][PSTR]
// ---------------------------------------------------------------------------
constexpr int PSTR = 2512;

__global__ void posx_kernel(const float* __restrict__ X, float* __restrict__ posG) {
  int total = Bc * PSTR;
  for (int i = blockIdx.x * blockDim.x + threadIdx.x; i < total;
       i += gridDim.x * blockDim.x) {
    int comp = i / PSTR, j = i - comp * PSTR;
    float x = 1e30f, y = 1e30f, z = 1e30f;
    if (j < Lc) {
      size_t g = (size_t)(comp * Lc + j) * X3;
      x = X[g + 3]; y = X[g + 4]; z = X[g + 5];
    }
    float* b = posG + (size_t)comp * 3 * PSTR;
    b[j] = x; b[PSTR + j] = y; b[2 * PSTR + j] = z;
  }
}

// ---------------------------------------------------------------------------
// kNN, zero-LDS (unchanged from round 11)
// ---------------------------------------------------------------------------
constexpr int KR2 = 8;
constexpr int KC2 = 80;

__global__ __launch_bounds__(256) void knn_kernel(const float* __restrict__ posG,
                                                  int* __restrict__ nbr) {
  constexpr int bpc = (Lc + KR2 - 1) / KR2;   // 313
  int comp = blockIdx.x / bpc, rb = blockIdx.x % bpc;
  int t = threadIdx.x;
  int rl = t >> 5, q = t & 31;
  int r = rb * KR2 + rl;
  const float* px = posG + (size_t)comp * 3 * PSTR;
  const float* py = px + PSTR;
  const float* pz = py + PSTR;

  float bd[Kc];
  int   bi[Kc];
  #pragma unroll
  for (int k = 0; k < Kc; ++k) { bd[k] = __int_as_float(0x7f800000); bi[k] = 0x7fffffff; }

  if (r < Lc) {
    float rx = px[r], ry = py[r], rz = pz[r];
    int c0 = q * KC2;
    int c1 = c0 + KC2; if (c1 > Lc) c1 = Lc;
    for (int i = c0; i < c1; i += 4) {
      float4 xs = *(const float4*)(px + i);
      float4 ys = *(const float4*)(py + i);
      float4 zs = *(const float4*)(pz + i);
      float d2v[4];
      {
        float dx, dy, dz;
        dx = rx - xs.x; dy = ry - ys.x; dz = rz - zs.x; d2v[0] = dx*dx + dy*dy + dz*dz;
        dx = rx - xs.y; dy = ry - ys.y; dz = rz - zs.y; d2v[1] = dx*dx + dy*dy + dz*dz;
        dx = rx - xs.z; dy = ry - ys.z; dz = rz - zs.z; d2v[2] = dx*dx + dy*dy + dz*dz;
        dx = rx - xs.w; dy = ry - ys.w; dz = rz - zs.w; d2v[3] = dx*dx + dy*dy + dz*dz;
      }
      #pragma unroll
      for (int u = 0; u < 4; ++u) {
        int ii = i + u;
        float d2 = d2v[u];
        if (ii != r && d2 < bd[Kc - 1]) {
          bd[Kc - 1] = d2; bi[Kc - 1] = ii;
          #pragma unroll
          for (int p = Kc - 1; p > 0; --p) {
            if (bd[p] < bd[p - 1]) {
              float td = bd[p]; bd[p] = bd[p - 1]; bd[p - 1] = td;
              int   ti = bi[p]; bi[p] = bi[p - 1]; bi[p - 1] = ti;
            }
          }
        }
      }
    }
  }

  int gbase = (comp * Lc + r) * Kc;
  #pragma unroll
  for (int k = 0; k < Kc; ++k) {
    unsigned long long mykey =
        ((unsigned long long)__float_as_uint(bd[0]) << 32) | (unsigned int)bi[0];
    unsigned long long w = mykey;
    #pragma unroll
    for (int m = 1; m <= 16; m <<= 1) {
      unsigned long long o = __shfl_xor(w, m);
      if (o < w) w = o;
    }
    if (r < Lc && q == k)
      nbr[gbase + k] = comp * Lc + (int)(unsigned int)(w & 0xffffffffULL);
    if (mykey == w) {
      #pragma unroll
      for (int s = 0; s < Kc - 1; ++s) { bd[s] = bd[s + 1]; bi[s] = bi[s + 1]; }
      bd[Kc - 1] = __int_as_float(0x7f800000); bi[Kc - 1] = 0x7fffffff;
    }
  }
}

// ---------------------------------------------------------------------------
// MFMA node AB (layer 0): hA = h@We1a + be1, hB = h@We1b.  16 nodes/block.
// ---------------------------------------------------------------------------
__global__ __launch_bounds__(256) void nodeABm_kernel(
    const float* __restrict__ h,
    const unsigned short* __restrict__ We1a_s, const unsigned short* __restrict__ We1b_s,
    const float* __restrict__ be1n, bf16* __restrict__ hA, bf16* __restrict__ hB) {
  __shared__ __align__(16) unsigned short sB[4 * 512];
  int t = threadIdx.x, n0 = blockIdx.x * 16;
  int lane = t & 63, wv = t >> 6, quad = lane >> 4, l15 = lane & 15, wnb = wv << 5;

  for (int o = t; o < 16 * HID; o += 256) {
    int row = o >> 7, k = o & 127;
    sB[fragoff(row, k, 1)] = f2bu(h[(size_t)(n0 + row) * HID + k]);
  }
  __syncthreads();

  f32x4 a3[2] = {{0,0,0,0},{0,0,0,0}}, a4[2] = {{0,0,0,0},{0,0,0,0}};
  const sh8* sBv = (const sh8*)sB;
  for (int kt = 0; kt < 4; ++kt) {
    sh8 a = sBv[kt * 64 + lane];
    sh8 b0 = ((const sh8*)We1a_s)[((kt << 3) + (wv << 1) + 0) * 64 + lane];
    sh8 b1 = ((const sh8*)We1a_s)[((kt << 3) + (wv << 1) + 1) * 64 + lane];
    sh8 c0 = ((const sh8*)We1b_s)[((kt << 3) + (wv << 1) + 0) * 64 + lane];
    sh8 c1 = ((const sh8*)We1b_s)[((kt << 3) + (wv << 1) + 1) * 64 + lane];
    a3[0] = mfma16(a, b0, a3[0]); a3[1] = mfma16(a, b1, a3[1]);
    a4[0] = mfma16(a, c0, a4[0]); a4[1] = mfma16(a, c1, a4[1]);
  }
  #pragma unroll
  for (int nl = 0; nl < 2; ++nl) {
    int col = wnb + (nl << 4) + l15;
    float be = be1n[col];
    #pragma unroll
    for (int r = 0; r < 4; ++r) {
      int row = (quad << 2) + r;
      hA[(size_t)(n0 + row) * HID + col] = __float2bfloat16(a3[nl][r] + be);
      hB[(size_t)(n0 + row) * HID + col] = __float2bfloat16(a4[nl][r]);
    }
  }
}

// ---------------------------------------------------------------------------
// MFMA fused node update + next AB:
//   hn = h + silu(cat(h,aggm)@Wh1)@Wh2;  hA/hB = hn@We1n(+be1n)
// 16 nodes/block, 256 threads = 4 waves, M = one 16-tile.
// ---------------------------------------------------------------------------
__global__ __launch_bounds__(256) void fupdAB_kernel(
    float* __restrict__ h, const bf16* __restrict__ aggm,
    const unsigned short* __restrict__ Wh1_s, const unsigned short* __restrict__ Wh2_s,
    const unsigned short* __restrict__ We1a_s, const unsigned short* __restrict__ We1b_s,
    const float* __restrict__ be1n, bf16* __restrict__ hA, bf16* __restrict__ hB) {
  __shared__ __align__(16) unsigned short sA[8 * 512];   // cat frags (KT=8)
  __shared__ __align__(16) unsigned short sB[4 * 512];   // u / hn frags (KT=4)
  int t = threadIdx.x, n0 = blockIdx.x * 16;
  int lane = t & 63, wv = t >> 6, quad = lane >> 4, l15 = lane & 15, wnb = wv << 5;

  for (int o = t; o < 16 * 256; o += 256) {
    int row = o >> 8, k = o & 255;
    float v = (k < HID) ? h[(size_t)(n0 + row) * HID + k]
                        : b2f(aggm[(size_t)(n0 + row) * HID + (k - HID)]);
    sA[fragoff(row, k, 1)] = f2bu(v);
  }
  __syncthreads();

  // GEMM1: u = silu(cat @ Wh1)
  f32x4 a1[2] = {{0,0,0,0},{0,0,0,0}};
  const sh8* sAv = (const sh8*)sA;
  for (int kt = 0; kt < 8; ++kt) {
    sh8 a = sAv[kt * 64 + lane];
    sh8 b0 = ((const sh8*)Wh1_s)[((kt << 3) + (wv << 1) + 0) * 64 + lane];
    sh8 b1 = ((const sh8*)Wh1_s)[((kt << 3) + (wv << 1) + 1) * 64 + lane];
    a1[0] = mfma16(a, b0, a1[0]);
    a1[1] = mfma16(a, b1, a1[1]);
  }
  #pragma unroll
  for (int nl = 0; nl < 2; ++nl) {
    int col = wnb + (nl << 4) + l15;
    #pragma unroll
    for (int r = 0; r < 4; ++r)
      sB[fragoff((quad << 2) + r, col, 1)] = f2bu(siluf(a1[nl][r]));
  }
  __syncthreads();

  // GEMM2: hn = h + u @ Wh2
  f32x4 a2[2] = {{0,0,0,0},{0,0,0,0}};
  const sh8* sBv = (const sh8*)sB;
  for (int kt = 0; kt < 4; ++kt) {
    sh8 a = sBv[kt * 64 + lane];
    sh8 b0 = ((const sh8*)Wh2_s)[((kt << 3) + (wv << 1) + 0) * 64 + lane];
    sh8 b1 = ((const sh8*)Wh2_s)[((kt << 3) + (wv << 1) + 1) * 64 + lane];
    a2[0] = mfma16(a, b0, a2[0]);
    a2[1] = mfma16(a, b1, a2[1]);
  }
  float hn[2][4];
  #pragma unroll
  for (int nl = 0; nl < 2; ++nl) {
    int col = wnb + (nl << 4) + l15;
    #pragma unroll
    for (int r = 0; r < 4; ++r) {
      int row = (quad << 2) + r;
      float v = h[(size_t)(n0 + row) * HID + col] + a2[nl][r];
      h[(size_t)(n0 + row) * HID + col] = v;
      hn[nl][r] = v;
    }
  }
  __syncthreads();   // all GEMM2 reads of sB done
  #pragma unroll
  for (int nl = 0; nl < 2; ++nl) {
    int col = wnb + (nl << 4) + l15;
    #pragma unroll
    for (int r = 0; r < 4; ++r)
      sB[fragoff((quad << 2) + r, col, 1)] = f2bu(hn[nl][r]);
  }
  __syncthreads();

  // GEMM3/4: hA = hn@We1a + be1n, hB = hn@We1b
  f32x4 a3[2] = {{0,0,0,0},{0,0,0,0}}, a4[2] = {{0,0,0,0},{0,0,0,0}};
  for (int kt = 0; kt < 4; ++kt) {
    sh8 a = sBv[kt * 64 + lane];
    sh8 b0 = ((const sh8*)We1a_s)[((kt << 3) + (wv << 1) + 0) * 64 + lane];
    sh8 b1 = ((const sh8*)We1a_s)[((kt << 3) + (wv << 1) + 1) * 64 + lane];
    sh8 c0 = ((const sh8*)We1b_s)[((kt << 3) + (wv << 1) + 0) * 64 + lane];
    sh8 c1 = ((const sh8*)We1b_s)[((kt << 3) + (wv << 1) + 1) * 64 + lane];
    a3[0] = mfma16(a, b0, a3[0]); a3[1] = mfma16(a, b1, a3[1]);
    a4[0] = mfma16(a, c0, a4[0]); a4[1] = mfma16(a, c1, a4[1]);
  }
  #pragma unroll
  for (int nl = 0; nl < 2; ++nl) {
    int col = wnb + (nl << 4) + l15;
    float be = be1n[col];
    #pragma unroll
    for (int r = 0; r < 4; ++r) {
      int row = (quad << 2) + r;
      hA[(size_t)(n0 + row) * HID + col] = __float2bfloat16(a3[nl][r] + be);
      hB[(size_t)(n0 + row) * HID + col] = __float2bfloat16(a4[nl][r]);
    }
  }
}

// ---------------------------------------------------------------------------
// MFMA fused last node update + final FFN:
//   hn = h + silu(cat@Wh1)@Wh2;  logits = silu(silu(hn)@Wf1)@Wf2
// ---------------------------------------------------------------------------
__global__ __launch_bounds__(256) void fupdF_kernel(
    const float* __restrict__ h, const bf16* __restrict__ aggm,
    const unsigned short* __restrict__ Wh1_s, const unsigned short* __restrict__ Wh2_s,
    const unsigned short* __restrict__ Wf1_s, const unsigned short* __restrict__ Wf2_s,
    float* __restrict__ out) {
  __shared__ __align__(16) unsigned short sA[8 * 512];
  __shared__ __align__(16) unsigned short sB[4 * 512];
  int t = threadIdx.x, n0 = blockIdx.x * 16;
  int lane = t & 63, wv = t >> 6, quad = lane >> 4, l15 = lane & 15, wnb = wv << 5;

  for (int o = t; o < 16 * 256; o += 256) {
    int row = o >> 8, k = o & 255;
    float v = (k < HID) ? h[(size_t)(n0 + row) * HID + k]
                        : b2f(aggm[(size_t)(n0 + row) * HID + (k - HID)]);
    sA[fragoff(row, k, 1)] = f2bu(v);
  }
  __syncthreads();

  f32x4 a1[2] = {{0,0,0,0},{0,0,0,0}};
  const sh8* sAv = (const sh8*)sA;
  for (int kt = 0; kt < 8; ++kt) {
    sh8 a = sAv[kt * 64 + lane];
    sh8 b0 = ((const sh8*)Wh1_s)[((kt << 3) + (wv << 1) + 0) * 64 + lane];
    sh8 b1 = ((const sh8*)Wh1_s)[((kt << 3) + (wv << 1) + 1) * 64 + lane];
    a1[0] = mfma16(a, b0, a1[0]);
    a1[1] = mfma16(a, b1, a1[1]);
  }
  #pragma unroll
  for (int nl = 0; nl < 2; ++nl) {
    int col = wnb + (nl << 4) + l15;
    #pragma unroll
    for (int r = 0; r < 4; ++r)
      sB[fragoff((quad << 2) + r, col, 1)] = f2bu(siluf(a1[nl][r]));
  }
  __syncthreads();

  f32x4 a2[2] = {{0,0,0,0},{0,0,0,0}};
  const sh8* sBv = (const sh8*)sB;
  for (int kt = 0; kt < 4; ++kt) {
    sh8 a = sBv[kt * 64 + lane];
    sh8 b0 = ((const sh8*)Wh2_s)[((kt << 3) + (wv << 1) + 0) * 64 + lane];
    sh8 b1 = ((const sh8*)Wh2_s)[((kt << 3) + (wv << 1) + 1) * 64 + lane];
    a2[0] = mfma16(a, b0, a2[0]);
    a2[1] = mfma16(a, b1, a2[1]);
  }
  float u2[2][4];
  #pragma unroll
  for (int nl = 0; nl < 2; ++nl) {
    int col = wnb + (nl << 4) + l15;
    #pragma unroll
    for (int r = 0; r < 4; ++r) {
      int row = (quad << 2) + r;
      u2[nl][r] = siluf(h[(size_t)(n0 + row) * HID + col] + a2[nl][r]);
    }
  }
  __syncthreads();
  #pragma unroll
  for (int nl = 0; nl < 2; ++nl) {
    int col = wnb + (nl << 4) + l15;
    #pragma unroll
    for (int r = 0; r < 4; ++r)
      sB[fragoff((quad << 2) + r, col, 1)] = f2bu(u2[nl][r]);
  }
  __syncthreads();

  // GEMM3: v = silu(u2 @ Wf1) -> sA frags (KT=4)
  f32x4 a3[2] = {{0,0,0,0},{0,0,0,0}};
  for (int kt = 0; kt < 4; ++kt) {
    sh8 a = sBv[kt * 64 + lane];
    sh8 b0 = ((const sh8*)Wf1_s)[((kt << 3) + (wv << 1) + 0) * 64 + lane];
    sh8 b1 = ((const sh8*)Wf1_s)[((kt << 3) + (wv << 1) + 1) * 64 + lane];
    a3[0] = mfma16(a, b0, a3[0]);
    a3[1] = mfma16(a, b1, a3[1]);
  }
  #pragma unroll
  for (int nl = 0; nl < 2; ++nl) {
    int col = wnb + (nl << 4) + l15;
    #pragma unroll
    for (int r = 0; r < 4; ++r)
      sA[fragoff((quad << 2) + r, col, 1)] = f2bu(siluf(a3[nl][r]));
  }
  __syncthreads();

  // GEMM4: logits = v @ Wf2 (N=20 padded to 32; waves 0,1 take nt 0,1)
  if (wv < 2) {
    f32x4 a5 = {0.f, 0.f, 0.f, 0.f};
    for (int kt = 0; kt < 4; ++kt) {
      sh8 a = sAv[kt * 64 + lane];
      sh8 b = ((const sh8*)Wf2_s)[(kt * 2 + wv) * 64 + lane];
      a5 = mfma16(a, b, a5);
    }
    int col = (wv << 4) + l15;
    if (col < NCLS) {
      #pragma unroll
      for (int r = 0; r < 4; ++r) {
        int row = (quad << 2) + r;
        out[(size_t)(n0 + row) * NCLS + col] = a5[r];
      }
    }
  }
}

// ---------------------------------------------------------------------------
// MFMA edge kernel (unchanged)
// ---------------------------------------------------------------------------
constexpr int GN  = 4;
constexpr int NE  = GN * Kc;     // 36
constexpr int MT3 = 3;           // m-tiles (M padded to 48)

__global__ __launch_bounds__(256) void edge_kernel(
    const float* __restrict__ Xin, float* __restrict__ Xout,
    const bf16* __restrict__ hA, const bf16* __restrict__ hB,
    const int* __restrict__ S, const float* __restrict__ cwtab,
    const int* __restrict__ nbr,
    const unsigned short* __restrict__ Wrp_s, const unsigned short* __restrict__ We2_s,
    const unsigned short* __restrict__ Wx1_s, const unsigned short* __restrict__ Wx2_s,
    bf16* __restrict__ aggm) {
  __shared__ __align__(16) unsigned short s_R1[48 * 224];
  __shared__ __align__(16) unsigned short s_R2[48 * 128];
  __shared__ __align__(16) unsigned short s_xd[NE * 44];
  __shared__ __align__(16) unsigned short s_hB[NE * 130];
  __shared__ __align__(16) unsigned short s_hA[GN * 128];
  __shared__ float s_cw[GN * Cc];
  __shared__ int   s_dst[NE];

  int t = threadIdx.x;
  int n0 = blockIdx.x * GN;
  int lane = t & 63, wv = t >> 6;
  int quad = lane >> 4, l15 = lane & 15;
  int wnb = wv << 5;

  if (t < NE) s_dst[t] = clampi(nbr[n0 * Kc + t], Nn);
  if (t >= 64 && t < 64 + GN * Cc) {
    int o = t - 64;
    s_cw[o] = cwtab[clampi(S[n0 + o / Cc], NCLS) * Cc + o % Cc];
  }
  {
    unsigned int* r1 = (unsigned int*)s_R1;
    for (int o = t; o < 48 * 112; o += 256) r1[o] = 0u;
    unsigned int* r2 = (unsigned int*)s_R2;
    for (int o = t; o < 48 * 64; o += 256) r2[o] = 0u;
    const unsigned int* src = (const unsigned int*)(hA + (size_t)n0 * HID);
    unsigned int* dA = (unsigned int*)s_hA;
    for (int o = t; o < GN * 64; o += 256) dA[o] = src[o];
  }
  __syncthreads();

  for (int o = t; o < NE * X3; o += 256) {
    int e = o / X3, i = o - e * X3;
    float v = Xin[(size_t)(n0 + e / Kc) * X3 + i] - Xin[(size_t)s_dst[e] * X3 + i];
    s_xd[e * 44 + i] = f2bu(v);
  }
  {
    unsigned int* d = (unsigned int*)s_hB;
    const unsigned int* hb = (const unsigned int*)hB;
    for (int o = t; o < NE * 64; o += 256) {
      int e = o >> 6, w = o & 63;
      d[e * 65 + w] = hb[(size_t)s_dst[e] * 64 + w];
    }
  }
  __syncthreads();

  for (int o = t; o < NE * CC; o += 256) {
    int e = o / CC, j = o - e * CC;
    int c = j / Cc, d = j - c * Cc;
    const unsigned short* xe = s_xd + e * 44;
    float v = (b2fu(xe[c * 3 + 0]) * b2fu(xe[d * 3 + 0]) +
               b2fu(xe[c * 3 + 1]) * b2fu(xe[d * 3 + 1]) +
               b2fu(xe[c * 3 + 2]) * b2fu(xe[d * 3 + 2])) * (1.0f / 14.0f);
    s_R1[fragoff(e, j, MT3)] = f2bu(v);
  }
  __syncthreads();

  f32x4 acc1[MT3][2];
  #pragma unroll
  for (int mt = 0; mt < MT3; ++mt)
    #pragma unroll
    for (int nl = 0; nl < 2; ++nl) acc1[mt][nl] = (f32x4){0.f, 0.f, 0.f, 0.f};
  const sh8* r1v = (const sh8*)s_R1;
  for (int kt = 0; kt < 7; ++kt) {
    sh8 b0 = ((const sh8*)Wrp_s)[((kt << 3) + (wv << 1) + 0) * 64 + lane];
    sh8 b1 = ((const sh8*)Wrp_s)[((kt << 3) + (wv << 1) + 1) * 64 + lane];
    #pragma unroll
    for (int mt = 0; mt < MT3; ++mt) {
      sh8 a = r1v[(kt * MT3 + mt) * 64 + lane];
      acc1[mt][0] = mfma16(a, b0, acc1[mt][0]);
      acc1[mt][1] = mfma16(a, b1, acc1[mt][1]);
    }
  }
  #pragma unroll
  for (int mt = 0; mt < MT3; ++mt)
    #pragma unroll
    for (int nl = 0; nl < 2; ++nl) {
      int col = wnb + (nl << 4) + l15;
      #pragma unroll
      for (int r = 0; r < 4; ++r) {
        int row = (mt << 4) + (quad << 2) + r;
        if (row < NE) {
          float v = acc1[mt][nl][r] + b2fu(s_hA[((row / Kc) << 7) + col]) +
                    b2fu(s_hB[row * 130 + col]);
          s_R2[fragoff(row, col, MT3)] = f2bu(siluf(v));
        }
      }
    }
  __syncthreads();

  f32x4 acc2[MT3][2];
  #pragma unroll
  for (int mt = 0; mt < MT3; ++mt)
    #pragma unroll
    for (int nl = 0; nl < 2; ++nl) acc2[mt][nl] = (f32x4){0.f, 0.f, 0.f, 0.f};
  const sh8* r2v = (const sh8*)s_R2;
  for (int kt = 0; kt < 4; ++kt) {
    sh8 b0 = ((const sh8*)We2_s)[((kt << 3) + (wv << 1) + 0) * 64 + lane];
    sh8 b1 = ((const sh8*)We2_s)[((kt << 3) + (wv << 1) + 1) * 64 + lane];
    #pragma unroll
    for (int mt = 0; mt < MT3; ++mt) {
      sh8 a = r2v[(kt * MT3 + mt) * 64 + lane];
      acc2[mt][0] = mfma16(a, b0, acc2[mt][0]);
      acc2[mt][1] = mfma16(a, b1, acc2[mt][1]);
    }
  }
  __syncthreads();
  #pragma unroll
  for (int mt = 0; mt < MT3; ++mt)
    #pragma unroll
    for (int nl = 0; nl < 2; ++nl) {
      int col = wnb + (nl << 4) + l15;
      #pragma unroll
      for (int r = 0; r < 4; ++r) {
        int row = (mt << 4) + (quad << 2) + r;
        s_R2[fragoff(row, col, MT3)] = f2bu(siluf(acc2[mt][nl][r]));
      }
    }
  __syncthreads();

  for (int o = t; o < GN * HID; o += 256) {
    int g = o >> 7, col = o & 127;
    float s = 0.f;
    #pragma unroll
    for (int k = 0; k < Kc; ++k) s += b2fu(s_R2[fragoff(g * Kc + k, col, MT3)]);
    aggm[(size_t)(n0 + g) * HID + col] = __float2bfloat16(s);
  }
  f32x4 acc3[MT3][2];
  #pragma unroll
  for (int mt = 0; mt < MT3; ++mt)
    #pragma unroll
    for (int nl = 0; nl < 2; ++nl) acc3[mt][nl] = (f32x4){0.f, 0.f, 0.f, 0.f};
  for (int kt = 0; kt < 4; ++kt) {
    sh8 b0 = ((const sh8*)Wx1_s)[((kt << 3) + (wv << 1) + 0) * 64 + lane];
    sh8 b1 = ((const sh8*)Wx1_s)[((kt << 3) + (wv << 1) + 1) * 64 + lane];
    #pragma unroll
    for (int mt = 0; mt < MT3; ++mt) {
      sh8 a = r2v[(kt * MT3 + mt) * 64 + lane];
      acc3[mt][0] = mfma16(a, b0, acc3[mt][0]);
      acc3[mt][1] = mfma16(a, b1, acc3[mt][1]);
    }
  }
  #pragma unroll
  for (int mt = 0; mt < MT3; ++mt)
    #pragma unroll
    for (int nl = 0; nl < 2; ++nl) {
      int col = wnb + (nl << 4) + l15;
      #pragma unroll
      for (int r = 0; r < 4; ++r) {
        int row = (mt << 4) + (quad << 2) + r;
        s_R1[fragoff(row, col, MT3)] = f2bu(siluf(acc3[mt][nl][r]));
      }
    }
  __syncthreads();

  float* s_coef = (float*)s_R2;
  if (wv == 0) {
    f32x4 a4[MT3];
    #pragma unroll
    for (int mt = 0; mt < MT3; ++mt) a4[mt] = (f32x4){0.f, 0.f, 0.f, 0.f};
    for (int kt = 0; kt < 4; ++kt) {
      sh8 b = ((const sh8*)Wx2_s)[kt * 64 + lane];
      #pragma unroll
      for (int mt = 0; mt < MT3; ++mt) {
        sh8 a = r1v[(kt * MT3 + mt) * 64 + lane];
        a4[mt] = mfma16(a, b, a4[mt]);
      }
    }
    #pragma unroll
    for (int mt = 0; mt < MT3; ++mt)
      #pragma unroll
      for (int r = 0; r < 4; ++r) {
        int row = (mt << 4) + (quad << 2) + r;
        s_coef[(row << 4) + l15] = a4[mt][r];
      }
  }
  __syncthreads();

  for (int o = t; o < GN * X3; o += 256) {
    int g = o / X3, rem = o - g * X3, c = rem / 3;
    float s = 0.f;
    #pragma unroll
    for (int k = 0; k < Kc; ++k) {
      int e = g * Kc + k;
      s += b2fu(s_xd[e * 44 + rem]) * s_coef[(e << 4) + c];
    }
    int gn = n0 + g;
    Xout[(size_t)gn * X3 + rem] =
        Xin[(size_t)gn * X3 + rem] + s * s_cw[g * Cc + c] * (1.0f / 9.0f);
  }
}

// ---------------------------------------------------------------------------
extern "C" void kernel_launch(void* const* d_in, const int* in_sizes, int n_in,
                              void* d_out, int out_size, void* d_ws, size_t ws_size,
                              hipStream_t stream) {
  const float* X    = (const float*)d_in[0];
  const int*   S    = (const int*)d_in[1];
  const float* Etab = (const float*)d_in[2];
  const float* Wch  = (const float*)d_in[3];
  const float* Win  = (const float*)d_in[4];
  const float* Wr   = (const float*)d_in[5];
  const float* We1  = (const float*)d_in[6];
  const float* be1  = (const float*)d_in[7];
  const float* We2  = (const float*)d_in[8];
  const float* Wx1  = (const float*)d_in[9];
  const float* Wx2  = (const float*)d_in[10];
  const float* Wh1  = (const float*)d_in[11];
  const float* Wh2  = (const float*)d_in[12];
  const float* Wf1  = (const float*)d_in[13];
  const float* Wf2  = (const float*)d_in[14];
  (void)in_sizes; (void)n_in; (void)out_size; (void)ws_size;

  char* base = (char*)d_ws;
  size_t off = 0;
  auto alloc = [&](size_t bytes) {
    void* p = base + off;
    off += (bytes + 255) & ~(size_t)255;
    return p;
  };
  int*   nbr   = (int*)  alloc((size_t)Nn * Kc * 4);
  float* Htab  = (float*)alloc(NCLS * HID * 4);
  float* cwtab = (float*)alloc(NCLS * Cc * 4);
  float* Wrpf  = (float*)alloc((size_t)NL * CC * HID * 4);
  float* posG  = (float*)alloc((size_t)Bc * 3 * PSTR * 4);
  float* Xa    = (float*)alloc((size_t)Nn * X3 * 4);
  float* Xb    = (float*)alloc((size_t)Nn * X3 * 4);
  float* hv    = (float*)alloc((size_t)Nn * HID * 4);
  bf16*  hAv   = (bf16*) alloc((size_t)Nn * HID * 2);
  bf16*  hBv   = (bf16*) alloc((size_t)Nn * HID * 2);
  bf16*  aggmv = (bf16*) alloc((size_t)Nn * HID * 2);
  constexpr int WRP_SZ = 7 * 8 * 512;
  constexpr int W128_SZ = 4 * 8 * 512;
  constexpr int WX2_SZ = 4 * 1 * 512;
  constexpr int WH1_SZ = 8 * 8 * 512;
  constexpr int WF2_SZ = 4 * 2 * 512;
  unsigned short* Wrp_s  = (unsigned short*)alloc((size_t)NL * WRP_SZ * 2);
  unsigned short* We2_s  = (unsigned short*)alloc((size_t)NL * W128_SZ * 2);
  unsigned short* Wx1_s  = (unsigned short*)alloc((size_t)NL * W128_SZ * 2);
  unsigned short* Wx2_s  = (unsigned short*)alloc((size_t)NL * WX2_SZ * 2);
  unsigned short* Wh1_s  = (unsigned short*)alloc((size_t)NL * WH1_SZ * 2);
  unsigned short* Wh2_s  = (unsigned short*)alloc((size_t)NL * W128_SZ * 2);
  unsigned short* We1a_s = (unsigned short*)alloc((size_t)NL * W128_SZ * 2);
  unsigned short* We1b_s = (unsigned short*)alloc((size_t)NL * W128_SZ * 2);
  unsigned short* Wf1_s  = (unsigned short*)alloc(W128_SZ * 2);
  unsigned short* Wf2_s  = (unsigned short*)alloc(WF2_SZ * 2);

  wrp_kernel<<<NL * CC, 128, 0, stream>>>(Wr, We1, Wrpf);
  htab_kernel<<<NCLS, 128, 0, stream>>>(Etab, Win, Wch, Htab, cwtab);
  gather_kernel<<<512, 256, 0, stream>>>(S, Htab, hv);
  posx_kernel<<<79, 256, 0, stream>>>(X, posG);
  knn_kernel<<<Bc * ((Lc + KR2 - 1) / KR2), 256, 0, stream>>>(posG, nbr);

  ShufArgs sa;
  for (int l = 0; l < NL; ++l) {
    int e = l * 8;
    sa.src[e+0] = Wrpf + (size_t)l * CC * HID;       sa.dst[e+0] = Wrp_s  + (size_t)l * WRP_SZ;
    sa.K[e+0] = CC;  sa.N[e+0] = HID; sa.KT[e+0] = 7; sa.NT[e+0] = 8;
    sa.src[e+1] = We2 + (size_t)l * HID * HID;       sa.dst[e+1] = We2_s  + (size_t)l * W128_SZ;
    sa.K[e+1] = HID; sa.N[e+1] = HID; sa.KT[e+1] = 4; sa.NT[e+1] = 8;
    sa.src[e+2] = Wx1 + (size_t)l * HID * HID;       sa.dst[e+2] = Wx1_s  + (size_t)l * W128_SZ;
    sa.K[e+2] = HID; sa.N[e+2] = HID; sa.KT[e+2] = 4; sa.NT[e+2] = 8;
    sa.src[e+3] = Wx2 + (size_t)l * HID * Cc;        sa.dst[e+3] = Wx2_s  + (size_t)l * WX2_SZ;
    sa.K[e+3] = HID; sa.N[e+3] = Cc;  sa.KT[e+3] = 4; sa.NT[e+3] = 1;
    sa.src[e+4] = Wh1 + (size_t)l * 256 * HID;       sa.dst[e+4] = Wh1_s  + (size_t)l * WH1_SZ;
    sa.K[e+4] = 256; sa.N[e+4] = HID; sa.KT[e+4] = 8; sa.NT[e+4] = 8;
    sa.src[e+5] = Wh2 + (size_t)l * HID * HID;       sa.dst[e+5] = Wh2_s  + (size_t)l * W128_SZ;
    sa.K[e+5] = HID; sa.N[e+5] = HID; sa.KT[e+5] = 4; sa.NT[e+5] = 8;
    sa.src[e+6] = We1 + (size_t)l * 384 * HID;       sa.dst[e+6] = We1a_s + (size_t)l * W128_SZ;
    sa.K[e+6] = HID; sa.N[e+6] = HID; sa.KT[e+6] = 4; sa.NT[e+6] = 8;
    sa.src[e+7] = We1 + (size_t)l * 384 * HID + (size_t)HID * HID;
    sa.dst[e+7] = We1b_s + (size_t)l * W128_SZ;
    sa.K[e+7] = HID; sa.N[e+7] = HID; sa.KT[e+7] = 4; sa.NT[e+7] = 8;
  }
  sa.src[24] = Wf1; sa.dst[24] = Wf1_s; sa.K[24] = HID; sa.N[24] = HID;
  sa.KT[24] = 4; sa.NT[24] = 8;
  sa.src[25] = Wf2; sa.dst[25] = Wf2_s; sa.K[25] = HID; sa.N[25] = NCLS;
  sa.KT[25] = 4; sa.NT[25] = 2;
  shufb_kernel<<<dim3(16, NSH), 256, 0, stream>>>(sa);

  nodeABm_kernel<<<Nn / 16, 256, 0, stream>>>(hv, We1a_s, We1b_s, be1, hAv, hBv);

  float* out = (float*)d_out;
  float* outX = out + (size_t)Nn * NCLS;
  const float* Xi = X;
  for (int l = 0; l < NL; ++l) {
    float* Xo = (l == NL - 1) ? outX : ((l == 0) ? Xb : Xa);
    edge_kernel<<<Nn / GN, 256, 0, stream>>>(
        Xi, Xo, hAv, hBv, S, cwtab, nbr,
        Wrp_s + (size_t)l * WRP_SZ, We2_s + (size_t)l * W128_SZ,
        Wx1_s + (size_t)l * W128_SZ, Wx2_s + (size_t)l * WX2_SZ, aggmv);
    if (l < NL - 1) {
      fupdAB_kernel<<<Nn / 16, 256, 0, stream>>>(
          hv, aggmv, Wh1_s + (size_t)l * WH1_SZ, Wh2_s + (size_t)l * W128_SZ,
          We1a_s + (size_t)(l + 1) * W128_SZ, We1b_s + (size_t)(l + 1) * W128_SZ,
          be1 + (l + 1) * HID, hAv, hBv);
    } else {
      fupdF_kernel<<<Nn / 16, 256, 0, stream>>>(
          hv, aggmv, Wh1_s + (size_t)l * WH1_SZ, Wh2_s + (size_t)l * W128_SZ,
          Wf1_s, Wf2_s, out);
    }
    Xi = Xo;
  }
}

// Round 13
// 569.384 us; speedup vs baseline: 5.4690x; 1.1950x over previous
//
#include <hip/hip_runtime.h>
#include <hip/hip_bf16.h>

typedef __hip_bfloat16 bf16;

// Problem constants
constexpr int Bc  = 8;
constexpr int Lc  = 2500;
constexpr int Cc  = 14;
constexpr int Kc  = 9;
constexpr int Nn  = Bc * Lc;     // 20000
constexpr int NCLS = 20;
constexpr int HID = 128;
constexpr int NL  = 3;
constexpr int CC  = Cc * Cc;     // 196
constexpr int X3  = Cc * 3;      // 42

typedef __bf16 bf16x8 __attribute__((ext_vector_type(8)));
typedef short  sh8    __attribute__((ext_vector_type(8)));
typedef float  f32x4  __attribute__((ext_vector_type(4)));

__device__ __forceinline__ float b2f(bf16 x) { return __bfloat162float(x); }
__device__ __forceinline__ float b2fu(unsigned short u) {
  return __uint_as_float(((unsigned int)u) << 16);
}
__device__ __forceinline__ unsigned short f2bu(float x) {
  bf16 h = __float2bfloat16(x);
  return *reinterpret_cast<unsigned short*>(&h);
}
// fast silu: v_exp-based expf + v_rcp (no full-precision divide)
__device__ __forceinline__ float siluf(float x) {
  return x * __builtin_amdgcn_rcpf(1.0f + __expf(-x));
}
__device__ __forceinline__ int clampi(int v, int n) {
  return ((unsigned)v < (unsigned)n) ? v : 0;
}
__device__ __forceinline__ void unpk2(unsigned int u, float& a, float& b) {
  a = __uint_as_float(u << 16);
  b = __uint_as_float(u & 0xffff0000u);
}

__device__ __forceinline__ f32x4 mfma16(sh8 a, sh8 b, f32x4 c) {
  return __builtin_amdgcn_mfma_f32_16x16x32_bf16(
      __builtin_bit_cast(bf16x8, a), __builtin_bit_cast(bf16x8, b), c, 0, 0, 0);
}

// A/activation fragment-linear offset (in shorts). MT m-tiles; tile = 512 shorts.
__device__ __forceinline__ int fragoff(int e, int k, int MT) {
  return (((k >> 5) * MT + (e >> 4)) << 9) +
         (((e & 15) + (((k >> 3) & 3) << 4)) << 3) + (k & 7);
}

// ---------------------------------------------------------------------------
// Wrp[l] = Wr[l] @ We1[l][256:384,:]  (fp32, fold radial proj into edge MLP)
// ---------------------------------------------------------------------------
__global__ __launch_bounds__(128) void wrp_kernel(const float* __restrict__ Wr,
                                                  const float* __restrict__ We1,
                                                  float* __restrict__ Wrp) {
  int l = blockIdx.x / CC, j = blockIdx.x % CC;
  int t = threadIdx.x;
  __shared__ float row[HID];
  row[t] = Wr[(size_t)(l * CC + j) * HID + t];
  __syncthreads();
  float acc = 0.f;
  #pragma unroll 4
  for (int k = 0; k < HID; ++k)
    acc += row[k] * We1[(size_t)(l * 384 + 256 + k) * HID + t];
  Wrp[(size_t)(l * CC + j) * HID + t] = acc;
}

// ---------------------------------------------------------------------------
// Batched weight shuffle: fp32 KxN -> B-fragment-linear bf16 (zero-padded).
// ---------------------------------------------------------------------------
constexpr int NSH = 26;
struct ShufArgs {
  const float* src[NSH];
  unsigned short* dst[NSH];
  int K[NSH], N[NSH], KT[NSH], NT[NSH];
};

__global__ void shufb_kernel(ShufArgs a) {
  int e = blockIdx.y;
  int K = a.K[e], N = a.N[e], NT = a.NT[e];
  int total = a.KT[e] * NT * 512;
  const float* W = a.src[e];
  unsigned short* out = a.dst[e];
  for (int idx = blockIdx.x * blockDim.x + threadIdx.x; idx < total;
       idx += gridDim.x * blockDim.x) {
    int j = idx & 7;
    int lane = (idx >> 3) & 63;
    int nt = (idx >> 9) % NT;
    int kt = idx / (512 * NT);
    int k = kt * 32 + ((lane >> 4) << 3) + j;
    int n = nt * 16 + (lane & 15);
    float v = (k < K && n < N) ? W[(size_t)k * N + n] : 0.f;
    out[idx] = f2bu(v);
  }
}

// Htab = E_tab @ Win (20x128); cwtab = row-softmax(Wchan) (20x14)
__global__ __launch_bounds__(128) void htab_kernel(const float* __restrict__ Et,
                                                   const float* __restrict__ Win,
                                                   const float* __restrict__ Wch,
                                                   float* __restrict__ Htab,
                                                   float* __restrict__ cwtab) {
  int r = blockIdx.x, t = threadIdx.x;
  __shared__ float e[HID];
  e[t] = Et[r * HID + t];
  __syncthreads();
  float acc = 0.f;
  #pragma unroll 4
  for (int k = 0; k < HID; ++k) acc += e[k] * Win[k * HID + t];
  Htab[r * HID + t] = acc;
  if (t == 0) {
    float v[Cc];
    float mx = -1e30f;
    for (int c = 0; c < Cc; ++c) { v[c] = Wch[r * Cc + c]; mx = fmaxf(mx, v[c]); }
    float s = 0.f;
    for (int c = 0; c < Cc; ++c) { v[c] = __expf(v[c] - mx); s += v[c]; }
    float inv = 1.0f / s;
    for (int c = 0; c < Cc; ++c) cwtab[r * Cc + c] = v[c] * inv;
  }
}

// h[n] = Htab[S[n]]
__global__ void gather_kernel(const int* __restrict__ S, const float* __restrict__ Htab,
                              float* __restrict__ h) {
  int stride = gridDim.x * blockDim.x;
  for (int i = blockIdx.x * blockDim.x + threadIdx.x; i < Nn * HID; i += stride)
    h[i] = Htab[clampi(S[i >> 7], NCLS) * HID + (i & 127)];
}

// ---------------------------------------------------------------------------
// Extract CA coords to compact global SoA: posG[comp][axis][PSTR]
// ---------------------------------------------------------------------------
constexpr int PSTR = 2512;

__global__ void posx_kernel(const float* __restrict__ X, float* __restrict__ posG) {
  int total = Bc * PSTR;
  for (int i = blockIdx.x * blockDim.x + threadIdx.x; i < total;
       i += gridDim.x * blockDim.x) {
    int comp = i / PSTR, j = i - comp * PSTR;
    float x = 1e30f, y = 1e30f, z = 1e30f;
    if (j < Lc) {
      size_t g = (size_t)(comp * Lc + j) * X3;
      x = X[g + 3]; y = X[g + 4]; z = X[g + 5];
    }
    float* b = posG + (size_t)comp * 3 * PSTR;
    b[j] = x; b[PSTR + j] = y; b[2 * PSTR + j] = z;
  }
}

// ---------------------------------------------------------------------------
// kNN, zero-LDS (unchanged from round 11/12)
// ---------------------------------------------------------------------------
constexpr int KR2 = 8;
constexpr int KC2 = 80;

__global__ __launch_bounds__(256) void knn_kernel(const float* __restrict__ posG,
                                                  int* __restrict__ nbr) {
  constexpr int bpc = (Lc + KR2 - 1) / KR2;   // 313
  int comp = blockIdx.x / bpc, rb = blockIdx.x % bpc;
  int t = threadIdx.x;
  int rl = t >> 5, q = t & 31;
  int r = rb * KR2 + rl;
  const float* px = posG + (size_t)comp * 3 * PSTR;
  const float* py = px + PSTR;
  const float* pz = py + PSTR;

  float bd[Kc];
  int   bi[Kc];
  #pragma unroll
  for (int k = 0; k < Kc; ++k) { bd[k] = __int_as_float(0x7f800000); bi[k] = 0x7fffffff; }

  if (r < Lc) {
    float rx = px[r], ry = py[r], rz = pz[r];
    int c0 = q * KC2;
    int c1 = c0 + KC2; if (c1 > Lc) c1 = Lc;
    for (int i = c0; i < c1; i += 4) {
      float4 xs = *(const float4*)(px + i);
      float4 ys = *(const float4*)(py + i);
      float4 zs = *(const float4*)(pz + i);
      float d2v[4];
      {
        float dx, dy, dz;
        dx = rx - xs.x; dy = ry - ys.x; dz = rz - zs.x; d2v[0] = dx*dx + dy*dy + dz*dz;
        dx = rx - xs.y; dy = ry - ys.y; dz = rz - zs.y; d2v[1] = dx*dx + dy*dy + dz*dz;
        dx = rx - xs.z; dy = ry - ys.z; dz = rz - zs.z; d2v[2] = dx*dx + dy*dy + dz*dz;
        dx = rx - xs.w; dy = ry - ys.w; dz = rz - zs.w; d2v[3] = dx*dx + dy*dy + dz*dz;
      }
      #pragma unroll
      for (int u = 0; u < 4; ++u) {
        int ii = i + u;
        float d2 = d2v[u];
        if (ii != r && d2 < bd[Kc - 1]) {
          bd[Kc - 1] = d2; bi[Kc - 1] = ii;
          #pragma unroll
          for (int p = Kc - 1; p > 0; --p) {
            if (bd[p] < bd[p - 1]) {
              float td = bd[p]; bd[p] = bd[p - 1]; bd[p - 1] = td;
              int   ti = bi[p]; bi[p] = bi[p - 1]; bi[p - 1] = ti;
            }
          }
        }
      }
    }
  }

  int gbase = (comp * Lc + r) * Kc;
  #pragma unroll
  for (int k = 0; k < Kc; ++k) {
    unsigned long long mykey =
        ((unsigned long long)__float_as_uint(bd[0]) << 32) | (unsigned int)bi[0];
    unsigned long long w = mykey;
    #pragma unroll
    for (int m = 1; m <= 16; m <<= 1) {
      unsigned long long o = __shfl_xor(w, m);
      if (o < w) w = o;
    }
    if (r < Lc && q == k)
      nbr[gbase + k] = comp * Lc + (int)(unsigned int)(w & 0xffffffffULL);
    if (mykey == w) {
      #pragma unroll
      for (int s = 0; s < Kc - 1; ++s) { bd[s] = bd[s + 1]; bi[s] = bi[s + 1]; }
      bd[Kc - 1] = __int_as_float(0x7f800000); bi[Kc - 1] = 0x7fffffff;
    }
  }
}

// ---------------------------------------------------------------------------
// MFMA node AB (layer 0): hA = h@We1a + be1, hB = h@We1b.  16 nodes/block.
// ---------------------------------------------------------------------------
__global__ __launch_bounds__(256) void nodeABm_kernel(
    const float* __restrict__ h,
    const unsigned short* __restrict__ We1a_s, const unsigned short* __restrict__ We1b_s,
    const float* __restrict__ be1n, bf16* __restrict__ hA, bf16* __restrict__ hB) {
  __shared__ __align__(16) unsigned short sB[4 * 512];
  int t = threadIdx.x, n0 = blockIdx.x * 16;
  int lane = t & 63, wv = t >> 6, quad = lane >> 4, l15 = lane & 15, wnb = wv << 5;

  for (int o = t; o < 16 * HID; o += 256) {
    int row = o >> 7, k = o & 127;
    sB[fragoff(row, k, 1)] = f2bu(h[(size_t)(n0 + row) * HID + k]);
  }
  __syncthreads();

  f32x4 a3[2] = {{0,0,0,0},{0,0,0,0}}, a4[2] = {{0,0,0,0},{0,0,0,0}};
  const sh8* sBv = (const sh8*)sB;
  for (int kt = 0; kt < 4; ++kt) {
    sh8 a = sBv[kt * 64 + lane];
    sh8 b0 = ((const sh8*)We1a_s)[((kt << 3) + (wv << 1) + 0) * 64 + lane];
    sh8 b1 = ((const sh8*)We1a_s)[((kt << 3) + (wv << 1) + 1) * 64 + lane];
    sh8 c0 = ((const sh8*)We1b_s)[((kt << 3) + (wv << 1) + 0) * 64 + lane];
    sh8 c1 = ((const sh8*)We1b_s)[((kt << 3) + (wv << 1) + 1) * 64 + lane];
    a3[0] = mfma16(a, b0, a3[0]); a3[1] = mfma16(a, b1, a3[1]);
    a4[0] = mfma16(a, c0, a4[0]); a4[1] = mfma16(a, c1, a4[1]);
  }
  #pragma unroll
  for (int nl = 0; nl < 2; ++nl) {
    int col = wnb + (nl << 4) + l15;
    float be = be1n[col];
    #pragma unroll
    for (int r = 0; r < 4; ++r) {
      int row = (quad << 2) + r;
      hA[(size_t)(n0 + row) * HID + col] = __float2bfloat16(a3[nl][r] + be);
      hB[(size_t)(n0 + row) * HID + col] = __float2bfloat16(a4[nl][r]);
    }
  }
}

// ---------------------------------------------------------------------------
// MFMA fused node update + next AB
// ---------------------------------------------------------------------------
__global__ __launch_bounds__(256) void fupdAB_kernel(
    float* __restrict__ h, const bf16* __restrict__ aggm,
    const unsigned short* __restrict__ Wh1_s, const unsigned short* __restrict__ Wh2_s,
    const unsigned short* __restrict__ We1a_s, const unsigned short* __restrict__ We1b_s,
    const float* __restrict__ be1n, bf16* __restrict__ hA, bf16* __restrict__ hB) {
  __shared__ __align__(16) unsigned short sA[8 * 512];
  __shared__ __align__(16) unsigned short sB[4 * 512];
  int t = threadIdx.x, n0 = blockIdx.x * 16;
  int lane = t & 63, wv = t >> 6, quad = lane >> 4, l15 = lane & 15, wnb = wv << 5;

  for (int o = t; o < 16 * 256; o += 256) {
    int row = o >> 8, k = o & 255;
    float v = (k < HID) ? h[(size_t)(n0 + row) * HID + k]
                        : b2f(aggm[(size_t)(n0 + row) * HID + (k - HID)]);
    sA[fragoff(row, k, 1)] = f2bu(v);
  }
  __syncthreads();

  f32x4 a1[2] = {{0,0,0,0},{0,0,0,0}};
  const sh8* sAv = (const sh8*)sA;
  for (int kt = 0; kt < 8; ++kt) {
    sh8 a = sAv[kt * 64 + lane];
    sh8 b0 = ((const sh8*)Wh1_s)[((kt << 3) + (wv << 1) + 0) * 64 + lane];
    sh8 b1 = ((const sh8*)Wh1_s)[((kt << 3) + (wv << 1) + 1) * 64 + lane];
    a1[0] = mfma16(a, b0, a1[0]);
    a1[1] = mfma16(a, b1, a1[1]);
  }
  #pragma unroll
  for (int nl = 0; nl < 2; ++nl) {
    int col = wnb + (nl << 4) + l15;
    #pragma unroll
    for (int r = 0; r < 4; ++r)
      sB[fragoff((quad << 2) + r, col, 1)] = f2bu(siluf(a1[nl][r]));
  }
  __syncthreads();

  f32x4 a2[2] = {{0,0,0,0},{0,0,0,0}};
  const sh8* sBv = (const sh8*)sB;
  for (int kt = 0; kt < 4; ++kt) {
    sh8 a = sBv[kt * 64 + lane];
    sh8 b0 = ((const sh8*)Wh2_s)[((kt << 3) + (wv << 1) + 0) * 64 + lane];
    sh8 b1 = ((const sh8*)Wh2_s)[((kt << 3) + (wv << 1) + 1) * 64 + lane];
    a2[0] = mfma16(a, b0, a2[0]);
    a2[1] = mfma16(a, b1, a2[1]);
  }
  float hn[2][4];
  #pragma unroll
  for (int nl = 0; nl < 2; ++nl) {
    int col = wnb + (nl << 4) + l15;
    #pragma unroll
    for (int r = 0; r < 4; ++r) {
      int row = (quad << 2) + r;
      float v = h[(size_t)(n0 + row) * HID + col] + a2[nl][r];
      h[(size_t)(n0 + row) * HID + col] = v;
      hn[nl][r] = v;
    }
  }
  __syncthreads();
  #pragma unroll
  for (int nl = 0; nl < 2; ++nl) {
    int col = wnb + (nl << 4) + l15;
    #pragma unroll
    for (int r = 0; r < 4; ++r)
      sB[fragoff((quad << 2) + r, col, 1)] = f2bu(hn[nl][r]);
  }
  __syncthreads();

  f32x4 a3[2] = {{0,0,0,0},{0,0,0,0}}, a4[2] = {{0,0,0,0},{0,0,0,0}};
  for (int kt = 0; kt < 4; ++kt) {
    sh8 a = sBv[kt * 64 + lane];
    sh8 b0 = ((const sh8*)We1a_s)[((kt << 3) + (wv << 1) + 0) * 64 + lane];
    sh8 b1 = ((const sh8*)We1a_s)[((kt << 3) + (wv << 1) + 1) * 64 + lane];
    sh8 c0 = ((const sh8*)We1b_s)[((kt << 3) + (wv << 1) + 0) * 64 + lane];
    sh8 c1 = ((const sh8*)We1b_s)[((kt << 3) + (wv << 1) + 1) * 64 + lane];
    a3[0] = mfma16(a, b0, a3[0]); a3[1] = mfma16(a, b1, a3[1]);
    a4[0] = mfma16(a, c0, a4[0]); a4[1] = mfma16(a, c1, a4[1]);
  }
  #pragma unroll
  for (int nl = 0; nl < 2; ++nl) {
    int col = wnb + (nl << 4) + l15;
    float be = be1n[col];
    #pragma unroll
    for (int r = 0; r < 4; ++r) {
      int row = (quad << 2) + r;
      hA[(size_t)(n0 + row) * HID + col] = __float2bfloat16(a3[nl][r] + be);
      hB[(size_t)(n0 + row) * HID + col] = __float2bfloat16(a4[nl][r]);
    }
  }
}

// ---------------------------------------------------------------------------
// MFMA fused last node update + final FFN
// ---------------------------------------------------------------------------
__global__ __launch_bounds__(256) void fupdF_kernel(
    const float* __restrict__ h, const bf16* __restrict__ aggm,
    const unsigned short* __restrict__ Wh1_s, const unsigned short* __restrict__ Wh2_s,
    const unsigned short* __restrict__ Wf1_s, const unsigned short* __restrict__ Wf2_s,
    float* __restrict__ out) {
  __shared__ __align__(16) unsigned short sA[8 * 512];
  __shared__ __align__(16) unsigned short sB[4 * 512];
  int t = threadIdx.x, n0 = blockIdx.x * 16;
  int lane = t & 63, wv = t >> 6, quad = lane >> 4, l15 = lane & 15, wnb = wv << 5;

  for (int o = t; o < 16 * 256; o += 256) {
    int row = o >> 8, k = o & 255;
    float v = (k < HID) ? h[(size_t)(n0 + row) * HID + k]
                        : b2f(aggm[(size_t)(n0 + row) * HID + (k - HID)]);
    sA[fragoff(row, k, 1)] = f2bu(v);
  }
  __syncthreads();

  f32x4 a1[2] = {{0,0,0,0},{0,0,0,0}};
  const sh8* sAv = (const sh8*)sA;
  for (int kt = 0; kt < 8; ++kt) {
    sh8 a = sAv[kt * 64 + lane];
    sh8 b0 = ((const sh8*)Wh1_s)[((kt << 3) + (wv << 1) + 0) * 64 + lane];
    sh8 b1 = ((const sh8*)Wh1_s)[((kt << 3) + (wv << 1) + 1) * 64 + lane];
    a1[0] = mfma16(a, b0, a1[0]);
    a1[1] = mfma16(a, b1, a1[1]);
  }
  #pragma unroll
  for (int nl = 0; nl < 2; ++nl) {
    int col = wnb + (nl << 4) + l15;
    #pragma unroll
    for (int r = 0; r < 4; ++r)
      sB[fragoff((quad << 2) + r, col, 1)] = f2bu(siluf(a1[nl][r]));
  }
  __syncthreads();

  f32x4 a2[2] = {{0,0,0,0},{0,0,0,0}};
  const sh8* sBv = (const sh8*)sB;
  for (int kt = 0; kt < 4; ++kt) {
    sh8 a = sBv[kt * 64 + lane];
    sh8 b0 = ((const sh8*)Wh2_s)[((kt << 3) + (wv << 1) + 0) * 64 + lane];
    sh8 b1 = ((const sh8*)Wh2_s)[((kt << 3) + (wv << 1) + 1) * 64 + lane];
    a2[0] = mfma16(a, b0, a2[0]);
    a2[1] = mfma16(a, b1, a2[1]);
  }
  float u2[2][4];
  #pragma unroll
  for (int nl = 0; nl < 2; ++nl) {
    int col = wnb + (nl << 4) + l15;
    #pragma unroll
    for (int r = 0; r < 4; ++r) {
      int row = (quad << 2) + r;
      u2[nl][r] = siluf(h[(size_t)(n0 + row) * HID + col] + a2[nl][r]);
    }
  }
  __syncthreads();
  #pragma unroll
  for (int nl = 0; nl < 2; ++nl) {
    int col = wnb + (nl << 4) + l15;
    #pragma unroll
    for (int r = 0; r < 4; ++r)
      sB[fragoff((quad << 2) + r, col, 1)] = f2bu(u2[nl][r]);
  }
  __syncthreads();

  f32x4 a3[2] = {{0,0,0,0},{0,0,0,0}};
  for (int kt = 0; kt < 4; ++kt) {
    sh8 a = sBv[kt * 64 + lane];
    sh8 b0 = ((const sh8*)Wf1_s)[((kt << 3) + (wv << 1) + 0) * 64 + lane];
    sh8 b1 = ((const sh8*)Wf1_s)[((kt << 3) + (wv << 1) + 1) * 64 + lane];
    a3[0] = mfma16(a, b0, a3[0]);
    a3[1] = mfma16(a, b1, a3[1]);
  }
  #pragma unroll
  for (int nl = 0; nl < 2; ++nl) {
    int col = wnb + (nl << 4) + l15;
    #pragma unroll
    for (int r = 0; r < 4; ++r)
      sA[fragoff((quad << 2) + r, col, 1)] = f2bu(siluf(a3[nl][r]));
  }
  __syncthreads();

  if (wv < 2) {
    f32x4 a5 = {0.f, 0.f, 0.f, 0.f};
    for (int kt = 0; kt < 4; ++kt) {
      sh8 a = sAv[kt * 64 + lane];
      sh8 b = ((const sh8*)Wf2_s)[(kt * 2 + wv) * 64 + lane];
      a5 = mfma16(a, b, a5);
    }
    int col = (wv << 4) + l15;
    if (col < NCLS) {
      #pragma unroll
      for (int r = 0; r < 4; ++r) {
        int row = (quad << 2) + r;
        out[(size_t)(n0 + row) * NCLS + col] = a5[r];
      }
    }
  }
}

// ---------------------------------------------------------------------------
// MFMA edge kernel — rad loop restructured (no divisions, register xd),
// uint4 zero-init, fast silu.
// ---------------------------------------------------------------------------
constexpr int GN  = 4;
constexpr int NE  = GN * Kc;     // 36
constexpr int MT3 = 3;           // m-tiles (M padded to 48)

__global__ __launch_bounds__(256) void edge_kernel(
    const float* __restrict__ Xin, float* __restrict__ Xout,
    const bf16* __restrict__ hA, const bf16* __restrict__ hB,
    const int* __restrict__ S, const float* __restrict__ cwtab,
    const int* __restrict__ nbr,
    const unsigned short* __restrict__ Wrp_s, const unsigned short* __restrict__ We2_s,
    const unsigned short* __restrict__ Wx1_s, const unsigned short* __restrict__ Wx2_s,
    bf16* __restrict__ aggm) {
  __shared__ __align__(16) unsigned short s_R1[48 * 224];
  __shared__ __align__(16) unsigned short s_R2[48 * 128];
  __shared__ __align__(16) unsigned short s_xd[NE * 44];
  __shared__ __align__(16) unsigned short s_hB[NE * 130];
  __shared__ __align__(16) unsigned short s_hA[GN * 128];
  __shared__ float s_cw[GN * Cc];
  __shared__ int   s_dst[NE];

  int t = threadIdx.x;
  int n0 = blockIdx.x * GN;
  int lane = t & 63, wv = t >> 6;
  int quad = lane >> 4, l15 = lane & 15;
  int wnb = wv << 5;

  if (t < NE) s_dst[t] = clampi(nbr[n0 * Kc + t], Nn);
  if (t >= 64 && t < 64 + GN * Cc) {
    int o = t - 64;
    s_cw[o] = cwtab[clampi(S[n0 + o / Cc], NCLS) * Cc + o % Cc];
  }
  {
    uint4* r1 = (uint4*)s_R1;       // 48*224*2B = 1344 uint4
    for (int o = t; o < 1344; o += 256) r1[o] = make_uint4(0u, 0u, 0u, 0u);
    uint4* r2 = (uint4*)s_R2;       // 48*128*2B = 768 uint4
    for (int o = t; o < 768; o += 256) r2[o] = make_uint4(0u, 0u, 0u, 0u);
    const unsigned int* src = (const unsigned int*)(hA + (size_t)n0 * HID);
    unsigned int* dA = (unsigned int*)s_hA;
    for (int o = t; o < GN * 64; o += 256) dA[o] = src[o];
  }
  __syncthreads();

  for (int o = t; o < NE * X3; o += 256) {
    int e = o / X3, i = o - e * X3;
    float v = Xin[(size_t)(n0 + e / Kc) * X3 + i] - Xin[(size_t)s_dst[e] * X3 + i];
    s_xd[e * 44 + i] = f2bu(v);
  }
  {
    unsigned int* d = (unsigned int*)s_hB;
    const unsigned int* hb = (const unsigned int*)hB;
    for (int o = t; o < NE * 64; o += 256) {
      int e = o >> 6, w = o & 63;
      d[e * 65 + w] = hb[(size_t)s_dst[e] * 64 + w];
    }
  }
  __syncthreads();

  // ---- rad -> R1 frag-linear: thread = (e, jc); 28 j's per thread, no div ----
  if (t < 252) {
    int e = t / 7, jc = t - (t / 7) * 7;   // e in [0,36), jc in [0,7)
    const unsigned int* xu = (const unsigned int*)(s_xd + e * 44);
    unsigned int u[21];
    #pragma unroll
    for (int i = 0; i < 21; ++i) u[i] = xu[i];
    float xdv[42];
    #pragma unroll
    for (int i = 0; i < 21; ++i) unpk2(u[i], xdv[2 * i], xdv[2 * i + 1]);
    #pragma unroll
    for (int half = 0; half < 2; ++half) {
      int c = 2 * jc + half;                // [0,14)
      const unsigned short* xe = s_xd + e * 44;
      float xc0 = b2fu(xe[c * 3 + 0]);
      float xc1 = b2fu(xe[c * 3 + 1]);
      float xc2 = b2fu(xe[c * 3 + 2]);
      int jbase = c * Cc;                   // j = c*14 + d
      #pragma unroll
      for (int d = 0; d < 14; ++d) {
        float v = (xc0 * xdv[d * 3 + 0] + xc1 * xdv[d * 3 + 1] +
                   xc2 * xdv[d * 3 + 2]) * (1.0f / 14.0f);
        s_R1[fragoff(e, jbase + d, MT3)] = f2bu(v);
      }
    }
  }
  __syncthreads();

  f32x4 acc1[MT3][2];
  #pragma unroll
  for (int mt = 0; mt < MT3; ++mt)
    #pragma unroll
    for (int nl = 0; nl < 2; ++nl) acc1[mt][nl] = (f32x4){0.f, 0.f, 0.f, 0.f};
  const sh8* r1v = (const sh8*)s_R1;
  for (int kt = 0; kt < 7; ++kt) {
    sh8 b0 = ((const sh8*)Wrp_s)[((kt << 3) + (wv << 1) + 0) * 64 + lane];
    sh8 b1 = ((const sh8*)Wrp_s)[((kt << 3) + (wv << 1) + 1) * 64 + lane];
    #pragma unroll
    for (int mt = 0; mt < MT3; ++mt) {
      sh8 a = r1v[(kt * MT3 + mt) * 64 + lane];
      acc1[mt][0] = mfma16(a, b0, acc1[mt][0]);
      acc1[mt][1] = mfma16(a, b1, acc1[mt][1]);
    }
  }
  #pragma unroll
  for (int mt = 0; mt < MT3; ++mt)
    #pragma unroll
    for (int nl = 0; nl < 2; ++nl) {
      int col = wnb + (nl << 4) + l15;
      #pragma unroll
      for (int r = 0; r < 4; ++r) {
        int row = (mt << 4) + (quad << 2) + r;
        if (row < NE) {
          float v = acc1[mt][nl][r] + b2fu(s_hA[((row / Kc) << 7) + col]) +
                    b2fu(s_hB[row * 130 + col]);
          s_R2[fragoff(row, col, MT3)] = f2bu(siluf(v));
        }
      }
    }
  __syncthreads();

  f32x4 acc2[MT3][2];
  #pragma unroll
  for (int mt = 0; mt < MT3; ++mt)
    #pragma unroll
    for (int nl = 0; nl < 2; ++nl) acc2[mt][nl] = (f32x4){0.f, 0.f, 0.f, 0.f};
  const sh8* r2v = (const sh8*)s_R2;
  for (int kt = 0; kt < 4; ++kt) {
    sh8 b0 = ((const sh8*)We2_s)[((kt << 3) + (wv << 1) + 0) * 64 + lane];
    sh8 b1 = ((const sh8*)We2_s)[((kt << 3) + (wv << 1) + 1) * 64 + lane];
    #pragma unroll
    for (int mt = 0; mt < MT3; ++mt) {
      sh8 a = r2v[(kt * MT3 + mt) * 64 + lane];
      acc2[mt][0] = mfma16(a, b0, acc2[mt][0]);
      acc2[mt][1] = mfma16(a, b1, acc2[mt][1]);
    }
  }
  __syncthreads();
  #pragma unroll
  for (int mt = 0; mt < MT3; ++mt)
    #pragma unroll
    for (int nl = 0; nl < 2; ++nl) {
      int col = wnb + (nl << 4) + l15;
      #pragma unroll
      for (int r = 0; r < 4; ++r) {
        int row = (mt << 4) + (quad << 2) + r;
        s_R2[fragoff(row, col, MT3)] = f2bu(siluf(acc2[mt][nl][r]));
      }
    }
  __syncthreads();

  for (int o = t; o < GN * HID; o += 256) {
    int g = o >> 7, col = o & 127;
    float s = 0.f;
    #pragma unroll
    for (int k = 0; k < Kc; ++k) s += b2fu(s_R2[fragoff(g * Kc + k, col, MT3)]);
    aggm[(size_t)(n0 + g) * HID + col] = __float2bfloat16(s);
  }
  f32x4 acc3[MT3][2];
  #pragma unroll
  for (int mt = 0; mt < MT3; ++mt)
    #pragma unroll
    for (int nl = 0; nl < 2; ++nl) acc3[mt][nl] = (f32x4){0.f, 0.f, 0.f, 0.f};
  for (int kt = 0; kt < 4; ++kt) {
    sh8 b0 = ((const sh8*)Wx1_s)[((kt << 3) + (wv << 1) + 0) * 64 + lane];
    sh8 b1 = ((const sh8*)Wx1_s)[((kt << 3) + (wv << 1) + 1) * 64 + lane];
    #pragma unroll
    for (int mt = 0; mt < MT3; ++mt) {
      sh8 a = r2v[(kt * MT3 + mt) * 64 + lane];
      acc3[mt][0] = mfma16(a, b0, acc3[mt][0]);
      acc3[mt][1] = mfma16(a, b1, acc3[mt][1]);
    }
  }
  #pragma unroll
  for (int mt = 0; mt < MT3; ++mt)
    #pragma unroll
    for (int nl = 0; nl < 2; ++nl) {
      int col = wnb + (nl << 4) + l15;
      #pragma unroll
      for (int r = 0; r < 4; ++r) {
        int row = (mt << 4) + (quad << 2) + r;
        s_R1[fragoff(row, col, MT3)] = f2bu(siluf(acc3[mt][nl][r]));
      }
    }
  __syncthreads();

  float* s_coef = (float*)s_R2;
  if (wv == 0) {
    f32x4 a4[MT3];
    #pragma unroll
    for (int mt = 0; mt < MT3; ++mt) a4[mt] = (f32x4){0.f, 0.f, 0.f, 0.f};
    for (int kt = 0; kt < 4; ++kt) {
      sh8 b = ((const sh8*)Wx2_s)[kt * 64 + lane];
      #pragma unroll
      for (int mt = 0; mt < MT3; ++mt) {
        sh8 a = r1v[(kt * MT3 + mt) * 64 + lane];
        a4[mt] = mfma16(a, b, a4[mt]);
      }
    }
    #pragma unroll
    for (int mt = 0; mt < MT3; ++mt)
      #pragma unroll
      for (int r = 0; r < 4; ++r) {
        int row = (mt << 4) + (quad << 2) + r;
        s_coef[(row << 4) + l15] = a4[mt][r];
      }
  }
  __syncthreads();

  for (int o = t; o < GN * X3; o += 256) {
    int g = o / X3, rem = o - g * X3, c = rem / 3;
    float s = 0.f;
    #pragma unroll
    for (int k = 0; k < Kc; ++k) {
      int e = g * Kc + k;
      s += b2fu(s_xd[e * 44 + rem]) * s_coef[(e << 4) + c];
    }
    int gn = n0 + g;
    Xout[(size_t)gn * X3 + rem] =
        Xin[(size_t)gn * X3 + rem] + s * s_cw[g * Cc + c] * (1.0f / 9.0f);
  }
}

// ---------------------------------------------------------------------------
extern "C" void kernel_launch(void* const* d_in, const int* in_sizes, int n_in,
                              void* d_out, int out_size, void* d_ws, size_t ws_size,
                              hipStream_t stream) {
  const float* X    = (const float*)d_in[0];
  const int*   S    = (const int*)d_in[1];
  const float* Etab = (const float*)d_in[2];
  const float* Wch  = (const float*)d_in[3];
  const float* Win  = (const float*)d_in[4];
  const float* Wr   = (const float*)d_in[5];
  const float* We1  = (const float*)d_in[6];
  const float* be1  = (const float*)d_in[7];
  const float* We2  = (const float*)d_in[8];
  const float* Wx1  = (const float*)d_in[9];
  const float* Wx2  = (const float*)d_in[10];
  const float* Wh1  = (const float*)d_in[11];
  const float* Wh2  = (const float*)d_in[12];
  const float* Wf1  = (const float*)d_in[13];
  const float* Wf2  = (const float*)d_in[14];
  (void)in_sizes; (void)n_in; (void)out_size; (void)ws_size;

  char* base = (char*)d_ws;
  size_t off = 0;
  auto alloc = [&](size_t bytes) {
    void* p = base + off;
    off += (bytes + 255) & ~(size_t)255;
    return p;
  };
  int*   nbr   = (int*)  alloc((size_t)Nn * Kc * 4);
  float* Htab  = (float*)alloc(NCLS * HID * 4);
  float* cwtab = (float*)alloc(NCLS * Cc * 4);
  float* Wrpf  = (float*)alloc((size_t)NL * CC * HID * 4);
  float* posG  = (float*)alloc((size_t)Bc * 3 * PSTR * 4);
  float* Xa    = (float*)alloc((size_t)Nn * X3 * 4);
  float* Xb    = (float*)alloc((size_t)Nn * X3 * 4);
  float* hv    = (float*)alloc((size_t)Nn * HID * 4);
  bf16*  hAv   = (bf16*) alloc((size_t)Nn * HID * 2);
  bf16*  hBv   = (bf16*) alloc((size_t)Nn * HID * 2);
  bf16*  aggmv = (bf16*) alloc((size_t)Nn * HID * 2);
  constexpr int WRP_SZ = 7 * 8 * 512;
  constexpr int W128_SZ = 4 * 8 * 512;
  constexpr int WX2_SZ = 4 * 1 * 512;
  constexpr int WH1_SZ = 8 * 8 * 512;
  constexpr int WF2_SZ = 4 * 2 * 512;
  unsigned short* Wrp_s  = (unsigned short*)alloc((size_t)NL * WRP_SZ * 2);
  unsigned short* We2_s  = (unsigned short*)alloc((size_t)NL * W128_SZ * 2);
  unsigned short* Wx1_s  = (unsigned short*)alloc((size_t)NL * W128_SZ * 2);
  unsigned short* Wx2_s  = (unsigned short*)alloc((size_t)NL * WX2_SZ * 2);
  unsigned short* Wh1_s  = (unsigned short*)alloc((size_t)NL * WH1_SZ * 2);
  unsigned short* Wh2_s  = (unsigned short*)alloc((size_t)NL * W128_SZ * 2);
  unsigned short* We1a_s = (unsigned short*)alloc((size_t)NL * W128_SZ * 2);
  unsigned short* We1b_s = (unsigned short*)alloc((size_t)NL * W128_SZ * 2);
  unsigned short* Wf1_s  = (unsigned short*)alloc(W128_SZ * 2);
  unsigned short* Wf2_s  = (unsigned short*)alloc(WF2_SZ * 2);

  wrp_kernel<<<NL * CC, 128, 0, stream>>>(Wr, We1, Wrpf);
  htab_kernel<<<NCLS, 128, 0, stream>>>(Etab, Win, Wch, Htab, cwtab);
  gather_kernel<<<512, 256, 0, stream>>>(S, Htab, hv);
  posx_kernel<<<79, 256, 0, stream>>>(X, posG);
  knn_kernel<<<Bc * ((Lc + KR2 - 1) / KR2), 256, 0, stream>>>(posG, nbr);

  ShufArgs sa;
  for (int l = 0; l < NL; ++l) {
    int e = l * 8;
    sa.src[e+0] = Wrpf + (size_t)l * CC * HID;       sa.dst[e+0] = Wrp_s  + (size_t)l * WRP_SZ;
    sa.K[e+0] = CC;  sa.N[e+0] = HID; sa.KT[e+0] = 7; sa.NT[e+0] = 8;
    sa.src[e+1] = We2 + (size_t)l * HID * HID;       sa.dst[e+1] = We2_s  + (size_t)l * W128_SZ;
    sa.K[e+1] = HID; sa.N[e+1] = HID; sa.KT[e+1] = 4; sa.NT[e+1] = 8;
    sa.src[e+2] = Wx1 + (size_t)l * HID * HID;       sa.dst[e+2] = Wx1_s  + (size_t)l * W128_SZ;
    sa.K[e+2] = HID; sa.N[e+2] = HID; sa.KT[e+2] = 4; sa.NT[e+2] = 8;
    sa.src[e+3] = Wx2 + (size_t)l * HID * Cc;        sa.dst[e+3] = Wx2_s  + (size_t)l * WX2_SZ;
    sa.K[e+3] = HID; sa.N[e+3] = Cc;  sa.KT[e+3] = 4; sa.NT[e+3] = 1;
    sa.src[e+4] = Wh1 + (size_t)l * 256 * HID;       sa.dst[e+4] = Wh1_s  + (size_t)l * WH1_SZ;
    sa.K[e+4] = 256; sa.N[e+4] = HID; sa.KT[e+4] = 8; sa.NT[e+4] = 8;
    sa.src[e+5] = Wh2 + (size_t)l * HID * HID;       sa.dst[e+5] = Wh2_s  + (size_t)l * W128_SZ;
    sa.K[e+5] = HID; sa.N[e+5] = HID; sa.KT[e+5] = 4; sa.NT[e+5] = 8;
    sa.src[e+6] = We1 + (size_t)l * 384 * HID;       sa.dst[e+6] = We1a_s + (size_t)l * W128_SZ;
    sa.K[e+6] = HID; sa.N[e+6] = HID; sa.KT[e+6] = 4; sa.NT[e+6] = 8;
    sa.src[e+7] = We1 + (size_t)l * 384 * HID + (size_t)HID * HID;
    sa.dst[e+7] = We1b_s + (size_t)l * W128_SZ;
    sa.K[e+7] = HID; sa.N[e+7] = HID; sa.KT[e+7] = 4; sa.NT[e+7] = 8;
  }
  sa.src[24] = Wf1; sa.dst[24] = Wf1_s; sa.K[24] = HID; sa.N[24] = HID;
  sa.KT[24] = 4; sa.NT[24] = 8;
  sa.src[25] = Wf2; sa.dst[25] = Wf2_s; sa.K[25] = HID; sa.N[25] = NCLS;
  sa.KT[25] = 4; sa.NT[25] = 2;
  shufb_kernel<<<dim3(16, NSH), 256, 0, stream>>>(sa);

  nodeABm_kernel<<<Nn / 16, 256, 0, stream>>>(hv, We1a_s, We1b_s, be1, hAv, hBv);

  float* out = (float*)d_out;
  float* outX = out + (size_t)Nn * NCLS;
  const float* Xi = X;
  for (int l = 0; l < NL; ++l) {
    float* Xo = (l == NL - 1) ? outX : ((l == 0) ? Xb : Xa);
    edge_kernel<<<Nn / GN, 256, 0, stream>>>(
        Xi, Xo, hAv, hBv, S, cwtab, nbr,
        Wrp_s + (size_t)l * WRP_SZ, We2_s + (size_t)l * W128_SZ,
        Wx1_s + (size_t)l * W128_SZ, Wx2_s + (size_t)l * WX2_SZ, aggmv);
    if (l < NL - 1) {
      fupdAB_kernel<<<Nn / 16, 256, 0, stream>>>(
          hv, aggmv, Wh1_s + (size_t)l * WH1_SZ, Wh2_s + (size_t)l * W128_SZ,
          We1a_s + (size_t)(l + 1) * W128_SZ, We1b_s + (size_t)(l + 1) * W128_SZ,
          be1 + (l + 1) * HID, hAv, hBv);
    } else {
      fupdF_kernel<<<Nn / 16, 256, 0, stream>>>(
          hv, aggmv, Wh1_s + (size_t)l * WH1_SZ, Wh2_s + (size_t)l * W128_SZ,
          Wf1_s, Wf2_s, out);
    }
    Xi = Xo;
  }
}

// Round 14
// 497.018 us; speedup vs baseline: 6.2653x; 1.1456x over previous
//
#include <hip/hip_runtime.h>
#include <hip/hip_bf16.h>

typedef __hip_bfloat16 bf16;

// Problem constants
constexpr int Bc  = 8;
constexpr int Lc  = 2500;
constexpr int Cc  = 14;
constexpr int Kc  = 9;
constexpr int Nn  = Bc * Lc;     // 20000
constexpr int NCLS = 20;
constexpr int HID = 128;
constexpr int NL  = 3;
constexpr int CC  = Cc * Cc;     // 196
constexpr int X3  = Cc * 3;      // 42

typedef __bf16 bf16x8 __attribute__((ext_vector_type(8)));
typedef short  sh8    __attribute__((ext_vector_type(8)));
typedef float  f32x4  __attribute__((ext_vector_type(4)));

__device__ __forceinline__ float b2f(bf16 x) { return __bfloat162float(x); }
__device__ __forceinline__ float b2fu(unsigned short u) {
  return __uint_as_float(((unsigned int)u) << 16);
}
__device__ __forceinline__ unsigned short f2bu(float x) {
  bf16 h = __float2bfloat16(x);
  return *reinterpret_cast<unsigned short*>(&h);
}
// fast silu: v_exp-based expf + v_rcp (no full-precision divide)
__device__ __forceinline__ float siluf(float x) {
  return x * __builtin_amdgcn_rcpf(1.0f + __expf(-x));
}
__device__ __forceinline__ int clampi(int v, int n) {
  return ((unsigned)v < (unsigned)n) ? v : 0;
}
__device__ __forceinline__ void unpk2(unsigned int u, float& a, float& b) {
  a = __uint_as_float(u << 16);
  b = __uint_as_float(u & 0xffff0000u);
}

__device__ __forceinline__ f32x4 mfma16(sh8 a, sh8 b, f32x4 c) {
  return __builtin_amdgcn_mfma_f32_16x16x32_bf16(
      __builtin_bit_cast(bf16x8, a), __builtin_bit_cast(bf16x8, b), c, 0, 0, 0);
}

// A/activation fragment-linear offset (in shorts). MT m-tiles; tile = 512 shorts.
__device__ __forceinline__ int fragoff(int e, int k, int MT) {
  return (((k >> 5) * MT + (e >> 4)) << 9) +
         (((e & 15) + (((k >> 3) & 3) << 4)) << 3) + (k & 7);
}

// ---------------------------------------------------------------------------
// Wrp[l] = Wr[l] @ We1[l][256:384,:]  (fp32, fold radial proj into edge MLP)
// ---------------------------------------------------------------------------
__global__ __launch_bounds__(128) void wrp_kernel(const float* __restrict__ Wr,
                                                  const float* __restrict__ We1,
                                                  float* __restrict__ Wrp) {
  int l = blockIdx.x / CC, j = blockIdx.x % CC;
  int t = threadIdx.x;
  __shared__ float row[HID];
  row[t] = Wr[(size_t)(l * CC + j) * HID + t];
  __syncthreads();
  float acc = 0.f;
  #pragma unroll 4
  for (int k = 0; k < HID; ++k)
    acc += row[k] * We1[(size_t)(l * 384 + 256 + k) * HID + t];
  Wrp[(size_t)(l * CC + j) * HID + t] = acc;
}

// ---------------------------------------------------------------------------
// Batched weight shuffle: fp32 KxN -> B-fragment-linear bf16 (zero-padded).
// ---------------------------------------------------------------------------
constexpr int NSH = 26;
struct ShufArgs {
  const float* src[NSH];
  unsigned short* dst[NSH];
  int K[NSH], N[NSH], KT[NSH], NT[NSH];
};

__global__ void shufb_kernel(ShufArgs a) {
  int e = blockIdx.y;
  int K = a.K[e], N = a.N[e], NT = a.NT[e];
  int total = a.KT[e] * NT * 512;
  const float* W = a.src[e];
  unsigned short* out = a.dst[e];
  for (int idx = blockIdx.x * blockDim.x + threadIdx.x; idx < total;
       idx += gridDim.x * blockDim.x) {
    int j = idx & 7;
    int lane = (idx >> 3) & 63;
    int nt = (idx >> 9) % NT;
    int kt = idx / (512 * NT);
    int k = kt * 32 + ((lane >> 4) << 3) + j;
    int n = nt * 16 + (lane & 15);
    float v = (k < K && n < N) ? W[(size_t)k * N + n] : 0.f;
    out[idx] = f2bu(v);
  }
}

// Htab = E_tab @ Win (20x128); cwtab = row-softmax(Wchan) (20x14)
__global__ __launch_bounds__(128) void htab_kernel(const float* __restrict__ Et,
                                                   const float* __restrict__ Win,
                                                   const float* __restrict__ Wch,
                                                   float* __restrict__ Htab,
                                                   float* __restrict__ cwtab) {
  int r = blockIdx.x, t = threadIdx.x;
  __shared__ float e[HID];
  e[t] = Et[r * HID + t];
  __syncthreads();
  float acc = 0.f;
  #pragma unroll 4
  for (int k = 0; k < HID; ++k) acc += e[k] * Win[k * HID + t];
  Htab[r * HID + t] = acc;
  if (t == 0) {
    float v[Cc];
    float mx = -1e30f;
    for (int c = 0; c < Cc; ++c) { v[c] = Wch[r * Cc + c]; mx = fmaxf(mx, v[c]); }
    float s = 0.f;
    for (int c = 0; c < Cc; ++c) { v[c] = __expf(v[c] - mx); s += v[c]; }
    float inv = 1.0f / s;
    for (int c = 0; c < Cc; ++c) cwtab[r * Cc + c] = v[c] * inv;
  }
}

// ---------------------------------------------------------------------------
// Extract CA coords to compact global SoA: posG[comp][axis][PSTR]
// ---------------------------------------------------------------------------
constexpr int PSTR = 2512;

__global__ void posx_kernel(const float* __restrict__ X, float* __restrict__ posG) {
  int total = Bc * PSTR;
  for (int i = blockIdx.x * blockDim.x + threadIdx.x; i < total;
       i += gridDim.x * blockDim.x) {
    int comp = i / PSTR, j = i - comp * PSTR;
    float x = 1e30f, y = 1e30f, z = 1e30f;
    if (j < Lc) {
      size_t g = (size_t)(comp * Lc + j) * X3;
      x = X[g + 3]; y = X[g + 4]; z = X[g + 5];
    }
    float* b = posG + (size_t)comp * 3 * PSTR;
    b[j] = x; b[PSTR + j] = y; b[2 * PSTR + j] = z;
  }
}

// ---------------------------------------------------------------------------
// kNN, zero-LDS (unchanged)
// ---------------------------------------------------------------------------
constexpr int KR2 = 8;
constexpr int KC2 = 80;

__global__ __launch_bounds__(256) void knn_kernel(const float* __restrict__ posG,
                                                  int* __restrict__ nbr) {
  constexpr int bpc = (Lc + KR2 - 1) / KR2;   // 313
  int comp = blockIdx.x / bpc, rb = blockIdx.x % bpc;
  int t = threadIdx.x;
  int rl = t >> 5, q = t & 31;
  int r = rb * KR2 + rl;
  const float* px = posG + (size_t)comp * 3 * PSTR;
  const float* py = px + PSTR;
  const float* pz = py + PSTR;

  float bd[Kc];
  int   bi[Kc];
  #pragma unroll
  for (int k = 0; k < Kc; ++k) { bd[k] = __int_as_float(0x7f800000); bi[k] = 0x7fffffff; }

  if (r < Lc) {
    float rx = px[r], ry = py[r], rz = pz[r];
    int c0 = q * KC2;
    int c1 = c0 + KC2; if (c1 > Lc) c1 = Lc;
    for (int i = c0; i < c1; i += 4) {
      float4 xs = *(const float4*)(px + i);
      float4 ys = *(const float4*)(py + i);
      float4 zs = *(const float4*)(pz + i);
      float d2v[4];
      {
        float dx, dy, dz;
        dx = rx - xs.x; dy = ry - ys.x; dz = rz - zs.x; d2v[0] = dx*dx + dy*dy + dz*dz;
        dx = rx - xs.y; dy = ry - ys.y; dz = rz - zs.y; d2v[1] = dx*dx + dy*dy + dz*dz;
        dx = rx - xs.z; dy = ry - ys.z; dz = rz - zs.z; d2v[2] = dx*dx + dy*dy + dz*dz;
        dx = rx - xs.w; dy = ry - ys.w; dz = rz - zs.w; d2v[3] = dx*dx + dy*dy + dz*dz;
      }
      #pragma unroll
      for (int u = 0; u < 4; ++u) {
        int ii = i + u;
        float d2 = d2v[u];
        if (ii != r && d2 < bd[Kc - 1]) {
          bd[Kc - 1] = d2; bi[Kc - 1] = ii;
          #pragma unroll
          for (int p = Kc - 1; p > 0; --p) {
            if (bd[p] < bd[p - 1]) {
              float td = bd[p]; bd[p] = bd[p - 1]; bd[p - 1] = td;
              int   ti = bi[p]; bi[p] = bi[p - 1]; bi[p - 1] = ti;
            }
          }
        }
      }
    }
  }

  int gbase = (comp * Lc + r) * Kc;
  #pragma unroll
  for (int k = 0; k < Kc; ++k) {
    unsigned long long mykey =
        ((unsigned long long)__float_as_uint(bd[0]) << 32) | (unsigned int)bi[0];
    unsigned long long w = mykey;
    #pragma unroll
    for (int m = 1; m <= 16; m <<= 1) {
      unsigned long long o = __shfl_xor(w, m);
      if (o < w) w = o;
    }
    if (r < Lc && q == k)
      nbr[gbase + k] = comp * Lc + (int)(unsigned int)(w & 0xffffffffULL);
    if (mykey == w) {
      #pragma unroll
      for (int s = 0; s < Kc - 1; ++s) { bd[s] = bd[s + 1]; bi[s] = bi[s + 1]; }
      bd[Kc - 1] = __int_as_float(0x7f800000); bi[Kc - 1] = 0x7fffffff;
    }
  }
}

// ---------------------------------------------------------------------------
// MFMA node AB (layer 0), with fused embedding gather:
//   h[n] = Htab[S[n]]  (written to hv);  hA = h@We1a + be1, hB = h@We1b
// ---------------------------------------------------------------------------
__global__ __launch_bounds__(256) void nodeABm_kernel(
    const int* __restrict__ S, const float* __restrict__ Htab,
    float* __restrict__ hv,
    const unsigned short* __restrict__ We1a_s, const unsigned short* __restrict__ We1b_s,
    const float* __restrict__ be1n, bf16* __restrict__ hA, bf16* __restrict__ hB) {
  __shared__ __align__(16) unsigned short sB[4 * 512];
  int t = threadIdx.x, n0 = blockIdx.x * 16;
  int lane = t & 63, wv = t >> 6, quad = lane >> 4, l15 = lane & 15, wnb = wv << 5;

  for (int o = t; o < 16 * HID; o += 256) {
    int row = o >> 7, k = o & 127;
    float v = Htab[clampi(S[n0 + row], NCLS) * HID + k];
    hv[(size_t)(n0 + row) * HID + k] = v;
    sB[fragoff(row, k, 1)] = f2bu(v);
  }
  __syncthreads();

  f32x4 a3[2] = {{0,0,0,0},{0,0,0,0}}, a4[2] = {{0,0,0,0},{0,0,0,0}};
  const sh8* sBv = (const sh8*)sB;
  for (int kt = 0; kt < 4; ++kt) {
    sh8 a = sBv[kt * 64 + lane];
    sh8 b0 = ((const sh8*)We1a_s)[((kt << 3) + (wv << 1) + 0) * 64 + lane];
    sh8 b1 = ((const sh8*)We1a_s)[((kt << 3) + (wv << 1) + 1) * 64 + lane];
    sh8 c0 = ((const sh8*)We1b_s)[((kt << 3) + (wv << 1) + 0) * 64 + lane];
    sh8 c1 = ((const sh8*)We1b_s)[((kt << 3) + (wv << 1) + 1) * 64 + lane];
    a3[0] = mfma16(a, b0, a3[0]); a3[1] = mfma16(a, b1, a3[1]);
    a4[0] = mfma16(a, c0, a4[0]); a4[1] = mfma16(a, c1, a4[1]);
  }
  #pragma unroll
  for (int nl = 0; nl < 2; ++nl) {
    int col = wnb + (nl << 4) + l15;
    float be = be1n[col];
    #pragma unroll
    for (int r = 0; r < 4; ++r) {
      int row = (quad << 2) + r;
      hA[(size_t)(n0 + row) * HID + col] = __float2bfloat16(a3[nl][r] + be);
      hB[(size_t)(n0 + row) * HID + col] = __float2bfloat16(a4[nl][r]);
    }
  }
}

// ---------------------------------------------------------------------------
// MFMA fused node update + next AB  (unchanged)
// ---------------------------------------------------------------------------
__global__ __launch_bounds__(256) void fupdAB_kernel(
    float* __restrict__ h, const bf16* __restrict__ aggm,
    const unsigned short* __restrict__ Wh1_s, const unsigned short* __restrict__ Wh2_s,
    const unsigned short* __restrict__ We1a_s, const unsigned short* __restrict__ We1b_s,
    const float* __restrict__ be1n, bf16* __restrict__ hA, bf16* __restrict__ hB) {
  __shared__ __align__(16) unsigned short sA[8 * 512];
  __shared__ __align__(16) unsigned short sB[4 * 512];
  int t = threadIdx.x, n0 = blockIdx.x * 16;
  int lane = t & 63, wv = t >> 6, quad = lane >> 4, l15 = lane & 15, wnb = wv << 5;

  for (int o = t; o < 16 * 256; o += 256) {
    int row = o >> 8, k = o & 255;
    float v = (k < HID) ? h[(size_t)(n0 + row) * HID + k]
                        : b2f(aggm[(size_t)(n0 + row) * HID + (k - HID)]);
    sA[fragoff(row, k, 1)] = f2bu(v);
  }
  __syncthreads();

  f32x4 a1[2] = {{0,0,0,0},{0,0,0,0}};
  const sh8* sAv = (const sh8*)sA;
  for (int kt = 0; kt < 8; ++kt) {
    sh8 a = sAv[kt * 64 + lane];
    sh8 b0 = ((const sh8*)Wh1_s)[((kt << 3) + (wv << 1) + 0) * 64 + lane];
    sh8 b1 = ((const sh8*)Wh1_s)[((kt << 3) + (wv << 1) + 1) * 64 + lane];
    a1[0] = mfma16(a, b0, a1[0]);
    a1[1] = mfma16(a, b1, a1[1]);
  }
  #pragma unroll
  for (int nl = 0; nl < 2; ++nl) {
    int col = wnb + (nl << 4) + l15;
    #pragma unroll
    for (int r = 0; r < 4; ++r)
      sB[fragoff((quad << 2) + r, col, 1)] = f2bu(siluf(a1[nl][r]));
  }
  __syncthreads();

  f32x4 a2[2] = {{0,0,0,0},{0,0,0,0}};
  const sh8* sBv = (const sh8*)sB;
  for (int kt = 0; kt < 4; ++kt) {
    sh8 a = sBv[kt * 64 + lane];
    sh8 b0 = ((const sh8*)Wh2_s)[((kt << 3) + (wv << 1) + 0) * 64 + lane];
    sh8 b1 = ((const sh8*)Wh2_s)[((kt << 3) + (wv << 1) + 1) * 64 + lane];
    a2[0] = mfma16(a, b0, a2[0]);
    a2[1] = mfma16(a, b1, a2[1]);
  }
  float hn[2][4];
  #pragma unroll
  for (int nl = 0; nl < 2; ++nl) {
    int col = wnb + (nl << 4) + l15;
    #pragma unroll
    for (int r = 0; r < 4; ++r) {
      int row = (quad << 2) + r;
      float v = h[(size_t)(n0 + row) * HID + col] + a2[nl][r];
      h[(size_t)(n0 + row) * HID + col] = v;
      hn[nl][r] = v;
    }
  }
  __syncthreads();
  #pragma unroll
  for (int nl = 0; nl < 2; ++nl) {
    int col = wnb + (nl << 4) + l15;
    #pragma unroll
    for (int r = 0; r < 4; ++r)
      sB[fragoff((quad << 2) + r, col, 1)] = f2bu(hn[nl][r]);
  }
  __syncthreads();

  f32x4 a3[2] = {{0,0,0,0},{0,0,0,0}}, a4[2] = {{0,0,0,0},{0,0,0,0}};
  for (int kt = 0; kt < 4; ++kt) {
    sh8 a = sBv[kt * 64 + lane];
    sh8 b0 = ((const sh8*)We1a_s)[((kt << 3) + (wv << 1) + 0) * 64 + lane];
    sh8 b1 = ((const sh8*)We1a_s)[((kt << 3) + (wv << 1) + 1) * 64 + lane];
    sh8 c0 = ((const sh8*)We1b_s)[((kt << 3) + (wv << 1) + 0) * 64 + lane];
    sh8 c1 = ((const sh8*)We1b_s)[((kt << 3) + (wv << 1) + 1) * 64 + lane];
    a3[0] = mfma16(a, b0, a3[0]); a3[1] = mfma16(a, b1, a3[1]);
    a4[0] = mfma16(a, c0, a4[0]); a4[1] = mfma16(a, c1, a4[1]);
  }
  #pragma unroll
  for (int nl = 0; nl < 2; ++nl) {
    int col = wnb + (nl << 4) + l15;
    float be = be1n[col];
    #pragma unroll
    for (int r = 0; r < 4; ++r) {
      int row = (quad << 2) + r;
      hA[(size_t)(n0 + row) * HID + col] = __float2bfloat16(a3[nl][r] + be);
      hB[(size_t)(n0 + row) * HID + col] = __float2bfloat16(a4[nl][r]);
    }
  }
}

// ---------------------------------------------------------------------------
// MFMA fused last node update + final FFN  (unchanged)
// ---------------------------------------------------------------------------
__global__ __launch_bounds__(256) void fupdF_kernel(
    const float* __restrict__ h, const bf16* __restrict__ aggm,
    const unsigned short* __restrict__ Wh1_s, const unsigned short* __restrict__ Wh2_s,
    const unsigned short* __restrict__ Wf1_s, const unsigned short* __restrict__ Wf2_s,
    float* __restrict__ out) {
  __shared__ __align__(16) unsigned short sA[8 * 512];
  __shared__ __align__(16) unsigned short sB[4 * 512];
  int t = threadIdx.x, n0 = blockIdx.x * 16;
  int lane = t & 63, wv = t >> 6, quad = lane >> 4, l15 = lane & 15, wnb = wv << 5;

  for (int o = t; o < 16 * 256; o += 256) {
    int row = o >> 8, k = o & 255;
    float v = (k < HID) ? h[(size_t)(n0 + row) * HID + k]
                        : b2f(aggm[(size_t)(n0 + row) * HID + (k - HID)]);
    sA[fragoff(row, k, 1)] = f2bu(v);
  }
  __syncthreads();

  f32x4 a1[2] = {{0,0,0,0},{0,0,0,0}};
  const sh8* sAv = (const sh8*)sA;
  for (int kt = 0; kt < 8; ++kt) {
    sh8 a = sAv[kt * 64 + lane];
    sh8 b0 = ((const sh8*)Wh1_s)[((kt << 3) + (wv << 1) + 0) * 64 + lane];
    sh8 b1 = ((const sh8*)Wh1_s)[((kt << 3) + (wv << 1) + 1) * 64 + lane];
    a1[0] = mfma16(a, b0, a1[0]);
    a1[1] = mfma16(a, b1, a1[1]);
  }
  #pragma unroll
  for (int nl = 0; nl < 2; ++nl) {
    int col = wnb + (nl << 4) + l15;
    #pragma unroll
    for (int r = 0; r < 4; ++r)
      sB[fragoff((quad << 2) + r, col, 1)] = f2bu(siluf(a1[nl][r]));
  }
  __syncthreads();

  f32x4 a2[2] = {{0,0,0,0},{0,0,0,0}};
  const sh8* sBv = (const sh8*)sB;
  for (int kt = 0; kt < 4; ++kt) {
    sh8 a = sBv[kt * 64 + lane];
    sh8 b0 = ((const sh8*)Wh2_s)[((kt << 3) + (wv << 1) + 0) * 64 + lane];
    sh8 b1 = ((const sh8*)Wh2_s)[((kt << 3) + (wv << 1) + 1) * 64 + lane];
    a2[0] = mfma16(a, b0, a2[0]);
    a2[1] = mfma16(a, b1, a2[1]);
  }
  float u2[2][4];
  #pragma unroll
  for (int nl = 0; nl < 2; ++nl) {
    int col = wnb + (nl << 4) + l15;
    #pragma unroll
    for (int r = 0; r < 4; ++r) {
      int row = (quad << 2) + r;
      u2[nl][r] = siluf(h[(size_t)(n0 + row) * HID + col] + a2[nl][r]);
    }
  }
  __syncthreads();
  #pragma unroll
  for (int nl = 0; nl < 2; ++nl) {
    int col = wnb + (nl << 4) + l15;
    #pragma unroll
    for (int r = 0; r < 4; ++r)
      sB[fragoff((quad << 2) + r, col, 1)] = f2bu(u2[nl][r]);
  }
  __syncthreads();

  f32x4 a3[2] = {{0,0,0,0},{0,0,0,0}};
  for (int kt = 0; kt < 4; ++kt) {
    sh8 a = sBv[kt * 64 + lane];
    sh8 b0 = ((const sh8*)Wf1_s)[((kt << 3) + (wv << 1) + 0) * 64 + lane];
    sh8 b1 = ((const sh8*)Wf1_s)[((kt << 3) + (wv << 1) + 1) * 64 + lane];
    a3[0] = mfma16(a, b0, a3[0]);
    a3[1] = mfma16(a, b1, a3[1]);
  }
  #pragma unroll
  for (int nl = 0; nl < 2; ++nl) {
    int col = wnb + (nl << 4) + l15;
    #pragma unroll
    for (int r = 0; r < 4; ++r)
      sA[fragoff((quad << 2) + r, col, 1)] = f2bu(siluf(a3[nl][r]));
  }
  __syncthreads();

  if (wv < 2) {
    f32x4 a5 = {0.f, 0.f, 0.f, 0.f};
    for (int kt = 0; kt < 4; ++kt) {
      sh8 a = sAv[kt * 64 + lane];
      sh8 b = ((const sh8*)Wf2_s)[(kt * 2 + wv) * 64 + lane];
      a5 = mfma16(a, b, a5);
    }
    int col = (wv << 4) + l15;
    if (col < NCLS) {
      #pragma unroll
      for (int r = 0; r < 4; ++r) {
        int row = (quad << 2) + r;
        out[(size_t)(n0 + row) * NCLS + col] = a5[r];
      }
    }
  }
}

// ---------------------------------------------------------------------------
// MFMA edge kernel — s_hB removed (hB read direct from global, prefetched
// across the stage-1 MFMA loop); LDS 38.4 KB -> 4 blocks/CU.
// ---------------------------------------------------------------------------
constexpr int GN  = 4;
constexpr int NE  = GN * Kc;     // 36
constexpr int MT3 = 3;           // m-tiles (M padded to 48)

__global__ __launch_bounds__(256) void edge_kernel(
    const float* __restrict__ Xin, float* __restrict__ Xout,
    const bf16* __restrict__ hA, const bf16* __restrict__ hB,
    const int* __restrict__ S, const float* __restrict__ cwtab,
    const int* __restrict__ nbr,
    const unsigned short* __restrict__ Wrp_s, const unsigned short* __restrict__ We2_s,
    const unsigned short* __restrict__ Wx1_s, const unsigned short* __restrict__ Wx2_s,
    bf16* __restrict__ aggm) {
  __shared__ __align__(16) unsigned short s_R1[48 * 224];  // 21504 B
  __shared__ __align__(16) unsigned short s_R2[48 * 128];  // 12288 B
  __shared__ __align__(16) unsigned short s_xd[NE * 44];   //  3168 B
  __shared__ __align__(16) unsigned short s_hA[GN * 128];  //  1024 B
  __shared__ float s_cw[GN * Cc];
  __shared__ int   s_dst[NE];

  int t = threadIdx.x;
  int n0 = blockIdx.x * GN;
  int lane = t & 63, wv = t >> 6;
  int quad = lane >> 4, l15 = lane & 15;
  int wnb = wv << 5;

  if (t < NE) s_dst[t] = clampi(nbr[n0 * Kc + t], Nn);
  if (t >= 64 && t < 64 + GN * Cc) {
    int o = t - 64;
    s_cw[o] = cwtab[clampi(S[n0 + o / Cc], NCLS) * Cc + o % Cc];
  }
  {
    uint4* r1 = (uint4*)s_R1;
    for (int o = t; o < 1344; o += 256) r1[o] = make_uint4(0u, 0u, 0u, 0u);
    uint4* r2 = (uint4*)s_R2;
    for (int o = t; o < 768; o += 256) r2[o] = make_uint4(0u, 0u, 0u, 0u);
    const unsigned int* src = (const unsigned int*)(hA + (size_t)n0 * HID);
    unsigned int* dA = (unsigned int*)s_hA;
    for (int o = t; o < GN * 64; o += 256) dA[o] = src[o];
  }
  __syncthreads();

  // prefetch hB fragments direct from global (latency hidden by stage-1 MFMA)
  unsigned short hbr[MT3][2][4];
  {
    const unsigned short* hbu = (const unsigned short*)hB;
    #pragma unroll
    for (int mt = 0; mt < MT3; ++mt)
      #pragma unroll
      for (int nl = 0; nl < 2; ++nl) {
        int col = wnb + (nl << 4) + l15;
        #pragma unroll
        for (int r = 0; r < 4; ++r) {
          int row = (mt << 4) + (quad << 2) + r;
          hbr[mt][nl][r] =
              (row < NE) ? hbu[(size_t)s_dst[row] * HID + col] : (unsigned short)0;
        }
      }
  }

  for (int o = t; o < NE * X3; o += 256) {
    int e = o / X3, i = o - e * X3;
    float v = Xin[(size_t)(n0 + e / Kc) * X3 + i] - Xin[(size_t)s_dst[e] * X3 + i];
    s_xd[e * 44 + i] = f2bu(v);
  }
  __syncthreads();

  // ---- rad -> R1 frag-linear: thread = (e, jc); 28 j's per thread, no div ----
  if (t < 252) {
    int e = t / 7, jc = t - (t / 7) * 7;
    const unsigned int* xu = (const unsigned int*)(s_xd + e * 44);
    unsigned int u[21];
    #pragma unroll
    for (int i = 0; i < 21; ++i) u[i] = xu[i];
    float xdv[42];
    #pragma unroll
    for (int i = 0; i < 21; ++i) unpk2(u[i], xdv[2 * i], xdv[2 * i + 1]);
    #pragma unroll
    for (int half = 0; half < 2; ++half) {
      int c = 2 * jc + half;
      const unsigned short* xe = s_xd + e * 44;
      float xc0 = b2fu(xe[c * 3 + 0]);
      float xc1 = b2fu(xe[c * 3 + 1]);
      float xc2 = b2fu(xe[c * 3 + 2]);
      int jbase = c * Cc;
      #pragma unroll
      for (int d = 0; d < 14; ++d) {
        float v = (xc0 * xdv[d * 3 + 0] + xc1 * xdv[d * 3 + 1] +
                   xc2 * xdv[d * 3 + 2]) * (1.0f / 14.0f);
        s_R1[fragoff(e, jbase + d, MT3)] = f2bu(v);
      }
    }
  }
  __syncthreads();

  f32x4 acc1[MT3][2];
  #pragma unroll
  for (int mt = 0; mt < MT3; ++mt)
    #pragma unroll
    for (int nl = 0; nl < 2; ++nl) acc1[mt][nl] = (f32x4){0.f, 0.f, 0.f, 0.f};
  const sh8* r1v = (const sh8*)s_R1;
  for (int kt = 0; kt < 7; ++kt) {
    sh8 b0 = ((const sh8*)Wrp_s)[((kt << 3) + (wv << 1) + 0) * 64 + lane];
    sh8 b1 = ((const sh8*)Wrp_s)[((kt << 3) + (wv << 1) + 1) * 64 + lane];
    #pragma unroll
    for (int mt = 0; mt < MT3; ++mt) {
      sh8 a = r1v[(kt * MT3 + mt) * 64 + lane];
      acc1[mt][0] = mfma16(a, b0, acc1[mt][0]);
      acc1[mt][1] = mfma16(a, b1, acc1[mt][1]);
    }
  }
  #pragma unroll
  for (int mt = 0; mt < MT3; ++mt)
    #pragma unroll
    for (int nl = 0; nl < 2; ++nl) {
      int col = wnb + (nl << 4) + l15;
      #pragma unroll
      for (int r = 0; r < 4; ++r) {
        int row = (mt << 4) + (quad << 2) + r;
        if (row < NE) {
          float v = acc1[mt][nl][r] + b2fu(s_hA[((row / Kc) << 7) + col]) +
                    b2fu(hbr[mt][nl][r]);
          s_R2[fragoff(row, col, MT3)] = f2bu(siluf(v));
        }
      }
    }
  __syncthreads();

  f32x4 acc2[MT3][2];
  #pragma unroll
  for (int mt = 0; mt < MT3; ++mt)
    #pragma unroll
    for (int nl = 0; nl < 2; ++nl) acc2[mt][nl] = (f32x4){0.f, 0.f, 0.f, 0.f};
  const sh8* r2v = (const sh8*)s_R2;
  for (int kt = 0; kt < 4; ++kt) {
    sh8 b0 = ((const sh8*)We2_s)[((kt << 3) + (wv << 1) + 0) * 64 + lane];
    sh8 b1 = ((const sh8*)We2_s)[((kt << 3) + (wv << 1) + 1) * 64 + lane];
    #pragma unroll
    for (int mt = 0; mt < MT3; ++mt) {
      sh8 a = r2v[(kt * MT3 + mt) * 64 + lane];
      acc2[mt][0] = mfma16(a, b0, acc2[mt][0]);
      acc2[mt][1] = mfma16(a, b1, acc2[mt][1]);
    }
  }
  __syncthreads();
  #pragma unroll
  for (int mt = 0; mt < MT3; ++mt)
    #pragma unroll
    for (int nl = 0; nl < 2; ++nl) {
      int col = wnb + (nl << 4) + l15;
      #pragma unroll
      for (int r = 0; r < 4; ++r) {
        int row = (mt << 4) + (quad << 2) + r;
        s_R2[fragoff(row, col, MT3)] = f2bu(siluf(acc2[mt][nl][r]));
      }
    }
  __syncthreads();

  for (int o = t; o < GN * HID; o += 256) {
    int g = o >> 7, col = o & 127;
    float s = 0.f;
    #pragma unroll
    for (int k = 0; k < Kc; ++k) s += b2fu(s_R2[fragoff(g * Kc + k, col, MT3)]);
    aggm[(size_t)(n0 + g) * HID + col] = __float2bfloat16(s);
  }
  f32x4 acc3[MT3][2];
  #pragma unroll
  for (int mt = 0; mt < MT3; ++mt)
    #pragma unroll
    for (int nl = 0; nl < 2; ++nl) acc3[mt][nl] = (f32x4){0.f, 0.f, 0.f, 0.f};
  for (int kt = 0; kt < 4; ++kt) {
    sh8 b0 = ((const sh8*)Wx1_s)[((kt << 3) + (wv << 1) + 0) * 64 + lane];
    sh8 b1 = ((const sh8*)Wx1_s)[((kt << 3) + (wv << 1) + 1) * 64 + lane];
    #pragma unroll
    for (int mt = 0; mt < MT3; ++mt) {
      sh8 a = r2v[(kt * MT3 + mt) * 64 + lane];
      acc3[mt][0] = mfma16(a, b0, acc3[mt][0]);
      acc3[mt][1] = mfma16(a, b1, acc3[mt][1]);
    }
  }
  #pragma unroll
  for (int mt = 0; mt < MT3; ++mt)
    #pragma unroll
    for (int nl = 0; nl < 2; ++nl) {
      int col = wnb + (nl << 4) + l15;
      #pragma unroll
      for (int r = 0; r < 4; ++r) {
        int row = (mt << 4) + (quad << 2) + r;
        s_R1[fragoff(row, col, MT3)] = f2bu(siluf(acc3[mt][nl][r]));
      }
    }
  __syncthreads();

  float* s_coef = (float*)s_R2;
  if (wv == 0) {
    f32x4 a4[MT3];
    #pragma unroll
    for (int mt = 0; mt < MT3; ++mt) a4[mt] = (f32x4){0.f, 0.f, 0.f, 0.f};
    for (int kt = 0; kt < 4; ++kt) {
      sh8 b = ((const sh8*)Wx2_s)[kt * 64 + lane];
      #pragma unroll
      for (int mt = 0; mt < MT3; ++mt) {
        sh8 a = r1v[(kt * MT3 + mt) * 64 + lane];
        a4[mt] = mfma16(a, b, a4[mt]);
      }
    }
    #pragma unroll
    for (int mt = 0; mt < MT3; ++mt)
      #pragma unroll
      for (int r = 0; r < 4; ++r) {
        int row = (mt << 4) + (quad << 2) + r;
        s_coef[(row << 4) + l15] = a4[mt][r];
      }
  }
  __syncthreads();

  for (int o = t; o < GN * X3; o += 256) {
    int g = o / X3, rem = o - g * X3, c = rem / 3;
    float s = 0.f;
    #pragma unroll
    for (int k = 0; k < Kc; ++k) {
      int e = g * Kc + k;
      s += b2fu(s_xd[e * 44 + rem]) * s_coef[(e << 4) + c];
    }
    int gn = n0 + g;
    Xout[(size_t)gn * X3 + rem] =
        Xin[(size_t)gn * X3 + rem] + s * s_cw[g * Cc + c] * (1.0f / 9.0f);
  }
}

// ---------------------------------------------------------------------------
extern "C" void kernel_launch(void* const* d_in, const int* in_sizes, int n_in,
                              void* d_out, int out_size, void* d_ws, size_t ws_size,
                              hipStream_t stream) {
  const float* X    = (const float*)d_in[0];
  const int*   S    = (const int*)d_in[1];
  const float* Etab = (const float*)d_in[2];
  const float* Wch  = (const float*)d_in[3];
  const float* Win  = (const float*)d_in[4];
  const float* Wr   = (const float*)d_in[5];
  const float* We1  = (const float*)d_in[6];
  const float* be1  = (const float*)d_in[7];
  const float* We2  = (const float*)d_in[8];
  const float* Wx1  = (const float*)d_in[9];
  const float* Wx2  = (const float*)d_in[10];
  const float* Wh1  = (const float*)d_in[11];
  const float* Wh2  = (const float*)d_in[12];
  const float* Wf1  = (const float*)d_in[13];
  const float* Wf2  = (const float*)d_in[14];
  (void)in_sizes; (void)n_in; (void)out_size; (void)ws_size;

  char* base = (char*)d_ws;
  size_t off = 0;
  auto alloc = [&](size_t bytes) {
    void* p = base + off;
    off += (bytes + 255) & ~(size_t)255;
    return p;
  };
  int*   nbr   = (int*)  alloc((size_t)Nn * Kc * 4);
  float* Htab  = (float*)alloc(NCLS * HID * 4);
  float* cwtab = (float*)alloc(NCLS * Cc * 4);
  float* Wrpf  = (float*)alloc((size_t)NL * CC * HID * 4);
  float* posG  = (float*)alloc((size_t)Bc * 3 * PSTR * 4);
  float* Xa    = (float*)alloc((size_t)Nn * X3 * 4);
  float* Xb    = (float*)alloc((size_t)Nn * X3 * 4);
  float* hv    = (float*)alloc((size_t)Nn * HID * 4);
  bf16*  hAv   = (bf16*) alloc((size_t)Nn * HID * 2);
  bf16*  hBv   = (bf16*) alloc((size_t)Nn * HID * 2);
  bf16*  aggmv = (bf16*) alloc((size_t)Nn * HID * 2);
  constexpr int WRP_SZ = 7 * 8 * 512;
  constexpr int W128_SZ = 4 * 8 * 512;
  constexpr int WX2_SZ = 4 * 1 * 512;
  constexpr int WH1_SZ = 8 * 8 * 512;
  constexpr int WF2_SZ = 4 * 2 * 512;
  unsigned short* Wrp_s  = (unsigned short*)alloc((size_t)NL * WRP_SZ * 2);
  unsigned short* We2_s  = (unsigned short*)alloc((size_t)NL * W128_SZ * 2);
  unsigned short* Wx1_s  = (unsigned short*)alloc((size_t)NL * W128_SZ * 2);
  unsigned short* Wx2_s  = (unsigned short*)alloc((size_t)NL * WX2_SZ * 2);
  unsigned short* Wh1_s  = (unsigned short*)alloc((size_t)NL * WH1_SZ * 2);
  unsigned short* Wh2_s  = (unsigned short*)alloc((size_t)NL * W128_SZ * 2);
  unsigned short* We1a_s = (unsigned short*)alloc((size_t)NL * W128_SZ * 2);
  unsigned short* We1b_s = (unsigned short*)alloc((size_t)NL * W128_SZ * 2);
  unsigned short* Wf1_s  = (unsigned short*)alloc(W128_SZ * 2);
  unsigned short* Wf2_s  = (unsigned short*)alloc(WF2_SZ * 2);

  wrp_kernel<<<NL * CC, 128, 0, stream>>>(Wr, We1, Wrpf);
  htab_kernel<<<NCLS, 128, 0, stream>>>(Etab, Win, Wch, Htab, cwtab);
  posx_kernel<<<79, 256, 0, stream>>>(X, posG);
  knn_kernel<<<Bc * ((Lc + KR2 - 1) / KR2), 256, 0, stream>>>(posG, nbr);

  ShufArgs sa;
  for (int l = 0; l < NL; ++l) {
    int e = l * 8;
    sa.src[e+0] = Wrpf + (size_t)l * CC * HID;       sa.dst[e+0] = Wrp_s  + (size_t)l * WRP_SZ;
    sa.K[e+0] = CC;  sa.N[e+0] = HID; sa.KT[e+0] = 7; sa.NT[e+0] = 8;
    sa.src[e+1] = We2 + (size_t)l * HID * HID;       sa.dst[e+1] = We2_s  + (size_t)l * W128_SZ;
    sa.K[e+1] = HID; sa.N[e+1] = HID; sa.KT[e+1] = 4; sa.NT[e+1] = 8;
    sa.src[e+2] = Wx1 + (size_t)l * HID * HID;       sa.dst[e+2] = Wx1_s  + (size_t)l * W128_SZ;
    sa.K[e+2] = HID; sa.N[e+2] = HID; sa.KT[e+2] = 4; sa.NT[e+2] = 8;
    sa.src[e+3] = Wx2 + (size_t)l * HID * Cc;        sa.dst[e+3] = Wx2_s  + (size_t)l * WX2_SZ;
    sa.K[e+3] = HID; sa.N[e+3] = Cc;  sa.KT[e+3] = 4; sa.NT[e+3] = 1;
    sa.src[e+4] = Wh1 + (size_t)l * 256 * HID;       sa.dst[e+4] = Wh1_s  + (size_t)l * WH1_SZ;
    sa.K[e+4] = 256; sa.N[e+4] = HID; sa.KT[e+4] = 8; sa.NT[e+4] = 8;
    sa.src[e+5] = Wh2 + (size_t)l * HID * HID;       sa.dst[e+5] = Wh2_s  + (size_t)l * W128_SZ;
    sa.K[e+5] = HID; sa.N[e+5] = HID; sa.KT[e+5] = 4; sa.NT[e+5] = 8;
    sa.src[e+6] = We1 + (size_t)l * 384 * HID;       sa.dst[e+6] = We1a_s + (size_t)l * W128_SZ;
    sa.K[e+6] = HID; sa.N[e+6] = HID; sa.KT[e+6] = 4; sa.NT[e+6] = 8;
    sa.src[e+7] = We1 + (size_t)l * 384 * HID + (size_t)HID * HID;
    sa.dst[e+7] = We1b_s + (size_t)l * W128_SZ;
    sa.K[e+7] = HID; sa.N[e+7] = HID; sa.KT[e+7] = 4; sa.NT[e+7] = 8;
  }
  sa.src[24] = Wf1; sa.dst[24] = Wf1_s; sa.K[24] = HID; sa.N[24] = HID;
  sa.KT[24] = 4; sa.NT[24] = 8;
  sa.src[25] = Wf2; sa.dst[25] = Wf2_s; sa.K[25] = HID; sa.N[25] = NCLS;
  sa.KT[25] = 4; sa.NT[25] = 2;
  shufb_kernel<<<dim3(16, NSH), 256, 0, stream>>>(sa);

  nodeABm_kernel<<<Nn / 16, 256, 0, stream>>>(S, Htab, hv, We1a_s, We1b_s, be1,
                                              hAv, hBv);

  float* out = (float*)d_out;
  float* outX = out + (size_t)Nn * NCLS;
  const float* Xi = X;
  for (int l = 0; l < NL; ++l) {
    float* Xo = (l == NL - 1) ? outX : ((l == 0) ? Xb : Xa);
    edge_kernel<<<Nn / GN, 256, 0, stream>>>(
        Xi, Xo, hAv, hBv, S, cwtab, nbr,
        Wrp_s + (size_t)l * WRP_SZ, We2_s + (size_t)l * W128_SZ,
        Wx1_s + (size_t)l * W128_SZ, Wx2_s + (size_t)l * WX2_SZ, aggmv);
    if (l < NL - 1) {
      fupdAB_kernel<<<Nn / 16, 256, 0, stream>>>(
          hv, aggmv, Wh1_s + (size_t)l * WH1_SZ, Wh2_s + (size_t)l * W128_SZ,
          We1a_s + (size_t)(l + 1) * W128_SZ, We1b_s + (size_t)(l + 1) * W128_SZ,
          be1 + (l + 1) * HID, hAv, hBv);
    } else {
      fupdF_kernel<<<Nn / 16, 256, 0, stream>>>(
          hv, aggmv, Wh1_s + (size_t)l * WH1_SZ, Wh2_s + (size_t)l * W128_SZ,
          Wf1_s, Wf2_s, out);
    }
    Xi = Xo;
  }
}